// Round 1
// 903.724 us; speedup vs baseline: 1.0592x; 1.0592x over previous
//
#include <hip/hip_runtime.h>
#include <hip/hip_bf16.h>

#define DEV static __device__ __forceinline__

typedef short bfx8 __attribute__((ext_vector_type(8)));   // 8 bf16 in 4 VGPRs (guide §3)
typedef float fx4  __attribute__((ext_vector_type(4)));

DEV float bf2f(__hip_bfloat16 h) { return __bfloat162float(h); }
DEV __hip_bfloat16 f2bf(float f) { return __float2bfloat16(f); }
DEV float uLO(unsigned u) { return __uint_as_float(u << 16); }
DEV float uHI(unsigned u) { return __uint_as_float(u & 0xffff0000u); }
DEV unsigned short f2bfu(float f) { __hip_bfloat16 h = __float2bfloat16(f); return *(unsigned short*)&h; }

DEV float wave_sum(float v) {
#pragma unroll
  for (int o = 32; o; o >>= 1) v += __shfl_xor(v, o, 64);
  return v;
}

#define GLD_LDS16(gp, lp) __builtin_amdgcn_global_load_lds( \
    (__attribute__((address_space(1))) void*)(gp),          \
    (__attribute__((address_space(3))) void*)(lp), 16, 0, 0)

// -------- transpose+convert: src fp32 [R][C] -> dst bf16 [C][R], batch z ----
__global__ __launch_bounds__(256) void transpose_k(
    const float* __restrict__ src, __hip_bfloat16* __restrict__ dst,
    int R, int C)
{
  __shared__ float tile[32][33];
  size_t off = (size_t)blockIdx.z * R * C;
  src += off; dst += off;
  int c0 = blockIdx.x * 32, r0 = blockIdx.y * 32;
#pragma unroll
  for (int i = 0; i < 32; i += 8)
    tile[threadIdx.y + i][threadIdx.x] =
        src[(size_t)(r0 + threadIdx.y + i) * C + c0 + threadIdx.x];
  __syncthreads();
#pragma unroll
  for (int i = 0; i < 32; i += 8)
    dst[(size_t)(c0 + threadIdx.y + i) * R + r0 + threadIdx.x] =
        f2bf(tile[threadIdx.x][threadIdx.y + i]);
}

// ---------------- GEMM: C = A[M,K] x B  (B given transposed: BT[N,K]) ------
// 128x128 tile, 4 waves, each wave 64x64 via 4x4 mfma_f32_16x16x32_bf16.
// Routed modes: rt layout = [8 expert counts][8 task counts]
//                           [8 x M expert token idx][8 x M task token idx]
enum { EPI_STORE = 0, EPI_GELU = 1, EPI_RESADD = 2, EPI_MOE = 3,
       EPI_GELU_R = 4, EPI_MOE_R = 5, EPI_HEAD_R = 6 };

template <int MODE>
__global__ __launch_bounds__(256) void gemm_bt(
    const __hip_bfloat16* __restrict__ A,    // [M,K]  (+ zt*strideAz)
    const __hip_bfloat16* __restrict__ BT,   // [zt][N,K]
    const float* __restrict__ bias,          // [zt][N] fp32
    int M, int N, int K, int splitK, int taskBase,
    long long strideBz, long long strideBiasz, long long strideAz, long long strideCz,
    __hip_bfloat16* __restrict__ Cb, float* __restrict__ Cf,
    const float* __restrict__ combine, const int* __restrict__ rt)
{
  constexpr bool ROUTED = (MODE == EPI_GELU_R || MODE == EPI_MOE_R || MODE == EPI_HEAD_R);
  constexpr bool GATHER = (MODE == EPI_GELU_R || MODE == EPI_HEAD_R);
  __shared__ __hip_bfloat16 sA[128 * 32];  // [m][k]
  __shared__ __hip_bfloat16 sB[128 * 32];  // [n][k]
  const int tid = threadIdx.x;
  const int wave = tid >> 6, lane = tid & 63;
  const int quad = lane >> 4, l16 = lane & 15;
  const int z = blockIdx.z;
  const int zt = z / splitK;
  const int kc = z - zt * splitK;
  const int task = taskBase + zt;
  const int Ksub = K / splitK;
  const int kbeg = kc * Ksub;
  const int m0 = blockIdx.y * 128, n0 = blockIdx.x * 128;

  int Meff = M;
  const int* ilist = nullptr;
  if (ROUTED) {
    const int base = (MODE == EPI_HEAD_R) ? 8 : 0;
    Meff = rt[base + zt];
    ilist = rt + 16 + (size_t)base * M + (size_t)zt * M;
    if (m0 >= Meff) return;   // whole block exits together, before any barrier
  }

  A += (size_t)zt * strideAz;
  Cb += (size_t)zt * strideCz;
  const __hip_bfloat16* Bz = BT + (size_t)zt * strideBz;
  const float* biasz = bias + (size_t)zt * strideBiasz;
  const int wm = (wave >> 1) * 64, wn = (wave & 1) * 64;

  fx4 acc[4][4];
#pragma unroll
  for (int i = 0; i < 4; ++i)
#pragma unroll
    for (int j = 0; j < 4; ++j) acc[i][j] = (fx4){0.f, 0.f, 0.f, 0.f};

  // staging: chunk c covers row c>>2, k-seg (c&3)*8 ; LDS dest = c*8 elems
  // (wave-uniform base + lane*16B — matches m104/m108 constraint)
  const int c0 = tid, c1 = tid + 256;
  const int mlim = Meff - 1;
  int gm0 = m0 + (c0 >> 2); if (gm0 > mlim) gm0 = mlim;
  int gm1 = m0 + (c1 >> 2); if (gm1 > mlim) gm1 = mlim;
  const int ar0 = GATHER ? ilist[gm0] : gm0;
  const int ar1 = GATHER ? ilist[gm1] : gm1;
  const int ak0 = (c0 & 3) * 8, ak1 = (c1 & 3) * 8;
  const __hip_bfloat16* pa0 = A + (size_t)ar0 * K + kbeg + ak0;
  const __hip_bfloat16* pa1 = A + (size_t)ar1 * K + kbeg + ak1;
  const __hip_bfloat16* pb0 = Bz + (size_t)(n0 + (c0 >> 2)) * K + kbeg + ak0;
  const __hip_bfloat16* pb1 = Bz + (size_t)(n0 + (c1 >> 2)) * K + kbeg + ak1;

  for (int kk = 0; kk < Ksub; kk += 32) {
    GLD_LDS16(pa0 + kk, &sA[c0 * 8]);
    GLD_LDS16(pa1 + kk, &sA[c1 * 8]);
    GLD_LDS16(pb0 + kk, &sB[c0 * 8]);
    GLD_LDS16(pb1 + kk, &sB[c1 * 8]);
    __syncthreads();   // drains vmcnt -> LDS writes visible
    bfx8 af[4], bfr[4];
#pragma unroll
    for (int i = 0; i < 4; ++i)
      af[i] = *(const bfx8*)(&sA[(wm + i * 16 + l16) * 32 + quad * 8]);
#pragma unroll
    for (int j = 0; j < 4; ++j)
      bfr[j] = *(const bfx8*)(&sB[(wn + j * 16 + l16) * 32 + quad * 8]);
#pragma unroll
    for (int i = 0; i < 4; ++i)
#pragma unroll
      for (int j = 0; j < 4; ++j)
        acc[i][j] = __builtin_amdgcn_mfma_f32_16x16x32_bf16(af[i], bfr[j], acc[i][j], 0, 0, 0);
    __syncthreads();
  }

  // epilogue: C/D layout col=lane&15, row=quad*4+reg (m89-verified)
  const int mb = m0 + wm + quad * 4;
  const int nb = n0 + wn + l16;
#pragma unroll
  for (int i = 0; i < 4; ++i) {
#pragma unroll
    for (int rr = 0; rr < 4; ++rr) {
      const int m = mb + i * 16 + rr;
      if (m >= Meff) continue;
      int orow = m;
      float sc = 0.f;
      if (MODE == EPI_MOE_R || MODE == EPI_HEAD_R) orow = ilist[m];
      if (MODE == EPI_MOE_R) sc = combine[orow * 8 + task];
#pragma unroll
      for (int j = 0; j < 4; ++j) {
        const int n = nb + j * 16;
        float v = acc[i][j][rr];
        if (MODE == EPI_STORE) {
          Cb[(size_t)m * N + n] = f2bf(v + biasz[n]);
        } else if (MODE == EPI_GELU || MODE == EPI_GELU_R) {
          float t = v + biasz[n];
          Cb[(size_t)m * N + n] = f2bf(0.5f * t * (1.f + erff(t * 0.70710678118654752f)));
        } else if (MODE == EPI_RESADD) {
          if (kc == 0) v += biasz[n];
          atomicAdd(&Cf[(size_t)m * N + n], v);
        } else if (MODE == EPI_MOE) {
          float s = combine[m * 8 + task];
          if (s != 0.f) {
            if (kc == 0) v += biasz[n];
            atomicAdd(&Cf[(size_t)m * N + n], s * v);
          }
        } else if (MODE == EPI_MOE_R) {
          if (kc == 0) v += biasz[n];
          atomicAdd(&Cf[(size_t)orow * N + n], sc * v);
        } else {  // EPI_HEAD_R
          atomicAdd(&Cf[(size_t)orow * N + n], v + biasz[n]);
        }
      }
    }
  }
}

// ---------------- MFMA attention ------------------------------------------
// grid.x = B*H*4 ; block = 256. Each wave owns one 16-row m-tile of S (13 tiles).
// QK^T: A/B frags straight from global (rows are k-contiguous).
// Softmax in regs (16-lane shuffle). P -> LDS strip (bf16 hi+lo compensated,
// two PV passes over the same strip — same-wave ordering, no barrier).
__global__ __launch_bounds__(256) void attn_mfma_k(
    const __hip_bfloat16* __restrict__ qkvb, __hip_bfloat16* __restrict__ outb)
{
  __shared__ __align__(16) unsigned short VT[64 * 232];       // V^T [d][tok], stride 232
  __shared__ __align__(16) unsigned short Pst[4][16 * 232];   // per-wave P strip [m][tok]
  const int tid = threadIdx.x;
  const int chunk = blockIdx.x & 3;
  const int bh = blockIdx.x >> 2;
  const int b = bh / 12, h = bh - b * 12;
  const size_t tokBase = (size_t)b * 197;
  const __hip_bfloat16* qkvh = qkvb + tokBase * 2304 + (size_t)h * 64;

  // stage V^T (which=2 -> +1536)
  for (int idx = tid; idx < 197 * 32; idx += 256) {
    int j = idx >> 5, dp = idx & 31;
    unsigned pv = *(const unsigned*)(qkvh + (size_t)j * 2304 + 1536 + dp * 2);
    VT[(2 * dp) * 232 + j]     = (unsigned short)(pv & 0xffffu);
    VT[(2 * dp + 1) * 232 + j] = (unsigned short)(pv >> 16);
  }
  // NaN fix: zero VT pad cols [197,232). PV reads cols up to 223; leftover LDS
  // bits there can be Inf/NaN-pattern bf16, and 0 (from P) * Inf = NaN.
  for (int idx = tid; idx < 64 * 35; idx += 256) {
    int r = idx / 35, c = 197 + idx % 35;
    VT[r * 232 + c] = 0;
  }
  __syncthreads();

  const int wave = tid >> 6, lane = tid & 63;
  const int quad = lane >> 4, l16 = lane & 15;
  const int mt = chunk * 4 + wave;   // m-tile 0..12
  if (mt >= 13) return;

  // zero P strip pad cols [208,224)
  {
    int r = lane >> 2, c = 208 + (lane & 3) * 4;
    *(uint2*)&Pst[wave][r * 232 + c] = (uint2){0u, 0u};
  }

  // Q A-frags (clamped rows; invalid rows computed but never stored)
  int tq = mt * 16 + l16; if (tq > 196) tq = 196;
  const bfx8 af0 = *(const bfx8*)(qkvh + (size_t)tq * 2304 + quad * 8);
  const bfx8 af1 = *(const bfx8*)(qkvh + (size_t)tq * 2304 + 32 + quad * 8);

  // S strip: 13 n-tiles, K frags from global (which=1 -> +768)
  fx4 sv[13];
#pragma unroll
  for (int n0 = 0; n0 < 13; ++n0) {
    int tk = n0 * 16 + l16; if (tk > 196) tk = 196;
    const __hip_bfloat16* kp = qkvh + (size_t)tk * 2304 + 768;
    bfx8 bf0 = *(const bfx8*)(kp + quad * 8);
    bfx8 bf1 = *(const bfx8*)(kp + 32 + quad * 8);
    fx4 a = (fx4){0.f, 0.f, 0.f, 0.f};
    a = __builtin_amdgcn_mfma_f32_16x16x32_bf16(af0, bf0, a, 0, 0, 0);
    a = __builtin_amdgcn_mfma_f32_16x16x32_bf16(af1, bf1, a, 0, 0, 0);
    sv[n0] = a;
  }

  // softmax per row (row = quad*4+rr); cols of lane: n0*16+l16
  float inv[4];
#pragma unroll
  for (int rr = 0; rr < 4; ++rr) {
    float mx = -3.0e38f;
#pragma unroll
    for (int n0 = 0; n0 < 13; ++n0) {
      bool ok = (n0 < 12) | (l16 < 5);           // col < 197
      float s = ok ? sv[n0][rr] * 0.125f : -3.0e38f;
      sv[n0][rr] = s;
      mx = fmaxf(mx, s);
    }
#pragma unroll
    for (int o = 1; o < 16; o <<= 1) mx = fmaxf(mx, __shfl_xor(mx, o, 64));
    float sum = 0.f;
#pragma unroll
    for (int n0 = 0; n0 < 13; ++n0) {
      float s = sv[n0][rr];
      float e = (s > -1.0e38f) ? __expf(s - mx) : 0.f;
      sv[n0][rr] = e;
      sum += e;
    }
#pragma unroll
    for (int o = 1; o < 16; o <<= 1) sum += __shfl_xor(sum, o, 64);
    inv[rr] = 1.f / sum;
    const int row = quad * 4 + rr;
#pragma unroll
    for (int n0 = 0; n0 < 13; ++n0)
      Pst[wave][row * 232 + n0 * 16 + l16] = f2bfu(sv[n0][rr]);   // P hi
  }

  // PV pass 1 (P hi)
  fx4 pv[4];
#pragma unroll
  for (int nd = 0; nd < 4; ++nd) pv[nd] = (fx4){0.f, 0.f, 0.f, 0.f};
#pragma unroll
  for (int kk = 0; kk < 7; ++kk) {
    bfx8 paf = *(const bfx8*)&Pst[wave][l16 * 232 + kk * 32 + quad * 8];
#pragma unroll
    for (int nd = 0; nd < 4; ++nd) {
      bfx8 bfv = *(const bfx8*)&VT[(nd * 16 + l16) * 232 + kk * 32 + quad * 8];
      pv[nd] = __builtin_amdgcn_mfma_f32_16x16x32_bf16(paf, bfv, pv[nd], 0, 0, 0);
    }
  }

  // P lo = e - bf16(e), overwrite same strip (same-wave ordering -> safe)
#pragma unroll
  for (int rr = 0; rr < 4; ++rr) {
    const int row = quad * 4 + rr;
#pragma unroll
    for (int n0 = 0; n0 < 13; ++n0) {
      float e = sv[n0][rr];
      Pst[wave][row * 232 + n0 * 16 + l16] = f2bfu(e - uLO(f2bfu(e)));
    }
  }

  // PV pass 2 (P lo) accumulates
#pragma unroll
  for (int kk = 0; kk < 7; ++kk) {
    bfx8 paf = *(const bfx8*)&Pst[wave][l16 * 232 + kk * 32 + quad * 8];
#pragma unroll
    for (int nd = 0; nd < 4; ++nd) {
      bfx8 bfv = *(const bfx8*)&VT[(nd * 16 + l16) * 232 + kk * 32 + quad * 8];
      pv[nd] = __builtin_amdgcn_mfma_f32_16x16x32_bf16(paf, bfv, pv[nd], 0, 0, 0);
    }
  }

  // store: row m = mt*16 + quad*4 + rr, col d = nd*16 + l16
#pragma unroll
  for (int rr = 0; rr < 4; ++rr) {
    int m = mt * 16 + quad * 4 + rr;
    if (m > 196) continue;
    __hip_bfloat16* op = outb + (tokBase + m) * 768 + (size_t)h * 64;
#pragma unroll
    for (int nd = 0; nd < 4; ++nd)
      op[nd * 16 + l16] = f2bf(pv[nd][rr] * inv[rr]);
  }
}

// ---------------- LayerNorm: one wave per token, fp32 in -> bf16 out -------
__global__ __launch_bounds__(256) void ln_k(
    const float* __restrict__ xf, const float* __restrict__ w,
    const float* __restrict__ b, __hip_bfloat16* __restrict__ out, int T)
{
  int wv = threadIdx.x >> 6, lane = threadIdx.x & 63;
  int t = blockIdx.x * 4 + wv;
  if (t >= T) return;
  const float* row = xf + (size_t)t * 768;
  float v[12]; float s = 0.f;
#pragma unroll
  for (int i = 0; i < 12; ++i) { v[i] = row[lane + i * 64]; s += v[i]; }
  s = wave_sum(s);
  float mean = s * (1.f / 768.f);
  float q = 0.f;
#pragma unroll
  for (int i = 0; i < 12; ++i) { float d = v[i] - mean; q += d * d; }
  q = wave_sum(q);
  float rstd = rsqrtf(q * (1.f / 768.f) + 1e-5f);
#pragma unroll
  for (int i = 0; i < 12; ++i) {
    int d = lane + i * 64;
    out[(size_t)t * 768 + d] = f2bf((v[i] - mean) * rstd * w[d] + b[d]);
  }
}

// ---------------- MoE gating: fp32 LN + logits + softmax + top-4 ----------
// Also appends token t to each selected expert's routing list in rt.
__global__ __launch_bounds__(256) void gate_k(
    const float* __restrict__ xf, const float* __restrict__ lw,
    const float* __restrict__ lb, const float* __restrict__ gw,
    float* __restrict__ combine, int* __restrict__ rt, int T)
{
  int wv = threadIdx.x >> 6, lane = threadIdx.x & 63;
  int t = blockIdx.x * 4 + wv;
  if (t >= T) return;
  const float* row = xf + (size_t)t * 768;
  float v[12]; float s = 0.f;
#pragma unroll
  for (int i = 0; i < 12; ++i) { v[i] = row[lane + i * 64]; s += v[i]; }
  s = wave_sum(s);
  float mean = s * (1.f / 768.f);
  float qv = 0.f;
#pragma unroll
  for (int i = 0; i < 12; ++i) { float d = v[i] - mean; qv += d * d; }
  qv = wave_sum(qv);
  float rstd = rsqrtf(qv * (1.f / 768.f) + 1e-5f);
  float acc[8];
#pragma unroll
  for (int e = 0; e < 8; ++e) acc[e] = 0.f;
#pragma unroll
  for (int i = 0; i < 12; ++i) {
    int d = lane + i * 64;
    float xn = (v[i] - mean) * rstd * lw[d] + lb[d];
    float4 g0 = *(const float4*)(gw + (size_t)d * 8);
    float4 g1 = *(const float4*)(gw + (size_t)d * 8 + 4);
    acc[0] += xn * g0.x; acc[1] += xn * g0.y;
    acc[2] += xn * g0.z; acc[3] += xn * g0.w;
    acc[4] += xn * g1.x; acc[5] += xn * g1.y;
    acc[6] += xn * g1.z; acc[7] += xn * g1.w;
  }
#pragma unroll
  for (int e = 0; e < 8; ++e) acc[e] = wave_sum(acc[e]);
  float mx = acc[0];
#pragma unroll
  for (int e = 1; e < 8; ++e) mx = fmaxf(mx, acc[e]);
  float p[8]; float se = 0.f;
#pragma unroll
  for (int e = 0; e < 8; ++e) { p[e] = __expf(acc[e] - mx); se += p[e]; }
  float inv = 1.f / se;
#pragma unroll
  for (int e = 0; e < 8; ++e) p[e] *= inv;
  float outv[8]; bool used[8];
#pragma unroll
  for (int e = 0; e < 8; ++e) { outv[e] = 0.f; used[e] = false; }
  for (int k = 0; k < 4; ++k) {   // top-4, ties -> lowest index (matches top_k)
    int best = -1; float bv = -1.f;
#pragma unroll
    for (int e = 0; e < 8; ++e) if (!used[e] && p[e] > bv) { bv = p[e]; best = e; }
#pragma unroll
    for (int e = 0; e < 8; ++e) if (e == best) { used[e] = true; outv[e] = bv; }
  }
#pragma unroll
  for (int e = 0; e < 8; ++e) if (lane == e) combine[(size_t)t * 8 + e] = outv[e];
  // routing: one lane per expert appends t to the expert's list (static idx —
  // rule #20: no runtime-indexed register arrays)
#pragma unroll
  for (int e = 0; e < 8; ++e)
    if (lane == e && outv[e] != 0.f) {
      int slot = atomicAdd(&rt[e], 1);
      rt[16 + e * T + slot] = t;
    }
}

// ---------------- masks / small utils --------------------------------------
// Builds cnt (per-token valid-task count) and per-task token lists in rt.
__global__ void mask_k(const int* __restrict__ sm, const int* __restrict__ am,
                       float* __restrict__ cnt, int* __restrict__ rt, int T)
{
  int t = blockIdx.x * 256 + threadIdx.x;
  if (t >= T) return;
  int a = am[t] != 0;
  float c = 0.f;
#pragma unroll
  for (int tt = 0; tt < 8; ++tt) {
    int vv = (sm[tt * T + t] != 0) & a;
    if (vv) {
      int slot = atomicAdd(&rt[8 + tt], 1);
      rt[16 + 8 * T + tt * T + slot] = t;
    }
    c += (float)vv;
  }
  cnt[t] = c;
}

__global__ void f2b_k(const float* __restrict__ in, __hip_bfloat16* __restrict__ out, int n) {
  int i = blockIdx.x * 256 + threadIdx.x;
  if (i < n) out[i] = f2bf(in[i]);
}
// in-place: out[i] = out[i] / (cnt[i/768] + 1e-6)
__global__ void final_k(float* __restrict__ out, const float* __restrict__ cnt, int n) {
  int i = blockIdx.x * 256 + threadIdx.x;
  if (i < n) out[i] = out[i] / (cnt[i / 768] + 1e-6f);
}

// ---------------- host ------------------------------------------------------
extern "C" void kernel_launch(void* const* d_in, const int* in_sizes, int n_in,
                              void* d_out, int out_size, void* d_ws, size_t ws_size,
                              hipStream_t stream)
{
  (void)in_sizes; (void)n_in; (void)out_size;
  const int Ttok = 8 * 197;  // 1576
  const int D = 768, HID = 3072;

  const float* x       = (const float*)d_in[0];
  const float* ln1a_w  = (const float*)d_in[1];
  const float* ln1a_b  = (const float*)d_in[2];
  const float* qkv_wa  = (const float*)d_in[3];
  const float* qkv_ba  = (const float*)d_in[4];
  const float* proj_wa = (const float*)d_in[5];
  const float* proj_ba = (const float*)d_in[6];
  const float* ln2a_w  = (const float*)d_in[7];
  const float* ln2a_b  = (const float*)d_in[8];
  const float* fc1_w   = (const float*)d_in[9];
  const float* fc1_b   = (const float*)d_in[10];
  const float* fc2_w   = (const float*)d_in[11];
  const float* fc2_b   = (const float*)d_in[12];
  const float* ln1b_w  = (const float*)d_in[13];
  const float* ln1b_b  = (const float*)d_in[14];
  const float* qkv_wb  = (const float*)d_in[15];
  const float* qkv_bb  = (const float*)d_in[16];
  const float* proj_wb = (const float*)d_in[17];
  const float* proj_bb = (const float*)d_in[18];
  const float* ln2b_w  = (const float*)d_in[19];
  const float* ln2b_b  = (const float*)d_in[20];
  const float* gate_w  = (const float*)d_in[21];
  const float* w1      = (const float*)d_in[22];
  const float* b1      = (const float*)d_in[23];
  const float* w2      = (const float*)d_in[24];
  const float* b2      = (const float*)d_in[25];
  const float* head_w  = (const float*)d_in[26];
  const float* head_b  = (const float*)d_in[27];
  const int* shared_masks = (const int*)d_in[28];
  const int* agg_mask     = (const int*)d_in[29];
  float* out           = (float*)d_out;

  char* wsp = (char*)d_ws;
  auto alloc = [&](size_t bytes) { char* p = wsp; wsp += (bytes + 255) & ~(size_t)255; return p; };
  float* xf             = (float*)alloc((size_t)Ttok * D * 4);
  __hip_bfloat16* lnb   = (__hip_bfloat16*)alloc((size_t)Ttok * D * 2);
  __hip_bfloat16* qkvb  = (__hip_bfloat16*)alloc((size_t)Ttok * 3 * D * 2);
  __hip_bfloat16* attnb = (__hip_bfloat16*)alloc((size_t)Ttok * D * 2);
  __hip_bfloat16* h1    = (__hip_bfloat16*)alloc((size_t)Ttok * HID * 2);
  float* combine        = (float*)alloc((size_t)Ttok * 8 * 4);
  float* cnt            = (float*)alloc((size_t)Ttok * 4);
  int* rt               = (int*)alloc((size_t)(16 + 16 * Ttok) * 4);  // counts + idx lists
  __hip_bfloat16* qkvaT = (__hip_bfloat16*)alloc((size_t)D * 3 * D * 2);
  __hip_bfloat16* projaT= (__hip_bfloat16*)alloc((size_t)D * D * 2);
  __hip_bfloat16* fc1T  = (__hip_bfloat16*)alloc((size_t)D * HID * 2);
  __hip_bfloat16* fc2T  = (__hip_bfloat16*)alloc((size_t)D * HID * 2);
  __hip_bfloat16* qkvbT = (__hip_bfloat16*)alloc((size_t)D * 3 * D * 2);
  __hip_bfloat16* projbT= (__hip_bfloat16*)alloc((size_t)D * D * 2);
  __hip_bfloat16* headT = (__hip_bfloat16*)alloc((size_t)8 * D * D * 2);
  __hip_bfloat16* wT    = (__hip_bfloat16*)alloc((size_t)D * HID * 2);

  // batched-MoE extra buffers (deterministic guard: ws_size constant per harness)
  const size_t used = (size_t)(wsp - (char*)d_ws);
  const size_t extraNeed = 2 * ((size_t)8 * D * HID * 2 + 255)        // w1T8 + w2T8
                         + ((size_t)8 * Ttok * HID * 2 + 255);        // h1_8
  const bool batched = (ws_size >= used + extraNeed);
  __hip_bfloat16* w1T8 = nullptr; __hip_bfloat16* w2T8 = nullptr; __hip_bfloat16* h1_8 = nullptr;
  if (batched) {
    w1T8 = (__hip_bfloat16*)alloc((size_t)8 * D * HID * 2);
    w2T8 = (__hip_bfloat16*)alloc((size_t)8 * D * HID * 2);
    h1_8 = (__hip_bfloat16*)alloc((size_t)8 * Ttok * HID * 2);
  }

  dim3 tb(32, 8);
  transpose_k<<<dim3(3*D/32, D/32, 1), tb, 0, stream>>>(qkv_wa, qkvaT, D, 3*D);
  transpose_k<<<dim3(D/32, D/32, 1),   tb, 0, stream>>>(proj_wa, projaT, D, D);
  transpose_k<<<dim3(HID/32, D/32, 1), tb, 0, stream>>>(fc1_w, fc1T, D, HID);
  transpose_k<<<dim3(D/32, HID/32, 1), tb, 0, stream>>>(fc2_w, fc2T, HID, D);
  transpose_k<<<dim3(3*D/32, D/32, 1), tb, 0, stream>>>(qkv_wb, qkvbT, D, 3*D);
  transpose_k<<<dim3(D/32, D/32, 1),   tb, 0, stream>>>(proj_wb, projbT, D, D);
  transpose_k<<<dim3(D/32, D/32, 8),   tb, 0, stream>>>(head_w, headT, D, D);
  if (batched) {
    transpose_k<<<dim3(HID/32, D/32, 8), tb, 0, stream>>>(w1, w1T8, D, HID);
    transpose_k<<<dim3(D/32, HID/32, 8), tb, 0, stream>>>(w2, w2T8, HID, D);
  }

  const int nTok = Ttok * D;
  hipMemcpyAsync(xf, x, (size_t)nTok * 4, hipMemcpyDeviceToDevice, stream);
  hipMemsetAsync(rt, 0, 64, stream);   // zero the 16 routing counters
  mask_k<<<(Ttok + 255)/256, 256, 0, stream>>>(shared_masks, agg_mask, cnt, rt, Ttok);
  hipMemsetAsync(out, 0, (size_t)nTok * 4, stream);  // head accumulation buffer

  const int lnGrid = (Ttok + 3) / 4;
  dim3 g_qkv(3*D/128, 13, 1);
  dim3 g_proj(D/128, 13, 4);    // split-K x4
  dim3 g_fc1(HID/128, 13, 1);
  dim3 g_fc2(D/128, 13, 4);     // split-K x4
  dim3 g_head(D/128, 13, 8);    // z = task (routed: blocks past count[t] exit)
  const int attnGrid = 96 * 4;  // (b,h) x 4 row-chunks

  // ---- dense ViT block ----
  ln_k<<<lnGrid, 256, 0, stream>>>(xf, ln1a_w, ln1a_b, lnb, Ttok);
  gemm_bt<EPI_STORE><<<g_qkv, 256, 0, stream>>>(lnb, qkvaT, qkv_ba, Ttok, 3*D, D, 1, 0, 0, 0, 0, 0, qkvb, nullptr, nullptr, nullptr);
  attn_mfma_k<<<attnGrid, 256, 0, stream>>>(qkvb, attnb);
  gemm_bt<EPI_RESADD><<<g_proj, 256, 0, stream>>>(attnb, projaT, proj_ba, Ttok, D, D, 4, 0, 0, 0, 0, 0, nullptr, xf, nullptr, nullptr);
  ln_k<<<lnGrid, 256, 0, stream>>>(xf, ln2a_w, ln2a_b, lnb, Ttok);
  gemm_bt<EPI_GELU><<<g_fc1, 256, 0, stream>>>(lnb, fc1T, fc1_b, Ttok, HID, D, 1, 0, 0, 0, 0, 0, h1, nullptr, nullptr, nullptr);
  gemm_bt<EPI_RESADD><<<g_fc2, 256, 0, stream>>>(h1, fc2T, fc2_b, Ttok, D, HID, 4, 0, 0, 0, 0, 0, nullptr, xf, nullptr, nullptr);

  // ---- MoE ViT block ----
  ln_k<<<lnGrid, 256, 0, stream>>>(xf, ln1b_w, ln1b_b, lnb, Ttok);
  gemm_bt<EPI_STORE><<<g_qkv, 256, 0, stream>>>(lnb, qkvbT, qkv_bb, Ttok, 3*D, D, 1, 0, 0, 0, 0, 0, qkvb, nullptr, nullptr, nullptr);
  attn_mfma_k<<<attnGrid, 256, 0, stream>>>(qkvb, attnb);
  gemm_bt<EPI_RESADD><<<g_proj, 256, 0, stream>>>(attnb, projbT, proj_bb, Ttok, D, D, 4, 0, 0, 0, 0, 0, nullptr, xf, nullptr, nullptr);
  gate_k<<<lnGrid, 256, 0, stream>>>(xf, ln2b_w, ln2b_b, gate_w, combine, rt, Ttok);
  ln_k<<<lnGrid, 256, 0, stream>>>(xf, ln2b_w, ln2b_b, lnb, Ttok);
  if (batched) {
    // routed: only selected (token,expert) pairs computed — 4/8 of dense work.
    gemm_bt<EPI_GELU_R><<<dim3(HID/128, 13, 8), 256, 0, stream>>>(
        lnb, w1T8, b1, Ttok, HID, D, 1, 0,
        (long long)D*HID, HID, 0, (long long)Ttok*HID, h1_8, nullptr, nullptr, rt);
    gemm_bt<EPI_MOE_R><<<dim3(D/128, 13, 32), 256, 0, stream>>>(
        h1_8, w2T8, b2, Ttok, D, HID, 4, 0,
        (long long)HID*D, D, (long long)Ttok*HID, 0, nullptr, xf, combine, rt);
  } else {
    for (int e = 0; e < 8; ++e) {
      transpose_k<<<dim3(HID/32, D/32, 1), tb, 0, stream>>>(w1 + (size_t)e*D*HID, wT, D, HID);
      gemm_bt<EPI_GELU><<<g_fc1, 256, 0, stream>>>(lnb, wT, b1 + (size_t)e*HID, Ttok, HID, D, 1, 0, 0, 0, 0, 0, h1, nullptr, nullptr, nullptr);
      transpose_k<<<dim3(D/32, HID/32, 1), tb, 0, stream>>>(w2 + (size_t)e*HID*D, wT, HID, D);
      gemm_bt<EPI_MOE><<<g_fc2, 256, 0, stream>>>(h1, wT, b2 + (size_t)e*D, Ttok, D, HID, 4, e, 0, 0, 0, 0, nullptr, xf, combine, nullptr);
    }
  }

  // ---- per-task heads + masked aggregation (routed: ~25% of token-task pairs) ----
  f2b_k<<<(nTok + 255)/256, 256, 0, stream>>>(xf, lnb, nTok);
  gemm_bt<EPI_HEAD_R><<<g_head, 256, 0, stream>>>(lnb, headT, head_b, Ttok, D, D, 1, 0, (long long)D*D, D, 0, 0, nullptr, out, nullptr, rt);
  final_k<<<(nTok + 255)/256, 256, 0, stream>>>(out, cnt, nTok);
}

// Round 3
// 870.160 us; speedup vs baseline: 1.1001x; 1.0386x over previous
//
#include <hip/hip_runtime.h>
#include <hip/hip_bf16.h>

#define DEV static __device__ __forceinline__

typedef short bfx8 __attribute__((ext_vector_type(8)));   // 8 bf16 in 4 VGPRs (guide §3)
typedef float fx4  __attribute__((ext_vector_type(4)));

DEV float bf2f(__hip_bfloat16 h) { return __bfloat162float(h); }
DEV __hip_bfloat16 f2bf(float f) { return __float2bfloat16(f); }
DEV float uLO(unsigned u) { return __uint_as_float(u << 16); }
DEV float uHI(unsigned u) { return __uint_as_float(u & 0xffff0000u); }
DEV unsigned short f2bfu(float f) { __hip_bfloat16 h = __float2bfloat16(f); return *(unsigned short*)&h; }

DEV float wave_sum(float v) {
#pragma unroll
  for (int o = 32; o; o >>= 1) v += __shfl_xor(v, o, 64);
  return v;
}

#define GLD_LDS16(gp, lp) __builtin_amdgcn_global_load_lds( \
    (__attribute__((address_space(1))) void*)(gp),          \
    (__attribute__((address_space(3))) void*)(lp), 16, 0, 0)

// -------- transpose+convert: src fp32 [R][C] -> dst bf16 [C][R], batch z ----
__global__ __launch_bounds__(256) void transpose_k(
    const float* __restrict__ src, __hip_bfloat16* __restrict__ dst,
    int R, int C)
{
  __shared__ float tile[32][33];
  size_t off = (size_t)blockIdx.z * R * C;
  src += off; dst += off;
  int c0 = blockIdx.x * 32, r0 = blockIdx.y * 32;
#pragma unroll
  for (int i = 0; i < 32; i += 8)
    tile[threadIdx.y + i][threadIdx.x] =
        src[(size_t)(r0 + threadIdx.y + i) * C + c0 + threadIdx.x];
  __syncthreads();
#pragma unroll
  for (int i = 0; i < 32; i += 8)
    dst[(size_t)(c0 + threadIdx.y + i) * R + r0 + threadIdx.x] =
        f2bf(tile[threadIdx.x][threadIdx.y + i]);
}

// ---------------- GEMM: C = A[M,K] x B  (B given transposed: BT[N,K]) ------
// 128x128 tile, 4 waves, each wave 64x64 via 4x4 mfma_f32_16x16x32_bf16.
// rt layout: [0..7] expert counts, [8..15] task counts, [16..23] expert bases,
//            [24 .. 24+8T) expert token lists, [24+8T .. 24+16T) task lists.
enum { EPI_STORE = 0, EPI_GELU = 1, EPI_RESADD = 2, EPI_MOE = 3,
       EPI_GELU_R = 4, EPI_MOEP = 5, EPI_HEAD_R = 6 };

template <int MODE>
__global__ __launch_bounds__(256) void gemm_bt(
    const __hip_bfloat16* __restrict__ A,    // [M,K]  (+ zt*strideAz)
    const __hip_bfloat16* __restrict__ BT,   // [zt][N,K]
    const float* __restrict__ bias,          // [zt][N] fp32
    int M, int N, int K, int splitK, int taskBase,
    long long strideBz, long long strideBiasz, long long strideAz, long long strideCz,
    __hip_bfloat16* __restrict__ Cb, float* __restrict__ Cf,
    const float* __restrict__ combine, const int* __restrict__ rt)
{
  constexpr bool ROUTED = (MODE == EPI_GELU_R || MODE == EPI_MOEP || MODE == EPI_HEAD_R);
  constexpr bool GATHER = (MODE == EPI_GELU_R || MODE == EPI_HEAD_R);
  __shared__ __hip_bfloat16 sA[128 * 32];  // [m][k]
  __shared__ __hip_bfloat16 sB[128 * 32];  // [n][k]
  const int tid = threadIdx.x;
  const int wave = tid >> 6, lane = tid & 63;
  const int quad = lane >> 4, l16 = lane & 15;
  const int z = blockIdx.z;
  const int zt = z / splitK;
  const int kc = z - zt * splitK;
  const int task = taskBase + zt;
  const int Ksub = K / splitK;
  const int kbeg = kc * Ksub;
  const int m0 = blockIdx.y * 128, n0 = blockIdx.x * 128;

  int Meff = M;
  int rtb = 0;
  const int* ilist = nullptr;
  if (ROUTED) {
    const int base = (MODE == EPI_HEAD_R) ? 8 : 0;
    Meff = rt[base + zt];
    ilist = rt + 24 + (size_t)base * M + (size_t)zt * M;
    if (MODE == EPI_MOEP) rtb = rt[16 + zt];   // compact output base for expert
    if (m0 >= Meff) return;   // whole block exits together, before any barrier
  }

  A += (size_t)zt * strideAz;
  if (MODE != EPI_MOEP) Cb += (size_t)zt * strideCz;
  const __hip_bfloat16* Bz = BT + (size_t)zt * strideBz;
  const float* biasz = bias + (size_t)zt * strideBiasz;
  const int wm = (wave >> 1) * 64, wn = (wave & 1) * 64;

  fx4 acc[4][4];
#pragma unroll
  for (int i = 0; i < 4; ++i)
#pragma unroll
    for (int j = 0; j < 4; ++j) acc[i][j] = (fx4){0.f, 0.f, 0.f, 0.f};

  // staging: chunk c covers row c>>2, k-seg (c&3)*8 ; LDS dest = c*8 elems
  // (wave-uniform base + lane*16B — matches m104/m108 constraint)
  const int c0 = tid, c1 = tid + 256;
  const int mlim = Meff - 1;
  int gm0 = m0 + (c0 >> 2); if (gm0 > mlim) gm0 = mlim;
  int gm1 = m0 + (c1 >> 2); if (gm1 > mlim) gm1 = mlim;
  const int ar0 = GATHER ? ilist[gm0] : gm0;
  const int ar1 = GATHER ? ilist[gm1] : gm1;
  const int ak0 = (c0 & 3) * 8, ak1 = (c1 & 3) * 8;
  const __hip_bfloat16* pa0 = A + (size_t)ar0 * K + kbeg + ak0;
  const __hip_bfloat16* pa1 = A + (size_t)ar1 * K + kbeg + ak1;
  const __hip_bfloat16* pb0 = Bz + (size_t)(n0 + (c0 >> 2)) * K + kbeg + ak0;
  const __hip_bfloat16* pb1 = Bz + (size_t)(n0 + (c1 >> 2)) * K + kbeg + ak1;

  for (int kk = 0; kk < Ksub; kk += 32) {
    GLD_LDS16(pa0 + kk, &sA[c0 * 8]);
    GLD_LDS16(pa1 + kk, &sA[c1 * 8]);
    GLD_LDS16(pb0 + kk, &sB[c0 * 8]);
    GLD_LDS16(pb1 + kk, &sB[c1 * 8]);
    __syncthreads();   // drains vmcnt -> LDS writes visible
    bfx8 af[4], bfr[4];
#pragma unroll
    for (int i = 0; i < 4; ++i)
      af[i] = *(const bfx8*)(&sA[(wm + i * 16 + l16) * 32 + quad * 8]);
#pragma unroll
    for (int j = 0; j < 4; ++j)
      bfr[j] = *(const bfx8*)(&sB[(wn + j * 16 + l16) * 32 + quad * 8]);
#pragma unroll
    for (int i = 0; i < 4; ++i)
#pragma unroll
      for (int j = 0; j < 4; ++j)
        acc[i][j] = __builtin_amdgcn_mfma_f32_16x16x32_bf16(af[i], bfr[j], acc[i][j], 0, 0, 0);
    __syncthreads();
  }

  // epilogue: C/D layout col=lane&15, row=quad*4+reg (m89-verified)
  const int mb = m0 + wm + quad * 4;
  const int nb = n0 + wn + l16;
#pragma unroll
  for (int i = 0; i < 4; ++i) {
#pragma unroll
    for (int rr = 0; rr < 4; ++rr) {
      const int m = mb + i * 16 + rr;
      if (m >= Meff) continue;
      int orow = m;
      if (MODE == EPI_HEAD_R) orow = ilist[m];
#pragma unroll
      for (int j = 0; j < 4; ++j) {
        const int n = nb + j * 16;
        float v = acc[i][j][rr];
        if (MODE == EPI_STORE) {
          Cb[(size_t)m * N + n] = f2bf(v + biasz[n]);
        } else if (MODE == EPI_GELU || MODE == EPI_GELU_R) {
          float t = v + biasz[n];
          Cb[(size_t)m * N + n] = f2bf(0.5f * t * (1.f + erff(t * 0.70710678118654752f)));
        } else if (MODE == EPI_RESADD) {
          if (kc == 0) v += biasz[n];
          atomicAdd(&Cf[(size_t)m * N + n], v);
        } else if (MODE == EPI_MOE) {
          float s = combine[m * 8 + task];
          if (s != 0.f) {
            if (kc == 0) v += biasz[n];
            atomicAdd(&Cf[(size_t)m * N + n], s * v);
          }
        } else if (MODE == EPI_MOEP) {
          // plain fp32 store of split-K partial into compact slot buffer
          if (kc == 0) v += biasz[n];
          Cf[(size_t)kc * strideCz + (size_t)(rtb + m) * N + n] = v;
        } else {  // EPI_HEAD_R
          atomicAdd(&Cf[(size_t)orow * N + n], v + biasz[n]);
        }
      }
    }
  }
}

// ---------------- MFMA attention ------------------------------------------
// grid.x = B*H*4 ; block = 256. Each wave owns one 16-row m-tile of S (13 tiles).
// QK^T: A/B frags straight from global (rows are k-contiguous).
// Softmax in regs (16-lane shuffle). P -> LDS strip (bf16 hi+lo compensated,
// two PV passes over the same strip — same-wave ordering, no barrier).
__global__ __launch_bounds__(256) void attn_mfma_k(
    const __hip_bfloat16* __restrict__ qkvb, __hip_bfloat16* __restrict__ outb)
{
  __shared__ __align__(16) unsigned short VT[64 * 232];       // V^T [d][tok], stride 232
  __shared__ __align__(16) unsigned short Pst[4][16 * 232];   // per-wave P strip [m][tok]
  const int tid = threadIdx.x;
  const int chunk = blockIdx.x & 3;
  const int bh = blockIdx.x >> 2;
  const int b = bh / 12, h = bh - b * 12;
  const size_t tokBase = (size_t)b * 197;
  const __hip_bfloat16* qkvh = qkvb + tokBase * 2304 + (size_t)h * 64;

  // stage V^T (which=2 -> +1536)
  for (int idx = tid; idx < 197 * 32; idx += 256) {
    int j = idx >> 5, dp = idx & 31;
    unsigned pv = *(const unsigned*)(qkvh + (size_t)j * 2304 + 1536 + dp * 2);
    VT[(2 * dp) * 232 + j]     = (unsigned short)(pv & 0xffffu);
    VT[(2 * dp + 1) * 232 + j] = (unsigned short)(pv >> 16);
  }
  // NaN fix: zero VT pad cols [197,232). PV reads cols up to 223; leftover LDS
  // bits there can be Inf/NaN-pattern bf16, and 0 (from P) * Inf = NaN.
  for (int idx = tid; idx < 64 * 35; idx += 256) {
    int r = idx / 35, c = 197 + idx % 35;
    VT[r * 232 + c] = 0;
  }
  __syncthreads();

  const int wave = tid >> 6, lane = tid & 63;
  const int quad = lane >> 4, l16 = lane & 15;
  const int mt = chunk * 4 + wave;   // m-tile 0..12
  if (mt >= 13) return;

  // zero P strip pad cols [208,224)
  {
    int r = lane >> 2, c = 208 + (lane & 3) * 4;
    *(uint2*)&Pst[wave][r * 232 + c] = (uint2){0u, 0u};
  }

  // Q A-frags (clamped rows; invalid rows computed but never stored)
  int tq = mt * 16 + l16; if (tq > 196) tq = 196;
  const bfx8 af0 = *(const bfx8*)(qkvh + (size_t)tq * 2304 + quad * 8);
  const bfx8 af1 = *(const bfx8*)(qkvh + (size_t)tq * 2304 + 32 + quad * 8);

  // S strip: 13 n-tiles, K frags from global (which=1 -> +768)
  fx4 sv[13];
#pragma unroll
  for (int n0 = 0; n0 < 13; ++n0) {
    int tk = n0 * 16 + l16; if (tk > 196) tk = 196;
    const __hip_bfloat16* kp = qkvh + (size_t)tk * 2304 + 768;
    bfx8 bf0 = *(const bfx8*)(kp + quad * 8);
    bfx8 bf1 = *(const bfx8*)(kp + 32 + quad * 8);
    fx4 a = (fx4){0.f, 0.f, 0.f, 0.f};
    a = __builtin_amdgcn_mfma_f32_16x16x32_bf16(af0, bf0, a, 0, 0, 0);
    a = __builtin_amdgcn_mfma_f32_16x16x32_bf16(af1, bf1, a, 0, 0, 0);
    sv[n0] = a;
  }

  // softmax per row (row = quad*4+rr); cols of lane: n0*16+l16
  float inv[4];
#pragma unroll
  for (int rr = 0; rr < 4; ++rr) {
    float mx = -3.0e38f;
#pragma unroll
    for (int n0 = 0; n0 < 13; ++n0) {
      bool ok = (n0 < 12) | (l16 < 5);           // col < 197
      float s = ok ? sv[n0][rr] * 0.125f : -3.0e38f;
      sv[n0][rr] = s;
      mx = fmaxf(mx, s);
    }
#pragma unroll
    for (int o = 1; o < 16; o <<= 1) mx = fmaxf(mx, __shfl_xor(mx, o, 64));
    float sum = 0.f;
#pragma unroll
    for (int n0 = 0; n0 < 13; ++n0) {
      float s = sv[n0][rr];
      float e = (s > -1.0e38f) ? __expf(s - mx) : 0.f;
      sv[n0][rr] = e;
      sum += e;
    }
#pragma unroll
    for (int o = 1; o < 16; o <<= 1) sum += __shfl_xor(sum, o, 64);
    inv[rr] = 1.f / sum;
    const int row = quad * 4 + rr;
#pragma unroll
    for (int n0 = 0; n0 < 13; ++n0)
      Pst[wave][row * 232 + n0 * 16 + l16] = f2bfu(sv[n0][rr]);   // P hi
  }

  // PV pass 1 (P hi)
  fx4 pv[4];
#pragma unroll
  for (int nd = 0; nd < 4; ++nd) pv[nd] = (fx4){0.f, 0.f, 0.f, 0.f};
#pragma unroll
  for (int kk = 0; kk < 7; ++kk) {
    bfx8 paf = *(const bfx8*)&Pst[wave][l16 * 232 + kk * 32 + quad * 8];
#pragma unroll
    for (int nd = 0; nd < 4; ++nd) {
      bfx8 bfv = *(const bfx8*)&VT[(nd * 16 + l16) * 232 + kk * 32 + quad * 8];
      pv[nd] = __builtin_amdgcn_mfma_f32_16x16x32_bf16(paf, bfv, pv[nd], 0, 0, 0);
    }
  }

  // P lo = e - bf16(e), overwrite same strip (same-wave ordering -> safe)
#pragma unroll
  for (int rr = 0; rr < 4; ++rr) {
    const int row = quad * 4 + rr;
#pragma unroll
    for (int n0 = 0; n0 < 13; ++n0) {
      float e = sv[n0][rr];
      Pst[wave][row * 232 + n0 * 16 + l16] = f2bfu(e - uLO(f2bfu(e)));
    }
  }

  // PV pass 2 (P lo) accumulates
#pragma unroll
  for (int kk = 0; kk < 7; ++kk) {
    bfx8 paf = *(const bfx8*)&Pst[wave][l16 * 232 + kk * 32 + quad * 8];
#pragma unroll
    for (int nd = 0; nd < 4; ++nd) {
      bfx8 bfv = *(const bfx8*)&VT[(nd * 16 + l16) * 232 + kk * 32 + quad * 8];
      pv[nd] = __builtin_amdgcn_mfma_f32_16x16x32_bf16(paf, bfv, pv[nd], 0, 0, 0);
    }
  }

  // store: row m = mt*16 + quad*4 + rr, col d = nd*16 + l16
#pragma unroll
  for (int rr = 0; rr < 4; ++rr) {
    int m = mt * 16 + quad * 4 + rr;
    if (m > 196) continue;
    __hip_bfloat16* op = outb + (tokBase + m) * 768 + (size_t)h * 64;
#pragma unroll
    for (int nd = 0; nd < 4; ++nd)
      op[nd * 16 + l16] = f2bf(pv[nd][rr] * inv[rr]);
  }
}

// ---------------- LayerNorm: one wave per token, fp32 in -> bf16 out -------
__global__ __launch_bounds__(256) void ln_k(
    const float* __restrict__ xf, const float* __restrict__ w,
    const float* __restrict__ b, __hip_bfloat16* __restrict__ out, int T)
{
  int wv = threadIdx.x >> 6, lane = threadIdx.x & 63;
  int t = blockIdx.x * 4 + wv;
  if (t >= T) return;
  const float* row = xf + (size_t)t * 768;
  float v[12]; float s = 0.f;
#pragma unroll
  for (int i = 0; i < 12; ++i) { v[i] = row[lane + i * 64]; s += v[i]; }
  s = wave_sum(s);
  float mean = s * (1.f / 768.f);
  float q = 0.f;
#pragma unroll
  for (int i = 0; i < 12; ++i) { float d = v[i] - mean; q += d * d; }
  q = wave_sum(q);
  float rstd = rsqrtf(q * (1.f / 768.f) + 1e-5f);
#pragma unroll
  for (int i = 0; i < 12; ++i) {
    int d = lane + i * 64;
    out[(size_t)t * 768 + d] = f2bf((v[i] - mean) * rstd * w[d] + b[d]);
  }
}

// ---------------- MoE gating: fp32 LN + logits + softmax + top-4 ----------
// Also writes lnb (the ln2b output — merged, replaces a separate ln_k),
// appends token t to each selected expert's routing list, records slot map.
__global__ __launch_bounds__(256) void gate_k(
    const float* __restrict__ xf, const float* __restrict__ lw,
    const float* __restrict__ lb, const float* __restrict__ gw,
    float* __restrict__ combine, int* __restrict__ rt, int* __restrict__ smap,
    __hip_bfloat16* __restrict__ lnbout, int T)
{
  int wv = threadIdx.x >> 6, lane = threadIdx.x & 63;
  int t = blockIdx.x * 4 + wv;
  if (t >= T) return;
  const float* row = xf + (size_t)t * 768;
  float v[12]; float s = 0.f;
#pragma unroll
  for (int i = 0; i < 12; ++i) { v[i] = row[lane + i * 64]; s += v[i]; }
  s = wave_sum(s);
  float mean = s * (1.f / 768.f);
  float qv = 0.f;
#pragma unroll
  for (int i = 0; i < 12; ++i) { float d = v[i] - mean; qv += d * d; }
  qv = wave_sum(qv);
  float rstd = rsqrtf(qv * (1.f / 768.f) + 1e-5f);
  float acc[8];
#pragma unroll
  for (int e = 0; e < 8; ++e) acc[e] = 0.f;
#pragma unroll
  for (int i = 0; i < 12; ++i) {
    int d = lane + i * 64;
    float xn = (v[i] - mean) * rstd * lw[d] + lb[d];
    lnbout[(size_t)t * 768 + d] = f2bf(xn);   // merged ln2b output
    float4 g0 = *(const float4*)(gw + (size_t)d * 8);
    float4 g1 = *(const float4*)(gw + (size_t)d * 8 + 4);
    acc[0] += xn * g0.x; acc[1] += xn * g0.y;
    acc[2] += xn * g0.z; acc[3] += xn * g0.w;
    acc[4] += xn * g1.x; acc[5] += xn * g1.y;
    acc[6] += xn * g1.z; acc[7] += xn * g1.w;
  }
#pragma unroll
  for (int e = 0; e < 8; ++e) acc[e] = wave_sum(acc[e]);
  float mx = acc[0];
#pragma unroll
  for (int e = 1; e < 8; ++e) mx = fmaxf(mx, acc[e]);
  float p[8]; float se = 0.f;
#pragma unroll
  for (int e = 0; e < 8; ++e) { p[e] = __expf(acc[e] - mx); se += p[e]; }
  float inv = 1.f / se;
#pragma unroll
  for (int e = 0; e < 8; ++e) p[e] *= inv;
  float outv[8]; bool used[8];
#pragma unroll
  for (int e = 0; e < 8; ++e) { outv[e] = 0.f; used[e] = false; }
  for (int k = 0; k < 4; ++k) {   // top-4, ties -> lowest index (matches top_k)
    int best = -1; float bv = -1.f;
#pragma unroll
    for (int e = 0; e < 8; ++e) if (!used[e] && p[e] > bv) { bv = p[e]; best = e; }
#pragma unroll
    for (int e = 0; e < 8; ++e) if (e == best) { used[e] = true; outv[e] = bv; }
  }
#pragma unroll
  for (int e = 0; e < 8; ++e) if (lane == e) combine[(size_t)t * 8 + e] = outv[e];
  // routing: one lane per expert appends t to the expert's list (static idx —
  // rule #20: no runtime-indexed register arrays)
#pragma unroll
  for (int e = 0; e < 8; ++e)
    if (lane == e && outv[e] != 0.f) {
      int slot = atomicAdd(&rt[e], 1);
      rt[24 + e * T + slot] = t;
      smap[(size_t)t * 8 + e] = slot;
    }
}

// exclusive prefix of the 8 expert counts -> compact slot bases rt[16..23]
__global__ void prefix_k(int* __restrict__ rt) {
  if (threadIdx.x == 0) {
    int s = 0;
#pragma unroll
    for (int e = 0; e < 8; ++e) { rt[16 + e] = s; s += rt[e]; }
  }
}

// per-token MoE combine: xf[t] += sum_e s_e * (y0[row_e] + y1[row_e])
__global__ __launch_bounds__(256) void combine_k(
    const float* __restrict__ y, const float* __restrict__ combine,
    const int* __restrict__ rt, const int* __restrict__ smap,
    float* __restrict__ xf, int T, int CAP)
{
  int wv = threadIdx.x >> 6, lane = threadIdx.x & 63;
  int t = blockIdx.x * 4 + wv;
  if (t >= T) return;
  float acc[12];
#pragma unroll
  for (int i = 0; i < 12; ++i) acc[i] = 0.f;
  for (int e = 0; e < 8; ++e) {
    float s = combine[(size_t)t * 8 + e];
    if (s != 0.f) {                       // wave-uniform branch
      int r = rt[16 + e] + smap[(size_t)t * 8 + e];
      const float* y0 = y + (size_t)r * 768;
      const float* y1 = y0 + (size_t)CAP * 768;
#pragma unroll
      for (int i = 0; i < 12; ++i)
        acc[i] += s * (y0[lane + i * 64] + y1[lane + i * 64]);
    }
  }
  float* xr = xf + (size_t)t * 768;
#pragma unroll
  for (int i = 0; i < 12; ++i) xr[lane + i * 64] += acc[i];
}

// ---------------- masks / small utils --------------------------------------
// Builds cnt (per-token valid-task count) and per-task token lists in rt.
__global__ void mask_k(const int* __restrict__ sm, const int* __restrict__ am,
                       float* __restrict__ cnt, int* __restrict__ rt, int T)
{
  int t = blockIdx.x * 256 + threadIdx.x;
  if (t >= T) return;
  int a = am[t] != 0;
  float c = 0.f;
#pragma unroll
  for (int tt = 0; tt < 8; ++tt) {
    int vv = (sm[tt * T + t] != 0) & a;
    if (vv) {
      int slot = atomicAdd(&rt[8 + tt], 1);
      rt[24 + 8 * T + tt * T + slot] = t;
    }
    c += (float)vv;
  }
  cnt[t] = c;
}

__global__ void f2b_k(const float* __restrict__ in, __hip_bfloat16* __restrict__ out, int n) {
  int i = blockIdx.x * 256 + threadIdx.x;
  if (i < n) out[i] = f2bf(in[i]);
}
// in-place: out[i] = out[i] / (cnt[i/768] + 1e-6)
__global__ void final_k(float* __restrict__ out, const float* __restrict__ cnt, int n) {
  int i = blockIdx.x * 256 + threadIdx.x;
  if (i < n) out[i] = out[i] / (cnt[i / 768] + 1e-6f);
}

// ---------------- host ------------------------------------------------------
extern "C" void kernel_launch(void* const* d_in, const int* in_sizes, int n_in,
                              void* d_out, int out_size, void* d_ws, size_t ws_size,
                              hipStream_t stream)
{
  (void)in_sizes; (void)n_in; (void)out_size;
  const int Ttok = 8 * 197;  // 1576
  const int D = 768, HID = 3072;
  const int CAP = 4 * Ttok;  // total routed (token,expert) pairs = top-4 exact

  const float* x       = (const float*)d_in[0];
  const float* ln1a_w  = (const float*)d_in[1];
  const float* ln1a_b  = (const float*)d_in[2];
  const float* qkv_wa  = (const float*)d_in[3];
  const float* qkv_ba  = (const float*)d_in[4];
  const float* proj_wa = (const float*)d_in[5];
  const float* proj_ba = (const float*)d_in[6];
  const float* ln2a_w  = (const float*)d_in[7];
  const float* ln2a_b  = (const float*)d_in[8];
  const float* fc1_w   = (const float*)d_in[9];
  const float* fc1_b   = (const float*)d_in[10];
  const float* fc2_w   = (const float*)d_in[11];
  const float* fc2_b   = (const float*)d_in[12];
  const float* ln1b_w  = (const float*)d_in[13];
  const float* ln1b_b  = (const float*)d_in[14];
  const float* qkv_wb  = (const float*)d_in[15];
  const float* qkv_bb  = (const float*)d_in[16];
  const float* proj_wb = (const float*)d_in[17];
  const float* proj_bb = (const float*)d_in[18];
  const float* ln2b_w  = (const float*)d_in[19];
  const float* ln2b_b  = (const float*)d_in[20];
  const float* gate_w  = (const float*)d_in[21];
  const float* w1      = (const float*)d_in[22];
  const float* b1      = (const float*)d_in[23];
  const float* w2      = (const float*)d_in[24];
  const float* b2      = (const float*)d_in[25];
  const float* head_w  = (const float*)d_in[26];
  const float* head_b  = (const float*)d_in[27];
  const int* shared_masks = (const int*)d_in[28];
  const int* agg_mask     = (const int*)d_in[29];
  float* out           = (float*)d_out;

  char* wsp = (char*)d_ws;
  auto alloc = [&](size_t bytes) { char* p = wsp; wsp += (bytes + 255) & ~(size_t)255; return p; };
  float* xf             = (float*)alloc((size_t)Ttok * D * 4);
  __hip_bfloat16* lnb   = (__hip_bfloat16*)alloc((size_t)Ttok * D * 2);
  __hip_bfloat16* qkvb  = (__hip_bfloat16*)alloc((size_t)Ttok * 3 * D * 2);
  __hip_bfloat16* attnb = (__hip_bfloat16*)alloc((size_t)Ttok * D * 2);
  __hip_bfloat16* h1    = (__hip_bfloat16*)alloc((size_t)Ttok * HID * 2);
  float* combine        = (float*)alloc((size_t)Ttok * 8 * 4);
  float* cnt            = (float*)alloc((size_t)Ttok * 4);
  int* rt               = (int*)alloc((size_t)(24 + 16 * Ttok) * 4);  // counts+bases+lists
  int* smap             = (int*)alloc((size_t)Ttok * 8 * 4);
  __hip_bfloat16* qkvaT = (__hip_bfloat16*)alloc((size_t)D * 3 * D * 2);
  __hip_bfloat16* projaT= (__hip_bfloat16*)alloc((size_t)D * D * 2);
  __hip_bfloat16* fc1T  = (__hip_bfloat16*)alloc((size_t)D * HID * 2);
  __hip_bfloat16* fc2T  = (__hip_bfloat16*)alloc((size_t)D * HID * 2);
  __hip_bfloat16* qkvbT = (__hip_bfloat16*)alloc((size_t)D * 3 * D * 2);
  __hip_bfloat16* projbT= (__hip_bfloat16*)alloc((size_t)D * D * 2);
  __hip_bfloat16* headT = (__hip_bfloat16*)alloc((size_t)8 * D * D * 2);
  __hip_bfloat16* wT    = (__hip_bfloat16*)alloc((size_t)D * HID * 2);

  // batched-MoE extra buffers (deterministic guard: ws_size constant per harness)
  const size_t used = (size_t)(wsp - (char*)d_ws);
  const size_t extraNeed = 2 * ((size_t)8 * D * HID * 2 + 255)        // w1T8 + w2T8
                         + ((size_t)8 * Ttok * HID * 2 + 255)         // h1_8
                         + (2 * (size_t)CAP * D * 4 + 255);           // y (2 split-K slices)
  const bool batched = (ws_size >= used + extraNeed);
  __hip_bfloat16* w1T8 = nullptr; __hip_bfloat16* w2T8 = nullptr; __hip_bfloat16* h1_8 = nullptr;
  float* yb = nullptr;
  if (batched) {
    w1T8 = (__hip_bfloat16*)alloc((size_t)8 * D * HID * 2);
    w2T8 = (__hip_bfloat16*)alloc((size_t)8 * D * HID * 2);
    h1_8 = (__hip_bfloat16*)alloc((size_t)8 * Ttok * HID * 2);
    yb   = (float*)alloc(2 * (size_t)CAP * D * 4);
  }

  dim3 tb(32, 8);
  transpose_k<<<dim3(3*D/32, D/32, 1), tb, 0, stream>>>(qkv_wa, qkvaT, D, 3*D);
  transpose_k<<<dim3(D/32, D/32, 1),   tb, 0, stream>>>(proj_wa, projaT, D, D);
  transpose_k<<<dim3(HID/32, D/32, 1), tb, 0, stream>>>(fc1_w, fc1T, D, HID);
  transpose_k<<<dim3(D/32, HID/32, 1), tb, 0, stream>>>(fc2_w, fc2T, HID, D);
  transpose_k<<<dim3(3*D/32, D/32, 1), tb, 0, stream>>>(qkv_wb, qkvbT, D, 3*D);
  transpose_k<<<dim3(D/32, D/32, 1),   tb, 0, stream>>>(proj_wb, projbT, D, D);
  transpose_k<<<dim3(D/32, D/32, 8),   tb, 0, stream>>>(head_w, headT, D, D);
  if (batched) {
    transpose_k<<<dim3(HID/32, D/32, 8), tb, 0, stream>>>(w1, w1T8, D, HID);
    transpose_k<<<dim3(D/32, HID/32, 8), tb, 0, stream>>>(w2, w2T8, HID, D);
  }

  const int nTok = Ttok * D;
  hipMemcpyAsync(xf, x, (size_t)nTok * 4, hipMemcpyDeviceToDevice, stream);
  hipMemsetAsync(rt, 0, 64, stream);   // zero the 16 routing counters
  mask_k<<<(Ttok + 255)/256, 256, 0, stream>>>(shared_masks, agg_mask, cnt, rt, Ttok);
  hipMemsetAsync(out, 0, (size_t)nTok * 4, stream);  // head accumulation buffer

  const int lnGrid = (Ttok + 3) / 4;
  dim3 g_qkv(3*D/128, 13, 1);
  dim3 g_proj(D/128, 13, 4);    // split-K x4
  dim3 g_fc1(HID/128, 13, 1);
  dim3 g_fc2(D/128, 13, 4);     // split-K x4
  dim3 g_head(D/128, 13, 8);    // z = task (routed: blocks past count[t] exit)
  const int attnGrid = 96 * 4;  // (b,h) x 4 row-chunks

  // ---- dense ViT block ----
  ln_k<<<lnGrid, 256, 0, stream>>>(xf, ln1a_w, ln1a_b, lnb, Ttok);
  gemm_bt<EPI_STORE><<<g_qkv, 256, 0, stream>>>(lnb, qkvaT, qkv_ba, Ttok, 3*D, D, 1, 0, 0, 0, 0, 0, qkvb, nullptr, nullptr, nullptr);
  attn_mfma_k<<<attnGrid, 256, 0, stream>>>(qkvb, attnb);
  gemm_bt<EPI_RESADD><<<g_proj, 256, 0, stream>>>(attnb, projaT, proj_ba, Ttok, D, D, 4, 0, 0, 0, 0, 0, nullptr, xf, nullptr, nullptr);
  ln_k<<<lnGrid, 256, 0, stream>>>(xf, ln2a_w, ln2a_b, lnb, Ttok);
  gemm_bt<EPI_GELU><<<g_fc1, 256, 0, stream>>>(lnb, fc1T, fc1_b, Ttok, HID, D, 1, 0, 0, 0, 0, 0, h1, nullptr, nullptr, nullptr);
  gemm_bt<EPI_RESADD><<<g_fc2, 256, 0, stream>>>(h1, fc2T, fc2_b, Ttok, D, HID, 4, 0, 0, 0, 0, 0, nullptr, xf, nullptr, nullptr);

  // ---- MoE ViT block ----
  ln_k<<<lnGrid, 256, 0, stream>>>(xf, ln1b_w, ln1b_b, lnb, Ttok);
  gemm_bt<EPI_STORE><<<g_qkv, 256, 0, stream>>>(lnb, qkvbT, qkv_bb, Ttok, 3*D, D, 1, 0, 0, 0, 0, 0, qkvb, nullptr, nullptr, nullptr);
  attn_mfma_k<<<attnGrid, 256, 0, stream>>>(qkvb, attnb);
  gemm_bt<EPI_RESADD><<<g_proj, 256, 0, stream>>>(attnb, projbT, proj_bb, Ttok, D, D, 4, 0, 0, 0, 0, 0, nullptr, xf, nullptr, nullptr);
  // gate_k writes combine + routing lists + lnb (merged ln2b)
  gate_k<<<lnGrid, 256, 0, stream>>>(xf, ln2b_w, ln2b_b, gate_w, combine, rt, smap, lnb, Ttok);
  prefix_k<<<1, 64, 0, stream>>>(rt);
  if (batched) {
    // routed: only selected (token,expert) pairs computed — 4/8 of dense work.
    gemm_bt<EPI_GELU_R><<<dim3(HID/128, 13, 8), 256, 0, stream>>>(
        lnb, w1T8, b1, Ttok, HID, D, 1, 0,
        (long long)D*HID, HID, 0, (long long)Ttok*HID, h1_8, nullptr, nullptr, rt);
    // FC2: split-K=2, plain fp32 stores into compact slot buffer (no atomics)
    gemm_bt<EPI_MOEP><<<dim3(D/128, 13, 16), 256, 0, stream>>>(
        h1_8, w2T8, b2, Ttok, D, HID, 2, 0,
        (long long)HID*D, D, (long long)Ttok*HID, (long long)CAP*D, nullptr, yb, nullptr, rt);
    combine_k<<<lnGrid, 256, 0, stream>>>(yb, combine, rt, smap, xf, Ttok, CAP);
  } else {
    for (int e = 0; e < 8; ++e) {
      transpose_k<<<dim3(HID/32, D/32, 1), tb, 0, stream>>>(w1 + (size_t)e*D*HID, wT, D, HID);
      gemm_bt<EPI_GELU><<<g_fc1, 256, 0, stream>>>(lnb, wT, b1 + (size_t)e*HID, Ttok, HID, D, 1, 0, 0, 0, 0, 0, h1, nullptr, nullptr, nullptr);
      transpose_k<<<dim3(D/32, HID/32, 1), tb, 0, stream>>>(w2 + (size_t)e*HID*D, wT, HID, D);
      gemm_bt<EPI_MOE><<<g_fc2, 256, 0, stream>>>(h1, wT, b2 + (size_t)e*D, Ttok, D, HID, 4, e, 0, 0, 0, 0, nullptr, xf, combine, nullptr);
    }
  }

  // ---- per-task heads + masked aggregation (routed: ~25% of token-task pairs) ----
  f2b_k<<<(nTok + 255)/256, 256, 0, stream>>>(xf, lnb, nTok);
  gemm_bt<EPI_HEAD_R><<<g_head, 256, 0, stream>>>(lnb, headT, head_b, Ttok, D, D, 1, 0, (long long)D*D, D, 0, 0, nullptr, out, nullptr, rt);
  final_k<<<(nTok + 255)/256, 256, 0, stream>>>(out, cnt, nTok);
}

// Round 4
// 834.307 us; speedup vs baseline: 1.1474x; 1.0430x over previous
//
#include <hip/hip_runtime.h>
#include <hip/hip_bf16.h>

#define DEV static __device__ __forceinline__

typedef short bfx8 __attribute__((ext_vector_type(8)));   // 8 bf16 in 4 VGPRs (guide §3)
typedef float fx4  __attribute__((ext_vector_type(4)));

DEV float bf2f(__hip_bfloat16 h) { return __bfloat162float(h); }
DEV __hip_bfloat16 f2bf(float f) { return __float2bfloat16(f); }
DEV float uLO(unsigned u) { return __uint_as_float(u << 16); }
DEV unsigned short f2bfu(float f) { __hip_bfloat16 h = __float2bfloat16(f); return *(unsigned short*)&h; }

DEV float wave_sum(float v) {
#pragma unroll
  for (int o = 32; o; o >>= 1) v += __shfl_xor(v, o, 64);
  return v;
}

#define GLD_LDS16(gp, lp) __builtin_amdgcn_global_load_lds( \
    (__attribute__((address_space(1))) void*)(gp),          \
    (__attribute__((address_space(3))) void*)(lp), 16, 0, 0)

// -------- fused transpose+convert: all weight matrices in ONE dispatch ------
// Each desc: src fp32 [R][C] -> dst bf16 [C][R], nz batches.
struct TDesc { const float* src; __hip_bfloat16* dst; int R, C, nz, tilesPerZ, tileOff; };
struct TPack { TDesc d[9]; int n; };

__global__ __launch_bounds__(256) void transpose_all_k(TPack p) {
  __shared__ float tile[32][33];
  const int bid = blockIdx.x;
  int di = 0;
#pragma unroll
  for (int i = 1; i < 9; ++i)
    if (i < p.n && bid >= p.d[i].tileOff) di = i;
  const TDesc d = p.d[di];
  int local = bid - d.tileOff;
  int z = local / d.tilesPerZ;
  int rem = local - z * d.tilesPerZ;
  int ctiles = d.C >> 5;
  int bx = rem % ctiles, by = rem / ctiles;
  const float* src = d.src + (size_t)z * d.R * d.C;
  __hip_bfloat16* dst = d.dst + (size_t)z * d.R * d.C;
  int c0 = bx * 32, r0 = by * 32;
#pragma unroll
  for (int i = 0; i < 32; i += 8)
    tile[threadIdx.y + i][threadIdx.x] =
        src[(size_t)(r0 + threadIdx.y + i) * d.C + c0 + threadIdx.x];
  __syncthreads();
#pragma unroll
  for (int i = 0; i < 32; i += 8)
    dst[(size_t)(c0 + threadIdx.y + i) * d.R + r0 + threadIdx.x] =
        f2bf(tile[threadIdx.x][threadIdx.y + i]);
}

// single-matrix transpose (fallback path only)
__global__ __launch_bounds__(256) void transpose_k(
    const float* __restrict__ src, __hip_bfloat16* __restrict__ dst,
    int R, int C)
{
  __shared__ float tile[32][33];
  size_t off = (size_t)blockIdx.z * R * C;
  src += off; dst += off;
  int c0 = blockIdx.x * 32, r0 = blockIdx.y * 32;
#pragma unroll
  for (int i = 0; i < 32; i += 8)
    tile[threadIdx.y + i][threadIdx.x] =
        src[(size_t)(r0 + threadIdx.y + i) * C + c0 + threadIdx.x];
  __syncthreads();
#pragma unroll
  for (int i = 0; i < 32; i += 8)
    dst[(size_t)(c0 + threadIdx.y + i) * R + r0 + threadIdx.x] =
        f2bf(tile[threadIdx.x][threadIdx.y + i]);
}

// ---------------- GEMM: C = A[M,K] x B  (B given transposed: BT[N,K]) ------
// 128x128 tile, 4 waves, each wave 64x64 via 4x4 mfma_f32_16x16x32_bf16.
// 2-phase double-buffered K-loop: prefetch tile t+1 (global_load_lds) BEFORE
// ds_read+MFMA on tile t; one barrier per iteration (T3-min, guide §5.5).
// rt layout: [0..7] expert counts, [8..15] task counts, [16..23] expert bases,
//            [24 .. 24+8T) expert token lists, [24+8T .. 24+16T) task lists.
enum { EPI_STORE = 0, EPI_GELU = 1, EPI_RESADD = 2, EPI_MOE = 3,
       EPI_GELU_R = 4, EPI_MOEP = 5, EPI_HEAD_R = 6 };

template <int MODE>
__global__ __launch_bounds__(256) void gemm_bt(
    const __hip_bfloat16* __restrict__ A,    // [M,K]  (+ zt*strideAz)
    const __hip_bfloat16* __restrict__ BT,   // [zt][N,K]
    const float* __restrict__ bias,          // [zt][N] fp32
    int M, int N, int K, int splitK, int taskBase,
    long long strideBz, long long strideBiasz, long long strideAz, long long strideCz,
    __hip_bfloat16* __restrict__ Cb, float* __restrict__ Cf,
    const float* __restrict__ combine, const int* __restrict__ rt)
{
  constexpr bool ROUTED = (MODE == EPI_GELU_R || MODE == EPI_MOEP || MODE == EPI_HEAD_R);
  constexpr bool GATHER = (MODE == EPI_GELU_R || MODE == EPI_HEAD_R);
  __shared__ __hip_bfloat16 sA[2][128 * 32];  // [buf][m][k]
  __shared__ __hip_bfloat16 sB[2][128 * 32];  // [buf][n][k]
  const int tid = threadIdx.x;
  const int wave = tid >> 6, lane = tid & 63;
  const int quad = lane >> 4, l16 = lane & 15;
  const int z = blockIdx.z;
  const int zt = z / splitK;
  const int kc = z - zt * splitK;
  const int task = taskBase + zt;
  const int Ksub = K / splitK;
  const int kbeg = kc * Ksub;
  const int m0 = blockIdx.y * 128, n0 = blockIdx.x * 128;

  int Meff = M;
  int rtb = 0;
  const int* ilist = nullptr;
  if (ROUTED) {
    const int base = (MODE == EPI_HEAD_R) ? 8 : 0;
    Meff = rt[base + zt];
    ilist = rt + 24 + (size_t)base * M + (size_t)zt * M;
    if (MODE == EPI_MOEP) rtb = rt[16 + zt];   // compact output base for expert
    if (m0 >= Meff) return;   // whole block exits together, before any barrier
  }

  A += (size_t)zt * strideAz;
  if (MODE != EPI_MOEP) Cb += (size_t)zt * strideCz;
  const __hip_bfloat16* Bz = BT + (size_t)zt * strideBz;
  const float* biasz = bias + (size_t)zt * strideBiasz;
  const int wm = (wave >> 1) * 64, wn = (wave & 1) * 64;

  fx4 acc[4][4];
#pragma unroll
  for (int i = 0; i < 4; ++i)
#pragma unroll
    for (int j = 0; j < 4; ++j) acc[i][j] = (fx4){0.f, 0.f, 0.f, 0.f};

  // staging: chunk c covers row c>>2, k-seg (c&3)*8 ; LDS dest = c*8 elems
  // (wave-uniform base + lane*16B — matches m104/m108 constraint)
  const int c0 = tid, c1 = tid + 256;
  const int mlim = Meff - 1;
  int gm0 = m0 + (c0 >> 2); if (gm0 > mlim) gm0 = mlim;
  int gm1 = m0 + (c1 >> 2); if (gm1 > mlim) gm1 = mlim;
  const int ar0 = GATHER ? ilist[gm0] : gm0;
  const int ar1 = GATHER ? ilist[gm1] : gm1;
  const int ak0 = (c0 & 3) * 8, ak1 = (c1 & 3) * 8;
  const __hip_bfloat16* pa0 = A + (size_t)ar0 * K + kbeg + ak0;
  const __hip_bfloat16* pa1 = A + (size_t)ar1 * K + kbeg + ak1;
  const __hip_bfloat16* pb0 = Bz + (size_t)(n0 + (c0 >> 2)) * K + kbeg + ak0;
  const __hip_bfloat16* pb1 = Bz + (size_t)(n0 + (c1 >> 2)) * K + kbeg + ak1;

  // prologue: stage tile 0 into buf 0
  GLD_LDS16(pa0, &sA[0][c0 * 8]);
  GLD_LDS16(pa1, &sA[0][c1 * 8]);
  GLD_LDS16(pb0, &sB[0][c0 * 8]);
  GLD_LDS16(pb1, &sB[0][c1 * 8]);
  __syncthreads();   // drains vmcnt -> LDS writes visible

  int cur = 0;
  for (int kk = 0; kk < Ksub; kk += 32) {
    const int nxt = kk + 32;
    if (nxt < Ksub) {          // prefetch t+1 into the other buffer
      GLD_LDS16(pa0 + nxt, &sA[cur ^ 1][c0 * 8]);
      GLD_LDS16(pa1 + nxt, &sA[cur ^ 1][c1 * 8]);
      GLD_LDS16(pb0 + nxt, &sB[cur ^ 1][c0 * 8]);
      GLD_LDS16(pb1 + nxt, &sB[cur ^ 1][c1 * 8]);
    }
    bfx8 af[4], bfr[4];
#pragma unroll
    for (int i = 0; i < 4; ++i)
      af[i] = *(const bfx8*)(&sA[cur][(wm + i * 16 + l16) * 32 + quad * 8]);
#pragma unroll
    for (int j = 0; j < 4; ++j)
      bfr[j] = *(const bfx8*)(&sB[cur][(wn + j * 16 + l16) * 32 + quad * 8]);
#pragma unroll
    for (int i = 0; i < 4; ++i)
#pragma unroll
      for (int j = 0; j < 4; ++j)
        acc[i][j] = __builtin_amdgcn_mfma_f32_16x16x32_bf16(af[i], bfr[j], acc[i][j], 0, 0, 0);
    __syncthreads();  // vmcnt(0)+barrier: t+1 visible, buf[cur] free for reuse
    cur ^= 1;
  }

  // epilogue: C/D layout col=lane&15, row=quad*4+reg (m89-verified)
  const int mb = m0 + wm + quad * 4;
  const int nb = n0 + wn + l16;
#pragma unroll
  for (int i = 0; i < 4; ++i) {
#pragma unroll
    for (int rr = 0; rr < 4; ++rr) {
      const int m = mb + i * 16 + rr;
      if (m >= Meff) continue;
      int orow = m;
      if (MODE == EPI_HEAD_R) orow = ilist[m];
#pragma unroll
      for (int j = 0; j < 4; ++j) {
        const int n = nb + j * 16;
        float v = acc[i][j][rr];
        if (MODE == EPI_STORE) {
          Cb[(size_t)m * N + n] = f2bf(v + biasz[n]);
        } else if (MODE == EPI_GELU || MODE == EPI_GELU_R) {
          float t = v + biasz[n];
          Cb[(size_t)m * N + n] = f2bf(0.5f * t * (1.f + erff(t * 0.70710678118654752f)));
        } else if (MODE == EPI_RESADD) {
          if (kc == 0) v += biasz[n];
          atomicAdd(&Cf[(size_t)m * N + n], v);
        } else if (MODE == EPI_MOE) {
          float s = combine[m * 8 + task];
          if (s != 0.f) {
            if (kc == 0) v += biasz[n];
            atomicAdd(&Cf[(size_t)m * N + n], s * v);
          }
        } else if (MODE == EPI_MOEP) {
          // plain fp32 store of split-K partial into compact slot buffer
          if (kc == 0) v += biasz[n];
          Cf[(size_t)kc * strideCz + (size_t)(rtb + m) * N + n] = v;
        } else {  // EPI_HEAD_R
          atomicAdd(&Cf[(size_t)orow * N + n], v + biasz[n]);
        }
      }
    }
  }
}

// ---------------- MFMA attention ------------------------------------------
__global__ __launch_bounds__(256) void attn_mfma_k(
    const __hip_bfloat16* __restrict__ qkvb, __hip_bfloat16* __restrict__ outb)
{
  __shared__ __align__(16) unsigned short VT[64 * 232];       // V^T [d][tok], stride 232
  __shared__ __align__(16) unsigned short Pst[4][16 * 232];   // per-wave P strip [m][tok]
  const int tid = threadIdx.x;
  const int chunk = blockIdx.x & 3;
  const int bh = blockIdx.x >> 2;
  const int b = bh / 12, h = bh - b * 12;
  const size_t tokBase = (size_t)b * 197;
  const __hip_bfloat16* qkvh = qkvb + tokBase * 2304 + (size_t)h * 64;

  // stage V^T (which=2 -> +1536)
  for (int idx = tid; idx < 197 * 32; idx += 256) {
    int j = idx >> 5, dp = idx & 31;
    unsigned pv = *(const unsigned*)(qkvh + (size_t)j * 2304 + 1536 + dp * 2);
    VT[(2 * dp) * 232 + j]     = (unsigned short)(pv & 0xffffu);
    VT[(2 * dp + 1) * 232 + j] = (unsigned short)(pv >> 16);
  }
  // NaN fix: zero VT pad cols [197,232).
  for (int idx = tid; idx < 64 * 35; idx += 256) {
    int r = idx / 35, c = 197 + idx % 35;
    VT[r * 232 + c] = 0;
  }
  __syncthreads();

  const int wave = tid >> 6, lane = tid & 63;
  const int quad = lane >> 4, l16 = lane & 15;
  const int mt = chunk * 4 + wave;   // m-tile 0..12
  if (mt >= 13) return;

  // zero P strip pad cols [208,224)
  {
    int r = lane >> 2, c = 208 + (lane & 3) * 4;
    *(uint2*)&Pst[wave][r * 232 + c] = (uint2){0u, 0u};
  }

  // Q A-frags (clamped rows; invalid rows computed but never stored)
  int tq = mt * 16 + l16; if (tq > 196) tq = 196;
  const bfx8 af0 = *(const bfx8*)(qkvh + (size_t)tq * 2304 + quad * 8);
  const bfx8 af1 = *(const bfx8*)(qkvh + (size_t)tq * 2304 + 32 + quad * 8);

  // S strip: 13 n-tiles, K frags from global (which=1 -> +768)
  fx4 sv[13];
#pragma unroll
  for (int n0 = 0; n0 < 13; ++n0) {
    int tk = n0 * 16 + l16; if (tk > 196) tk = 196;
    const __hip_bfloat16* kp = qkvh + (size_t)tk * 2304 + 768;
    bfx8 bf0 = *(const bfx8*)(kp + quad * 8);
    bfx8 bf1 = *(const bfx8*)(kp + 32 + quad * 8);
    fx4 a = (fx4){0.f, 0.f, 0.f, 0.f};
    a = __builtin_amdgcn_mfma_f32_16x16x32_bf16(af0, bf0, a, 0, 0, 0);
    a = __builtin_amdgcn_mfma_f32_16x16x32_bf16(af1, bf1, a, 0, 0, 0);
    sv[n0] = a;
  }

  // softmax per row (row = quad*4+rr); cols of lane: n0*16+l16
  float inv[4];
#pragma unroll
  for (int rr = 0; rr < 4; ++rr) {
    float mx = -3.0e38f;
#pragma unroll
    for (int n0 = 0; n0 < 13; ++n0) {
      bool ok = (n0 < 12) | (l16 < 5);           // col < 197
      float s = ok ? sv[n0][rr] * 0.125f : -3.0e38f;
      sv[n0][rr] = s;
      mx = fmaxf(mx, s);
    }
#pragma unroll
    for (int o = 1; o < 16; o <<= 1) mx = fmaxf(mx, __shfl_xor(mx, o, 64));
    float sum = 0.f;
#pragma unroll
    for (int n0 = 0; n0 < 13; ++n0) {
      float s = sv[n0][rr];
      float e = (s > -1.0e38f) ? __expf(s - mx) : 0.f;
      sv[n0][rr] = e;
      sum += e;
    }
#pragma unroll
    for (int o = 1; o < 16; o <<= 1) sum += __shfl_xor(sum, o, 64);
    inv[rr] = 1.f / sum;
    const int row = quad * 4 + rr;
#pragma unroll
    for (int n0 = 0; n0 < 13; ++n0)
      Pst[wave][row * 232 + n0 * 16 + l16] = f2bfu(sv[n0][rr]);   // P hi
  }

  // PV pass 1 (P hi)
  fx4 pv[4];
#pragma unroll
  for (int nd = 0; nd < 4; ++nd) pv[nd] = (fx4){0.f, 0.f, 0.f, 0.f};
#pragma unroll
  for (int kk = 0; kk < 7; ++kk) {
    bfx8 paf = *(const bfx8*)&Pst[wave][l16 * 232 + kk * 32 + quad * 8];
#pragma unroll
    for (int nd = 0; nd < 4; ++nd) {
      bfx8 bfv = *(const bfx8*)&VT[(nd * 16 + l16) * 232 + kk * 32 + quad * 8];
      pv[nd] = __builtin_amdgcn_mfma_f32_16x16x32_bf16(paf, bfv, pv[nd], 0, 0, 0);
    }
  }

  // P lo = e - bf16(e), overwrite same strip (same-wave ordering -> safe)
#pragma unroll
  for (int rr = 0; rr < 4; ++rr) {
    const int row = quad * 4 + rr;
#pragma unroll
    for (int n0 = 0; n0 < 13; ++n0) {
      float e = sv[n0][rr];
      Pst[wave][row * 232 + n0 * 16 + l16] = f2bfu(e - uLO(f2bfu(e)));
    }
  }

  // PV pass 2 (P lo) accumulates
#pragma unroll
  for (int kk = 0; kk < 7; ++kk) {
    bfx8 paf = *(const bfx8*)&Pst[wave][l16 * 232 + kk * 32 + quad * 8];
#pragma unroll
    for (int nd = 0; nd < 4; ++nd) {
      bfx8 bfv = *(const bfx8*)&VT[(nd * 16 + l16) * 232 + kk * 32 + quad * 8];
      pv[nd] = __builtin_amdgcn_mfma_f32_16x16x32_bf16(paf, bfv, pv[nd], 0, 0, 0);
    }
  }

  // store: row m = mt*16 + quad*4 + rr, col d = nd*16 + l16
#pragma unroll
  for (int rr = 0; rr < 4; ++rr) {
    int m = mt * 16 + quad * 4 + rr;
    if (m > 196) continue;
    __hip_bfloat16* op = outb + (tokBase + m) * 768 + (size_t)h * 64;
#pragma unroll
    for (int nd = 0; nd < 4; ++nd)
      op[nd * 16 + l16] = f2bf(pv[nd][rr] * inv[rr]);
  }
}

// ---------------- LayerNorm: one wave per token, fp32 in -> bf16 out -------
__global__ __launch_bounds__(256) void ln_k(
    const float* __restrict__ xf, const float* __restrict__ w,
    const float* __restrict__ b, __hip_bfloat16* __restrict__ out, int T)
{
  int wv = threadIdx.x >> 6, lane = threadIdx.x & 63;
  int t = blockIdx.x * 4 + wv;
  if (t >= T) return;
  const float* row = xf + (size_t)t * 768;
  float v[12]; float s = 0.f;
#pragma unroll
  for (int i = 0; i < 12; ++i) { v[i] = row[lane + i * 64]; s += v[i]; }
  s = wave_sum(s);
  float mean = s * (1.f / 768.f);
  float q = 0.f;
#pragma unroll
  for (int i = 0; i < 12; ++i) { float d = v[i] - mean; q += d * d; }
  q = wave_sum(q);
  float rstd = rsqrtf(q * (1.f / 768.f) + 1e-5f);
#pragma unroll
  for (int i = 0; i < 12; ++i) {
    int d = lane + i * 64;
    out[(size_t)t * 768 + d] = f2bf((v[i] - mean) * rstd * w[d] + b[d]);
  }
}

// ---------------- MoE gating: fp32 LN + logits + softmax + top-4 ----------
// Also writes lnb (merged ln2b), appends token t to selected experts' lists.
__global__ __launch_bounds__(256) void gate_k(
    const float* __restrict__ xf, const float* __restrict__ lw,
    const float* __restrict__ lb, const float* __restrict__ gw,
    float* __restrict__ combine, int* __restrict__ rt, int* __restrict__ smap,
    __hip_bfloat16* __restrict__ lnbout, int T)
{
  int wv = threadIdx.x >> 6, lane = threadIdx.x & 63;
  int t = blockIdx.x * 4 + wv;
  if (t >= T) return;
  const float* row = xf + (size_t)t * 768;
  float v[12]; float s = 0.f;
#pragma unroll
  for (int i = 0; i < 12; ++i) { v[i] = row[lane + i * 64]; s += v[i]; }
  s = wave_sum(s);
  float mean = s * (1.f / 768.f);
  float qv = 0.f;
#pragma unroll
  for (int i = 0; i < 12; ++i) { float d = v[i] - mean; qv += d * d; }
  qv = wave_sum(qv);
  float rstd = rsqrtf(qv * (1.f / 768.f) + 1e-5f);
  float acc[8];
#pragma unroll
  for (int e = 0; e < 8; ++e) acc[e] = 0.f;
#pragma unroll
  for (int i = 0; i < 12; ++i) {
    int d = lane + i * 64;
    float xn = (v[i] - mean) * rstd * lw[d] + lb[d];
    lnbout[(size_t)t * 768 + d] = f2bf(xn);   // merged ln2b output
    float4 g0 = *(const float4*)(gw + (size_t)d * 8);
    float4 g1 = *(const float4*)(gw + (size_t)d * 8 + 4);
    acc[0] += xn * g0.x; acc[1] += xn * g0.y;
    acc[2] += xn * g0.z; acc[3] += xn * g0.w;
    acc[4] += xn * g1.x; acc[5] += xn * g1.y;
    acc[6] += xn * g1.z; acc[7] += xn * g1.w;
  }
#pragma unroll
  for (int e = 0; e < 8; ++e) acc[e] = wave_sum(acc[e]);
  float mx = acc[0];
#pragma unroll
  for (int e = 1; e < 8; ++e) mx = fmaxf(mx, acc[e]);
  float p[8]; float se = 0.f;
#pragma unroll
  for (int e = 0; e < 8; ++e) { p[e] = __expf(acc[e] - mx); se += p[e]; }
  float inv = 1.f / se;
#pragma unroll
  for (int e = 0; e < 8; ++e) p[e] *= inv;
  float outv[8]; bool used[8];
#pragma unroll
  for (int e = 0; e < 8; ++e) { outv[e] = 0.f; used[e] = false; }
  for (int k = 0; k < 4; ++k) {   // top-4, ties -> lowest index (matches top_k)
    int best = -1; float bv = -1.f;
#pragma unroll
    for (int e = 0; e < 8; ++e) if (!used[e] && p[e] > bv) { bv = p[e]; best = e; }
#pragma unroll
    for (int e = 0; e < 8; ++e) if (e == best) { used[e] = true; outv[e] = bv; }
  }
#pragma unroll
  for (int e = 0; e < 8; ++e) if (lane == e) combine[(size_t)t * 8 + e] = outv[e];
#pragma unroll
  for (int e = 0; e < 8; ++e)
    if (lane == e && outv[e] != 0.f) {
      int slot = atomicAdd(&rt[e], 1);
      rt[24 + e * T + slot] = t;
      smap[(size_t)t * 8 + e] = slot;
    }
}

// exclusive prefix of the 8 expert counts -> compact slot bases rt[16..23]
__global__ void prefix_k(int* __restrict__ rt) {
  if (threadIdx.x == 0) {
    int s = 0;
#pragma unroll
    for (int e = 0; e < 8; ++e) { rt[16 + e] = s; s += rt[e]; }
  }
}

// per-token MoE combine: xf[t] += sum_e s_e*(y0+y1); also writes bf16 lnb
__global__ __launch_bounds__(256) void combine_k(
    const float* __restrict__ y, const float* __restrict__ combine,
    const int* __restrict__ rt, const int* __restrict__ smap,
    float* __restrict__ xf, __hip_bfloat16* __restrict__ lnbout, int T, int CAP)
{
  int wv = threadIdx.x >> 6, lane = threadIdx.x & 63;
  int t = blockIdx.x * 4 + wv;
  if (t >= T) return;
  float acc[12];
#pragma unroll
  for (int i = 0; i < 12; ++i) acc[i] = 0.f;
  for (int e = 0; e < 8; ++e) {
    float s = combine[(size_t)t * 8 + e];
    if (s != 0.f) {                       // wave-uniform branch
      int r = rt[16 + e] + smap[(size_t)t * 8 + e];
      const float* y0 = y + (size_t)r * 768;
      const float* y1 = y0 + (size_t)CAP * 768;
#pragma unroll
      for (int i = 0; i < 12; ++i)
        acc[i] += s * (y0[lane + i * 64] + y1[lane + i * 64]);
    }
  }
  float* xr = xf + (size_t)t * 768;
#pragma unroll
  for (int i = 0; i < 12; ++i) {
    float nv = xr[lane + i * 64] + acc[i];
    xr[lane + i * 64] = nv;
    lnbout[(size_t)t * 768 + lane + i * 64] = f2bf(nv);  // fused f2b for head GEMM
  }
}

// ---------------- masks / small utils --------------------------------------
__global__ void mask_k(const int* __restrict__ sm, const int* __restrict__ am,
                       float* __restrict__ cnt, int* __restrict__ rt, int T)
{
  int t = blockIdx.x * 256 + threadIdx.x;
  if (t >= T) return;
  int a = am[t] != 0;
  float c = 0.f;
#pragma unroll
  for (int tt = 0; tt < 8; ++tt) {
    int vv = (sm[tt * T + t] != 0) & a;
    if (vv) {
      int slot = atomicAdd(&rt[8 + tt], 1);
      rt[24 + 8 * T + tt * T + slot] = t;
    }
    c += (float)vv;
  }
  cnt[t] = c;
}

__global__ void f2b_k(const float* __restrict__ in, __hip_bfloat16* __restrict__ out, int n) {
  int i = blockIdx.x * 256 + threadIdx.x;
  if (i < n) out[i] = f2bf(in[i]);
}
// in-place: out[i] = out[i] / (cnt[i/768] + 1e-6)
__global__ void final_k(float* __restrict__ out, const float* __restrict__ cnt, int n) {
  int i = blockIdx.x * 256 + threadIdx.x;
  if (i < n) out[i] = out[i] / (cnt[i / 768] + 1e-6f);
}

// ---------------- host ------------------------------------------------------
extern "C" void kernel_launch(void* const* d_in, const int* in_sizes, int n_in,
                              void* d_out, int out_size, void* d_ws, size_t ws_size,
                              hipStream_t stream)
{
  (void)in_sizes; (void)n_in; (void)out_size;
  const int Ttok = 8 * 197;  // 1576
  const int D = 768, HID = 3072;
  const int CAP = 4 * Ttok;  // total routed (token,expert) pairs = top-4 exact

  const float* x       = (const float*)d_in[0];
  const float* ln1a_w  = (const float*)d_in[1];
  const float* ln1a_b  = (const float*)d_in[2];
  const float* qkv_wa  = (const float*)d_in[3];
  const float* qkv_ba  = (const float*)d_in[4];
  const float* proj_wa = (const float*)d_in[5];
  const float* proj_ba = (const float*)d_in[6];
  const float* ln2a_w  = (const float*)d_in[7];
  const float* ln2a_b  = (const float*)d_in[8];
  const float* fc1_w   = (const float*)d_in[9];
  const float* fc1_b   = (const float*)d_in[10];
  const float* fc2_w   = (const float*)d_in[11];
  const float* fc2_b   = (const float*)d_in[12];
  const float* ln1b_w  = (const float*)d_in[13];
  const float* ln1b_b  = (const float*)d_in[14];
  const float* qkv_wb  = (const float*)d_in[15];
  const float* qkv_bb  = (const float*)d_in[16];
  const float* proj_wb = (const float*)d_in[17];
  const float* proj_bb = (const float*)d_in[18];
  const float* ln2b_w  = (const float*)d_in[19];
  const float* ln2b_b  = (const float*)d_in[20];
  const float* gate_w  = (const float*)d_in[21];
  const float* w1      = (const float*)d_in[22];
  const float* b1      = (const float*)d_in[23];
  const float* w2      = (const float*)d_in[24];
  const float* b2      = (const float*)d_in[25];
  const float* head_w  = (const float*)d_in[26];
  const float* head_b  = (const float*)d_in[27];
  const int* shared_masks = (const int*)d_in[28];
  const int* agg_mask     = (const int*)d_in[29];
  float* out           = (float*)d_out;

  char* wsp = (char*)d_ws;
  auto alloc = [&](size_t bytes) { char* p = wsp; wsp += (bytes + 255) & ~(size_t)255; return p; };
  float* xf             = (float*)alloc((size_t)Ttok * D * 4);
  __hip_bfloat16* lnb   = (__hip_bfloat16*)alloc((size_t)Ttok * D * 2);
  __hip_bfloat16* qkvb  = (__hip_bfloat16*)alloc((size_t)Ttok * 3 * D * 2);
  __hip_bfloat16* attnb = (__hip_bfloat16*)alloc((size_t)Ttok * D * 2);
  __hip_bfloat16* h1    = (__hip_bfloat16*)alloc((size_t)Ttok * HID * 2);
  float* combine        = (float*)alloc((size_t)Ttok * 8 * 4);
  float* cnt            = (float*)alloc((size_t)Ttok * 4);
  int* rt               = (int*)alloc((size_t)(24 + 16 * Ttok) * 4);  // counts+bases+lists
  int* smap             = (int*)alloc((size_t)Ttok * 8 * 4);
  __hip_bfloat16* qkvaT = (__hip_bfloat16*)alloc((size_t)D * 3 * D * 2);
  __hip_bfloat16* projaT= (__hip_bfloat16*)alloc((size_t)D * D * 2);
  __hip_bfloat16* fc1T  = (__hip_bfloat16*)alloc((size_t)D * HID * 2);
  __hip_bfloat16* fc2T  = (__hip_bfloat16*)alloc((size_t)D * HID * 2);
  __hip_bfloat16* qkvbT = (__hip_bfloat16*)alloc((size_t)D * 3 * D * 2);
  __hip_bfloat16* projbT= (__hip_bfloat16*)alloc((size_t)D * D * 2);
  __hip_bfloat16* headT = (__hip_bfloat16*)alloc((size_t)8 * D * D * 2);
  __hip_bfloat16* wT    = (__hip_bfloat16*)alloc((size_t)D * HID * 2);

  // batched-MoE extra buffers (deterministic guard: ws_size constant per harness)
  const size_t used = (size_t)(wsp - (char*)d_ws);
  const size_t extraNeed = 2 * ((size_t)8 * D * HID * 2 + 255)        // w1T8 + w2T8
                         + ((size_t)8 * Ttok * HID * 2 + 255)         // h1_8
                         + (2 * (size_t)CAP * D * 4 + 255);           // y (2 split-K slices)
  const bool batched = (ws_size >= used + extraNeed);
  __hip_bfloat16* w1T8 = nullptr; __hip_bfloat16* w2T8 = nullptr; __hip_bfloat16* h1_8 = nullptr;
  float* yb = nullptr;
  if (batched) {
    w1T8 = (__hip_bfloat16*)alloc((size_t)8 * D * HID * 2);
    w2T8 = (__hip_bfloat16*)alloc((size_t)8 * D * HID * 2);
    h1_8 = (__hip_bfloat16*)alloc((size_t)8 * Ttok * HID * 2);
    yb   = (float*)alloc(2 * (size_t)CAP * D * 4);
  }

  dim3 tb(32, 8);
  if (batched) {
    // single fused transpose dispatch for all 9 weight matrices
    TPack p; int off = 0;
    auto addT = [&](int i, const float* s, __hip_bfloat16* dd, int R, int C, int nz) {
      int tpz = (R / 32) * (C / 32);
      p.d[i] = TDesc{s, dd, R, C, nz, tpz, off};
      off += tpz * nz;
    };
    addT(0, qkv_wa, qkvaT, D, 3 * D, 1);
    addT(1, proj_wa, projaT, D, D, 1);
    addT(2, fc1_w, fc1T, D, HID, 1);
    addT(3, fc2_w, fc2T, HID, D, 1);
    addT(4, qkv_wb, qkvbT, D, 3 * D, 1);
    addT(5, proj_wb, projbT, D, D, 1);
    addT(6, head_w, headT, D, D, 8);
    addT(7, w1, w1T8, D, HID, 8);
    addT(8, w2, w2T8, HID, D, 8);
    p.n = 9;
    transpose_all_k<<<off, tb, 0, stream>>>(p);
  } else {
    transpose_k<<<dim3(3*D/32, D/32, 1), tb, 0, stream>>>(qkv_wa, qkvaT, D, 3*D);
    transpose_k<<<dim3(D/32, D/32, 1),   tb, 0, stream>>>(proj_wa, projaT, D, D);
    transpose_k<<<dim3(HID/32, D/32, 1), tb, 0, stream>>>(fc1_w, fc1T, D, HID);
    transpose_k<<<dim3(D/32, HID/32, 1), tb, 0, stream>>>(fc2_w, fc2T, HID, D);
    transpose_k<<<dim3(3*D/32, D/32, 1), tb, 0, stream>>>(qkv_wb, qkvbT, D, 3*D);
    transpose_k<<<dim3(D/32, D/32, 1),   tb, 0, stream>>>(proj_wb, projbT, D, D);
    transpose_k<<<dim3(D/32, D/32, 8),   tb, 0, stream>>>(head_w, headT, D, D);
  }

  const int nTok = Ttok * D;
  hipMemcpyAsync(xf, x, (size_t)nTok * 4, hipMemcpyDeviceToDevice, stream);
  hipMemsetAsync(rt, 0, 64, stream);   // zero the 16 routing counters
  mask_k<<<(Ttok + 255)/256, 256, 0, stream>>>(shared_masks, agg_mask, cnt, rt, Ttok);
  hipMemsetAsync(out, 0, (size_t)nTok * 4, stream);  // head accumulation buffer

  const int lnGrid = (Ttok + 3) / 4;
  dim3 g_qkv(3*D/128, 13, 1);
  dim3 g_proj(D/128, 13, 4);    // split-K x4
  dim3 g_fc1(HID/128, 13, 1);
  dim3 g_fc2(D/128, 13, 4);     // split-K x4
  dim3 g_head(D/128, 13, 8);    // z = task (routed: blocks past count[t] exit)
  const int attnGrid = 96 * 4;  // (b,h) x 4 row-chunks

  // ---- dense ViT block ----
  ln_k<<<lnGrid, 256, 0, stream>>>(xf, ln1a_w, ln1a_b, lnb, Ttok);
  gemm_bt<EPI_STORE><<<g_qkv, 256, 0, stream>>>(lnb, qkvaT, qkv_ba, Ttok, 3*D, D, 1, 0, 0, 0, 0, 0, qkvb, nullptr, nullptr, nullptr);
  attn_mfma_k<<<attnGrid, 256, 0, stream>>>(qkvb, attnb);
  gemm_bt<EPI_RESADD><<<g_proj, 256, 0, stream>>>(attnb, projaT, proj_ba, Ttok, D, D, 4, 0, 0, 0, 0, 0, nullptr, xf, nullptr, nullptr);
  ln_k<<<lnGrid, 256, 0, stream>>>(xf, ln2a_w, ln2a_b, lnb, Ttok);
  gemm_bt<EPI_GELU><<<g_fc1, 256, 0, stream>>>(lnb, fc1T, fc1_b, Ttok, HID, D, 1, 0, 0, 0, 0, 0, h1, nullptr, nullptr, nullptr);
  gemm_bt<EPI_RESADD><<<g_fc2, 256, 0, stream>>>(h1, fc2T, fc2_b, Ttok, D, HID, 4, 0, 0, 0, 0, 0, nullptr, xf, nullptr, nullptr);

  // ---- MoE ViT block ----
  ln_k<<<lnGrid, 256, 0, stream>>>(xf, ln1b_w, ln1b_b, lnb, Ttok);
  gemm_bt<EPI_STORE><<<g_qkv, 256, 0, stream>>>(lnb, qkvbT, qkv_bb, Ttok, 3*D, D, 1, 0, 0, 0, 0, 0, qkvb, nullptr, nullptr, nullptr);
  attn_mfma_k<<<attnGrid, 256, 0, stream>>>(qkvb, attnb);
  gemm_bt<EPI_RESADD><<<g_proj, 256, 0, stream>>>(attnb, projbT, proj_bb, Ttok, D, D, 4, 0, 0, 0, 0, 0, nullptr, xf, nullptr, nullptr);
  // gate_k writes combine + routing lists + lnb (merged ln2b)
  gate_k<<<lnGrid, 256, 0, stream>>>(xf, ln2b_w, ln2b_b, gate_w, combine, rt, smap, lnb, Ttok);
  prefix_k<<<1, 64, 0, stream>>>(rt);
  if (batched) {
    // routed: only selected (token,expert) pairs computed — 4/8 of dense work.
    gemm_bt<EPI_GELU_R><<<dim3(HID/128, 13, 8), 256, 0, stream>>>(
        lnb, w1T8, b1, Ttok, HID, D, 1, 0,
        (long long)D*HID, HID, 0, (long long)Ttok*HID, h1_8, nullptr, nullptr, rt);
    // FC2: split-K=2, plain fp32 stores into compact slot buffer (no atomics)
    gemm_bt<EPI_MOEP><<<dim3(D/128, 13, 16), 256, 0, stream>>>(
        h1_8, w2T8, b2, Ttok, D, HID, 2, 0,
        (long long)HID*D, D, (long long)Ttok*HID, (long long)CAP*D, nullptr, yb, nullptr, rt);
    combine_k<<<lnGrid, 256, 0, stream>>>(yb, combine, rt, smap, xf, lnb, Ttok, CAP);
  } else {
    for (int e = 0; e < 8; ++e) {
      transpose_k<<<dim3(HID/32, D/32, 1), tb, 0, stream>>>(w1 + (size_t)e*D*HID, wT, D, HID);
      gemm_bt<EPI_GELU><<<g_fc1, 256, 0, stream>>>(lnb, wT, b1 + (size_t)e*HID, Ttok, HID, D, 1, 0, 0, 0, 0, 0, h1, nullptr, nullptr, nullptr);
      transpose_k<<<dim3(D/32, HID/32, 1), tb, 0, stream>>>(w2 + (size_t)e*HID*D, wT, HID, D);
      gemm_bt<EPI_MOE><<<g_fc2, 256, 0, stream>>>(h1, wT, b2 + (size_t)e*D, Ttok, D, HID, 4, e, 0, 0, 0, 0, nullptr, xf, combine, nullptr);
    }
    f2b_k<<<(nTok + 255)/256, 256, 0, stream>>>(xf, lnb, nTok);
  }

  // ---- per-task heads + masked aggregation (routed: ~25% of token-task pairs) ----
  gemm_bt<EPI_HEAD_R><<<g_head, 256, 0, stream>>>(lnb, headT, head_b, Ttok, D, D, 1, 0, (long long)D*D, D, 0, 0, nullptr, out, nullptr, rt);
  final_k<<<(nTok + 255)/256, 256, 0, stream>>>(out, cnt, nTok);
}

// Round 5
// 816.065 us; speedup vs baseline: 1.1730x; 1.0224x over previous
//
#include <hip/hip_runtime.h>
#include <hip/hip_bf16.h>

#define DEV static __device__ __forceinline__

typedef short bfx8 __attribute__((ext_vector_type(8)));   // 8 bf16 in 4 VGPRs (guide §3)
typedef float fx4  __attribute__((ext_vector_type(4)));

DEV float bf2f(__hip_bfloat16 h) { return __bfloat162float(h); }
DEV __hip_bfloat16 f2bf(float f) { return __float2bfloat16(f); }
DEV float uLO(unsigned u) { return __uint_as_float(u << 16); }
DEV unsigned short f2bfu(float f) { __hip_bfloat16 h = __float2bfloat16(f); return *(unsigned short*)&h; }

DEV float wave_sum(float v) {
#pragma unroll
  for (int o = 32; o; o >>= 1) v += __shfl_xor(v, o, 64);
  return v;
}

#define GLD_LDS16(gp, lp) __builtin_amdgcn_global_load_lds( \
    (__attribute__((address_space(1))) void*)(gp),          \
    (__attribute__((address_space(3))) void*)(lp), 16, 0, 0)

// -------- fused transpose+convert: all weight matrices in ONE dispatch ------
// 64x64 tiles, float4 loads (256B runs), bf16 LDS stride-66 (write 2-way=free,
// gather-read 4-way=1.58x), short8 stores (16B/lane, 128B runs). All R,C %64==0.
struct TDesc { const float* src; __hip_bfloat16* dst; int R, C, nz, tilesPerZ, tileOff; };
struct TPack { TDesc d[9]; int n; };

__global__ __launch_bounds__(256) void transpose_all_k(TPack p) {
  __shared__ unsigned short t[64 * 66];   // [src_row r][src_col c], stride 66
  const int bid = blockIdx.x;
  int di = 0;
#pragma unroll
  for (int i = 1; i < 9; ++i)
    if (i < p.n && bid >= p.d[i].tileOff) di = i;
  const TDesc d = p.d[di];
  int local = bid - d.tileOff;
  int z = local / d.tilesPerZ;
  int rem = local - z * d.tilesPerZ;
  int ctiles = d.C >> 6;
  int bx = rem % ctiles, by = rem / ctiles;
  const float* src = d.src + (size_t)z * d.R * d.C;
  __hip_bfloat16* dst = d.dst + (size_t)z * d.R * d.C;
  int c0 = bx * 64, r0 = by * 64;
  const int tid = threadIdx.x;
  // load+convert: 64 rows x 16 float4 per row
#pragma unroll
  for (int it = 0; it < 4; ++it) {
    int idx = tid + it * 256;
    int row = idx >> 4, q = idx & 15;
    float4 v = *(const float4*)(src + (size_t)(r0 + row) * d.C + c0 + q * 4);
    ushort2 lo, hi;
    lo.x = f2bfu(v.x); lo.y = f2bfu(v.y);
    hi.x = f2bfu(v.z); hi.y = f2bfu(v.w);
    *(ushort2*)&t[row * 66 + q * 4]     = lo;
    *(ushort2*)&t[row * 66 + q * 4 + 2] = hi;
  }
  __syncthreads();
  // store: dst row (c0+oc) <- src col oc over r0..r0+63; 8 bf16 (16B) per thread
#pragma unroll
  for (int it = 0; it < 2; ++it) {
    int idx = tid + it * 256;     // 512 short8-units
    int oc = idx >> 3, q = idx & 7;
    bfx8 w;
#pragma unroll
    for (int j = 0; j < 8; ++j)
      w[j] = (short)t[(q * 8 + j) * 66 + oc];
    *(bfx8*)(dst + (size_t)(c0 + oc) * d.R + r0 + q * 8) = w;
  }
}

// single-matrix transpose (fallback path only)
__global__ __launch_bounds__(256) void transpose_k(
    const float* __restrict__ src, __hip_bfloat16* __restrict__ dst,
    int R, int C)
{
  __shared__ float tile[32][33];
  size_t off = (size_t)blockIdx.z * R * C;
  src += off; dst += off;
  int c0 = blockIdx.x * 32, r0 = blockIdx.y * 32;
#pragma unroll
  for (int i = 0; i < 32; i += 8)
    tile[threadIdx.y + i][threadIdx.x] =
        src[(size_t)(r0 + threadIdx.y + i) * C + c0 + threadIdx.x];
  __syncthreads();
#pragma unroll
  for (int i = 0; i < 32; i += 8)
    dst[(size_t)(c0 + threadIdx.y + i) * R + r0 + threadIdx.x] =
        f2bf(tile[threadIdx.x][threadIdx.y + i]);
}

// ---------------- GEMM: C = A[M,K] x B  (B given transposed: BT[N,K]) ------
// 128x128 tile, 4 waves, 4x4 mfma_f32_16x16x32_bf16, 2-phase dbuf K-loop.
// rt layout: [0..7] expert counts, [8..15] task counts, [16..23] expert bases,
// [24..31] task bases, [32 .. 32+8T) expert token lists, [32+8T ..) task lists.
enum { EPI_STORE = 0, EPI_GELU = 1, EPI_RESADD = 2, EPI_MOE = 3,
       EPI_GELU_R = 4, EPI_MOEP = 5, EPI_HEAD_R = 6, EPI_HEADP = 7 };

template <int MODE>
__global__ __launch_bounds__(256) void gemm_bt(
    const __hip_bfloat16* __restrict__ A,    // [M,K]  (+ zt*strideAz)
    const __hip_bfloat16* __restrict__ BT,   // [zt][N,K]
    const float* __restrict__ bias,          // [zt][N] fp32
    int M, int N, int K, int splitK, int taskBase,
    long long strideBz, long long strideBiasz, long long strideAz, long long strideCz,
    __hip_bfloat16* __restrict__ Cb, float* __restrict__ Cf,
    const float* __restrict__ combine, const int* __restrict__ rt)
{
  constexpr bool ROUTED = (MODE == EPI_GELU_R || MODE == EPI_MOEP ||
                           MODE == EPI_HEAD_R || MODE == EPI_HEADP);
  constexpr bool GATHER = (MODE == EPI_GELU_R || MODE == EPI_HEAD_R || MODE == EPI_HEADP);
  __shared__ __hip_bfloat16 sA[2][128 * 32];  // [buf][m][k]
  __shared__ __hip_bfloat16 sB[2][128 * 32];  // [buf][n][k]
  const int tid = threadIdx.x;
  const int wave = tid >> 6, lane = tid & 63;
  const int quad = lane >> 4, l16 = lane & 15;
  const int z = blockIdx.z;
  const int zt = z / splitK;
  const int kc = z - zt * splitK;
  const int task = taskBase + zt;
  const int Ksub = K / splitK;
  const int kbeg = kc * Ksub;
  const int m0 = blockIdx.y * 128, n0 = blockIdx.x * 128;

  int Meff = M;
  int rtb = 0;
  const int* ilist = nullptr;
  if (ROUTED) {
    const int base = (MODE == EPI_HEAD_R || MODE == EPI_HEADP) ? 8 : 0;
    Meff = rt[base + zt];
    ilist = rt + 32 + (size_t)base * M + (size_t)zt * M;
    if (MODE == EPI_MOEP) rtb = rt[16 + zt];   // compact expert output base
    if (MODE == EPI_HEADP) rtb = rt[24 + zt];  // compact task output base
    if (m0 >= Meff) return;   // whole block exits together, before any barrier
  }

  A += (size_t)zt * strideAz;
  if (MODE != EPI_MOEP && MODE != EPI_HEADP) Cb += (size_t)zt * strideCz;
  const __hip_bfloat16* Bz = BT + (size_t)zt * strideBz;
  const float* biasz = bias + (size_t)zt * strideBiasz;
  const int wm = (wave >> 1) * 64, wn = (wave & 1) * 64;

  fx4 acc[4][4];
#pragma unroll
  for (int i = 0; i < 4; ++i)
#pragma unroll
    for (int j = 0; j < 4; ++j) acc[i][j] = (fx4){0.f, 0.f, 0.f, 0.f};

  // staging: chunk c covers row c>>2, k-seg (c&3)*8 ; LDS dest = c*8 elems
  const int c0 = tid, c1 = tid + 256;
  const int mlim = Meff - 1;
  int gm0 = m0 + (c0 >> 2); if (gm0 > mlim) gm0 = mlim;
  int gm1 = m0 + (c1 >> 2); if (gm1 > mlim) gm1 = mlim;
  const int ar0 = GATHER ? ilist[gm0] : gm0;
  const int ar1 = GATHER ? ilist[gm1] : gm1;
  const int ak0 = (c0 & 3) * 8, ak1 = (c1 & 3) * 8;
  const __hip_bfloat16* pa0 = A + (size_t)ar0 * K + kbeg + ak0;
  const __hip_bfloat16* pa1 = A + (size_t)ar1 * K + kbeg + ak1;
  const __hip_bfloat16* pb0 = Bz + (size_t)(n0 + (c0 >> 2)) * K + kbeg + ak0;
  const __hip_bfloat16* pb1 = Bz + (size_t)(n0 + (c1 >> 2)) * K + kbeg + ak1;

  // prologue: stage tile 0 into buf 0
  GLD_LDS16(pa0, &sA[0][c0 * 8]);
  GLD_LDS16(pa1, &sA[0][c1 * 8]);
  GLD_LDS16(pb0, &sB[0][c0 * 8]);
  GLD_LDS16(pb1, &sB[0][c1 * 8]);
  __syncthreads();   // drains vmcnt -> LDS writes visible

  int cur = 0;
  for (int kk = 0; kk < Ksub; kk += 32) {
    const int nxt = kk + 32;
    if (nxt < Ksub) {          // prefetch t+1 into the other buffer
      GLD_LDS16(pa0 + nxt, &sA[cur ^ 1][c0 * 8]);
      GLD_LDS16(pa1 + nxt, &sA[cur ^ 1][c1 * 8]);
      GLD_LDS16(pb0 + nxt, &sB[cur ^ 1][c0 * 8]);
      GLD_LDS16(pb1 + nxt, &sB[cur ^ 1][c1 * 8]);
    }
    bfx8 af[4], bfr[4];
#pragma unroll
    for (int i = 0; i < 4; ++i)
      af[i] = *(const bfx8*)(&sA[cur][(wm + i * 16 + l16) * 32 + quad * 8]);
#pragma unroll
    for (int j = 0; j < 4; ++j)
      bfr[j] = *(const bfx8*)(&sB[cur][(wn + j * 16 + l16) * 32 + quad * 8]);
#pragma unroll
    for (int i = 0; i < 4; ++i)
#pragma unroll
      for (int j = 0; j < 4; ++j)
        acc[i][j] = __builtin_amdgcn_mfma_f32_16x16x32_bf16(af[i], bfr[j], acc[i][j], 0, 0, 0);
    __syncthreads();  // vmcnt(0)+barrier: t+1 visible, buf[cur] free for reuse
    cur ^= 1;
  }

  // epilogue: C/D layout col=lane&15, row=quad*4+reg (m89-verified)
  const int mb = m0 + wm + quad * 4;
  const int nb = n0 + wn + l16;
#pragma unroll
  for (int i = 0; i < 4; ++i) {
#pragma unroll
    for (int rr = 0; rr < 4; ++rr) {
      const int m = mb + i * 16 + rr;
      if (m >= Meff) continue;
      int orow = m;
      if (MODE == EPI_HEAD_R) orow = ilist[m];
#pragma unroll
      for (int j = 0; j < 4; ++j) {
        const int n = nb + j * 16;
        float v = acc[i][j][rr];
        if (MODE == EPI_STORE) {
          Cb[(size_t)m * N + n] = f2bf(v + biasz[n]);
        } else if (MODE == EPI_GELU || MODE == EPI_GELU_R) {
          float t = v + biasz[n];
          Cb[(size_t)m * N + n] = f2bf(0.5f * t * (1.f + erff(t * 0.70710678118654752f)));
        } else if (MODE == EPI_RESADD) {
          if (kc == 0) v += biasz[n];
          atomicAdd(&Cf[(size_t)m * N + n], v);
        } else if (MODE == EPI_MOE) {
          float s = combine[m * 8 + task];
          if (s != 0.f) {
            if (kc == 0) v += biasz[n];
            atomicAdd(&Cf[(size_t)m * N + n], s * v);
          }
        } else if (MODE == EPI_MOEP) {
          if (kc == 0) v += biasz[n];
          Cf[(size_t)kc * strideCz + (size_t)(rtb + m) * N + n] = v;
        } else if (MODE == EPI_HEADP) {
          Cf[(size_t)(rtb + m) * N + n] = v + biasz[n];   // plain store, no atomics
        } else {  // EPI_HEAD_R (fallback)
          atomicAdd(&Cf[(size_t)orow * N + n], v + biasz[n]);
        }
      }
    }
  }
}

// ---------------- MFMA attention ------------------------------------------
__global__ __launch_bounds__(256) void attn_mfma_k(
    const __hip_bfloat16* __restrict__ qkvb, __hip_bfloat16* __restrict__ outb)
{
  __shared__ __align__(16) unsigned short VT[64 * 232];       // V^T [d][tok], stride 232
  __shared__ __align__(16) unsigned short Pst[4][16 * 232];   // per-wave P strip [m][tok]
  const int tid = threadIdx.x;
  const int chunk = blockIdx.x & 3;
  const int bh = blockIdx.x >> 2;
  const int b = bh / 12, h = bh - b * 12;
  const size_t tokBase = (size_t)b * 197;
  const __hip_bfloat16* qkvh = qkvb + tokBase * 2304 + (size_t)h * 64;

  // stage V^T (which=2 -> +1536)
  for (int idx = tid; idx < 197 * 32; idx += 256) {
    int j = idx >> 5, dp = idx & 31;
    unsigned pv = *(const unsigned*)(qkvh + (size_t)j * 2304 + 1536 + dp * 2);
    VT[(2 * dp) * 232 + j]     = (unsigned short)(pv & 0xffffu);
    VT[(2 * dp + 1) * 232 + j] = (unsigned short)(pv >> 16);
  }
  // NaN fix: zero VT pad cols [197,232).
  for (int idx = tid; idx < 64 * 35; idx += 256) {
    int r = idx / 35, c = 197 + idx % 35;
    VT[r * 232 + c] = 0;
  }
  __syncthreads();

  const int wave = tid >> 6, lane = tid & 63;
  const int quad = lane >> 4, l16 = lane & 15;
  const int mt = chunk * 4 + wave;   // m-tile 0..12
  if (mt >= 13) return;

  // zero P strip pad cols [208,224)
  {
    int r = lane >> 2, c = 208 + (lane & 3) * 4;
    *(uint2*)&Pst[wave][r * 232 + c] = (uint2){0u, 0u};
  }

  // Q A-frags (clamped rows; invalid rows computed but never stored)
  int tq = mt * 16 + l16; if (tq > 196) tq = 196;
  const bfx8 af0 = *(const bfx8*)(qkvh + (size_t)tq * 2304 + quad * 8);
  const bfx8 af1 = *(const bfx8*)(qkvh + (size_t)tq * 2304 + 32 + quad * 8);

  // S strip: 13 n-tiles, K frags from global (which=1 -> +768)
  fx4 sv[13];
#pragma unroll
  for (int n0 = 0; n0 < 13; ++n0) {
    int tk = n0 * 16 + l16; if (tk > 196) tk = 196;
    const __hip_bfloat16* kp = qkvh + (size_t)tk * 2304 + 768;
    bfx8 bf0 = *(const bfx8*)(kp + quad * 8);
    bfx8 bf1 = *(const bfx8*)(kp + 32 + quad * 8);
    fx4 a = (fx4){0.f, 0.f, 0.f, 0.f};
    a = __builtin_amdgcn_mfma_f32_16x16x32_bf16(af0, bf0, a, 0, 0, 0);
    a = __builtin_amdgcn_mfma_f32_16x16x32_bf16(af1, bf1, a, 0, 0, 0);
    sv[n0] = a;
  }

  // softmax per row (row = quad*4+rr); cols of lane: n0*16+l16
  float inv[4];
#pragma unroll
  for (int rr = 0; rr < 4; ++rr) {
    float mx = -3.0e38f;
#pragma unroll
    for (int n0 = 0; n0 < 13; ++n0) {
      bool ok = (n0 < 12) | (l16 < 5);           // col < 197
      float s = ok ? sv[n0][rr] * 0.125f : -3.0e38f;
      sv[n0][rr] = s;
      mx = fmaxf(mx, s);
    }
#pragma unroll
    for (int o = 1; o < 16; o <<= 1) mx = fmaxf(mx, __shfl_xor(mx, o, 64));
    float sum = 0.f;
#pragma unroll
    for (int n0 = 0; n0 < 13; ++n0) {
      float s = sv[n0][rr];
      float e = (s > -1.0e38f) ? __expf(s - mx) : 0.f;
      sv[n0][rr] = e;
      sum += e;
    }
#pragma unroll
    for (int o = 1; o < 16; o <<= 1) sum += __shfl_xor(sum, o, 64);
    inv[rr] = 1.f / sum;
    const int row = quad * 4 + rr;
#pragma unroll
    for (int n0 = 0; n0 < 13; ++n0)
      Pst[wave][row * 232 + n0 * 16 + l16] = f2bfu(sv[n0][rr]);   // P hi
  }

  // PV pass 1 (P hi)
  fx4 pv[4];
#pragma unroll
  for (int nd = 0; nd < 4; ++nd) pv[nd] = (fx4){0.f, 0.f, 0.f, 0.f};
#pragma unroll
  for (int kk = 0; kk < 7; ++kk) {
    bfx8 paf = *(const bfx8*)&Pst[wave][l16 * 232 + kk * 32 + quad * 8];
#pragma unroll
    for (int nd = 0; nd < 4; ++nd) {
      bfx8 bfv = *(const bfx8*)&VT[(nd * 16 + l16) * 232 + kk * 32 + quad * 8];
      pv[nd] = __builtin_amdgcn_mfma_f32_16x16x32_bf16(paf, bfv, pv[nd], 0, 0, 0);
    }
  }

  // P lo = e - bf16(e), overwrite same strip (same-wave ordering -> safe)
#pragma unroll
  for (int rr = 0; rr < 4; ++rr) {
    const int row = quad * 4 + rr;
#pragma unroll
    for (int n0 = 0; n0 < 13; ++n0) {
      float e = sv[n0][rr];
      Pst[wave][row * 232 + n0 * 16 + l16] = f2bfu(e - uLO(f2bfu(e)));
    }
  }

  // PV pass 2 (P lo) accumulates
#pragma unroll
  for (int kk = 0; kk < 7; ++kk) {
    bfx8 paf = *(const bfx8*)&Pst[wave][l16 * 232 + kk * 32 + quad * 8];
#pragma unroll
    for (int nd = 0; nd < 4; ++nd) {
      bfx8 bfv = *(const bfx8*)&VT[(nd * 16 + l16) * 232 + kk * 32 + quad * 8];
      pv[nd] = __builtin_amdgcn_mfma_f32_16x16x32_bf16(paf, bfv, pv[nd], 0, 0, 0);
    }
  }

  // store: row m = mt*16 + quad*4 + rr, col d = nd*16 + l16
#pragma unroll
  for (int rr = 0; rr < 4; ++rr) {
    int m = mt * 16 + quad * 4 + rr;
    if (m > 196) continue;
    __hip_bfloat16* op = outb + (tokBase + m) * 768 + (size_t)h * 64;
#pragma unroll
    for (int nd = 0; nd < 4; ++nd)
      op[nd * 16 + l16] = f2bf(pv[nd][rr] * inv[rr]);
  }
}

// ---------------- LayerNorm: one wave per token, fp32 in -> bf16 out -------
__global__ __launch_bounds__(256) void ln_k(
    const float* __restrict__ xf, const float* __restrict__ w,
    const float* __restrict__ b, __hip_bfloat16* __restrict__ out, int T)
{
  int wv = threadIdx.x >> 6, lane = threadIdx.x & 63;
  int t = blockIdx.x * 4 + wv;
  if (t >= T) return;
  const float* row = xf + (size_t)t * 768;
  float v[12]; float s = 0.f;
#pragma unroll
  for (int i = 0; i < 12; ++i) { v[i] = row[lane + i * 64]; s += v[i]; }
  s = wave_sum(s);
  float mean = s * (1.f / 768.f);
  float q = 0.f;
#pragma unroll
  for (int i = 0; i < 12; ++i) { float d = v[i] - mean; q += d * d; }
  q = wave_sum(q);
  float rstd = rsqrtf(q * (1.f / 768.f) + 1e-5f);
#pragma unroll
  for (int i = 0; i < 12; ++i) {
    int d = lane + i * 64;
    out[(size_t)t * 768 + d] = f2bf((v[i] - mean) * rstd * w[d] + b[d]);
  }
}

// ---------------- MoE gating: fp32 LN + logits + softmax + top-4 ----------
__global__ __launch_bounds__(256) void gate_k(
    const float* __restrict__ xf, const float* __restrict__ lw,
    const float* __restrict__ lb, const float* __restrict__ gw,
    float* __restrict__ combine, int* __restrict__ rt, int* __restrict__ smap,
    __hip_bfloat16* __restrict__ lnbout, int T)
{
  int wv = threadIdx.x >> 6, lane = threadIdx.x & 63;
  int t = blockIdx.x * 4 + wv;
  if (t >= T) return;
  const float* row = xf + (size_t)t * 768;
  float v[12]; float s = 0.f;
#pragma unroll
  for (int i = 0; i < 12; ++i) { v[i] = row[lane + i * 64]; s += v[i]; }
  s = wave_sum(s);
  float mean = s * (1.f / 768.f);
  float qv = 0.f;
#pragma unroll
  for (int i = 0; i < 12; ++i) { float d = v[i] - mean; qv += d * d; }
  qv = wave_sum(qv);
  float rstd = rsqrtf(qv * (1.f / 768.f) + 1e-5f);
  float acc[8];
#pragma unroll
  for (int e = 0; e < 8; ++e) acc[e] = 0.f;
#pragma unroll
  for (int i = 0; i < 12; ++i) {
    int d = lane + i * 64;
    float xn = (v[i] - mean) * rstd * lw[d] + lb[d];
    lnbout[(size_t)t * 768 + d] = f2bf(xn);   // merged ln2b output
    float4 g0 = *(const float4*)(gw + (size_t)d * 8);
    float4 g1 = *(const float4*)(gw + (size_t)d * 8 + 4);
    acc[0] += xn * g0.x; acc[1] += xn * g0.y;
    acc[2] += xn * g0.z; acc[3] += xn * g0.w;
    acc[4] += xn * g1.x; acc[5] += xn * g1.y;
    acc[6] += xn * g1.z; acc[7] += xn * g1.w;
  }
#pragma unroll
  for (int e = 0; e < 8; ++e) acc[e] = wave_sum(acc[e]);
  float mx = acc[0];
#pragma unroll
  for (int e = 1; e < 8; ++e) mx = fmaxf(mx, acc[e]);
  float p[8]; float se = 0.f;
#pragma unroll
  for (int e = 0; e < 8; ++e) { p[e] = __expf(acc[e] - mx); se += p[e]; }
  float inv = 1.f / se;
#pragma unroll
  for (int e = 0; e < 8; ++e) p[e] *= inv;
  float outv[8]; bool used[8];
#pragma unroll
  for (int e = 0; e < 8; ++e) { outv[e] = 0.f; used[e] = false; }
  for (int k = 0; k < 4; ++k) {   // top-4, ties -> lowest index (matches top_k)
    int best = -1; float bv = -1.f;
#pragma unroll
    for (int e = 0; e < 8; ++e) if (!used[e] && p[e] > bv) { bv = p[e]; best = e; }
#pragma unroll
    for (int e = 0; e < 8; ++e) if (e == best) { used[e] = true; outv[e] = bv; }
  }
#pragma unroll
  for (int e = 0; e < 8; ++e) if (lane == e) combine[(size_t)t * 8 + e] = outv[e];
#pragma unroll
  for (int e = 0; e < 8; ++e)
    if (lane == e && outv[e] != 0.f) {
      int slot = atomicAdd(&rt[e], 1);
      rt[32 + e * T + slot] = t;
      smap[(size_t)t * 8 + e] = slot;
    }
}

// exclusive prefix of expert counts -> rt[16..23]; task counts -> rt[24..31]
__global__ void prefix_k(int* __restrict__ rt) {
  if (threadIdx.x == 0) {
    int s = 0;
#pragma unroll
    for (int e = 0; e < 8; ++e) { rt[16 + e] = s; s += rt[e]; }
    int s2 = 0;
#pragma unroll
    for (int tt = 0; tt < 8; ++tt) { rt[24 + tt] = s2; s2 += rt[8 + tt]; }
  }
}

// per-token MoE combine: xf[t] += sum_e s_e*(y0+y1); also writes bf16 lnb
__global__ __launch_bounds__(256) void combine_k(
    const float* __restrict__ y, const float* __restrict__ combine,
    const int* __restrict__ rt, const int* __restrict__ smap,
    float* __restrict__ xf, __hip_bfloat16* __restrict__ lnbout, int T, int CAP)
{
  int wv = threadIdx.x >> 6, lane = threadIdx.x & 63;
  int t = blockIdx.x * 4 + wv;
  if (t >= T) return;
  float acc[12];
#pragma unroll
  for (int i = 0; i < 12; ++i) acc[i] = 0.f;
  for (int e = 0; e < 8; ++e) {
    float s = combine[(size_t)t * 8 + e];
    if (s != 0.f) {                       // wave-uniform branch
      int r = rt[16 + e] + smap[(size_t)t * 8 + e];
      const float* y0 = y + (size_t)r * 768;
      const float* y1 = y0 + (size_t)CAP * 768;
#pragma unroll
      for (int i = 0; i < 12; ++i)
        acc[i] += s * (y0[lane + i * 64] + y1[lane + i * 64]);
    }
  }
  float* xr = xf + (size_t)t * 768;
#pragma unroll
  for (int i = 0; i < 12; ++i) {
    float nv = xr[lane + i * 64] + acc[i];
    xr[lane + i * 64] = nv;
    lnbout[(size_t)t * 768 + lane + i * 64] = f2bf(nv);  // fused f2b for head GEMM
  }
}

// ---------------- masks / small utils --------------------------------------
// Builds cnt, per-task token lists, per-token task-slot map, valid (fallback).
__global__ void mask_k(const int* __restrict__ sm, const int* __restrict__ am,
                       float* __restrict__ cnt, int* __restrict__ rt,
                       int* __restrict__ tsmap, int* __restrict__ valid, int T)
{
  int t = blockIdx.x * 256 + threadIdx.x;
  if (t >= T) return;
  int a = am[t] != 0;
  float c = 0.f;
#pragma unroll
  for (int tt = 0; tt < 8; ++tt) {
    int vv = (sm[tt * T + t] != 0) & a;
    valid[tt * T + t] = vv;
    int slot = -1;
    if (vv) {
      slot = atomicAdd(&rt[8 + tt], 1);
      rt[32 + 8 * T + tt * T + slot] = t;
    }
    tsmap[(size_t)t * 8 + tt] = slot;
    c += (float)vv;
  }
  cnt[t] = c;
}

__global__ void f2b_k(const float* __restrict__ in, __hip_bfloat16* __restrict__ out, int n) {
  int i = blockIdx.x * 256 + threadIdx.x;
  if (i < n) out[i] = f2bf(in[i]);
}
// fallback: out[i] = out[i] / (cnt[i/768] + 1e-6)
__global__ void final_k(float* __restrict__ out, const float* __restrict__ cnt, int n) {
  int i = blockIdx.x * 256 + threadIdx.x;
  if (i < n) out[i] = out[i] / (cnt[i / 768] + 1e-6f);
}
// batched: gather task slots, sum, divide; one wave per token
__global__ __launch_bounds__(256) void final2_k(
    const float* __restrict__ y2, const int* __restrict__ rt,
    const int* __restrict__ tsmap, const float* __restrict__ cnt,
    float* __restrict__ out, int T)
{
  int wv = threadIdx.x >> 6, lane = threadIdx.x & 63;
  int t = blockIdx.x * 4 + wv;
  if (t >= T) return;
  float acc[12];
#pragma unroll
  for (int i = 0; i < 12; ++i) acc[i] = 0.f;
  for (int tt = 0; tt < 8; ++tt) {
    int s = tsmap[(size_t)t * 8 + tt];
    if (s >= 0) {                         // wave-uniform branch
      const float* yr = y2 + (size_t)(rt[24 + tt] + s) * 768;
#pragma unroll
      for (int i = 0; i < 12; ++i) acc[i] += yr[lane + i * 64];
    }
  }
  float inv = 1.f / (cnt[t] + 1e-6f);
  float* orow = out + (size_t)t * 768;
#pragma unroll
  for (int i = 0; i < 12; ++i) orow[lane + i * 64] = acc[i] * inv;
}

// ---------------- host ------------------------------------------------------
extern "C" void kernel_launch(void* const* d_in, const int* in_sizes, int n_in,
                              void* d_out, int out_size, void* d_ws, size_t ws_size,
                              hipStream_t stream)
{
  (void)in_sizes; (void)n_in; (void)out_size;
  const int Ttok = 8 * 197;  // 1576
  const int D = 768, HID = 3072;
  const int CAP = 4 * Ttok;  // total routed (token,expert) pairs = top-4 exact

  const float* x       = (const float*)d_in[0];
  const float* ln1a_w  = (const float*)d_in[1];
  const float* ln1a_b  = (const float*)d_in[2];
  const float* qkv_wa  = (const float*)d_in[3];
  const float* qkv_ba  = (const float*)d_in[4];
  const float* proj_wa = (const float*)d_in[5];
  const float* proj_ba = (const float*)d_in[6];
  const float* ln2a_w  = (const float*)d_in[7];
  const float* ln2a_b  = (const float*)d_in[8];
  const float* fc1_w   = (const float*)d_in[9];
  const float* fc1_b   = (const float*)d_in[10];
  const float* fc2_w   = (const float*)d_in[11];
  const float* fc2_b   = (const float*)d_in[12];
  const float* ln1b_w  = (const float*)d_in[13];
  const float* ln1b_b  = (const float*)d_in[14];
  const float* qkv_wb  = (const float*)d_in[15];
  const float* qkv_bb  = (const float*)d_in[16];
  const float* proj_wb = (const float*)d_in[17];
  const float* proj_bb = (const float*)d_in[18];
  const float* ln2b_w  = (const float*)d_in[19];
  const float* ln2b_b  = (const float*)d_in[20];
  const float* gate_w  = (const float*)d_in[21];
  const float* w1      = (const float*)d_in[22];
  const float* b1      = (const float*)d_in[23];
  const float* w2      = (const float*)d_in[24];
  const float* b2      = (const float*)d_in[25];
  const float* head_w  = (const float*)d_in[26];
  const float* head_b  = (const float*)d_in[27];
  const int* shared_masks = (const int*)d_in[28];
  const int* agg_mask     = (const int*)d_in[29];
  float* out           = (float*)d_out;

  char* wsp = (char*)d_ws;
  auto alloc = [&](size_t bytes) { char* p = wsp; wsp += (bytes + 255) & ~(size_t)255; return p; };
  float* xf             = (float*)alloc((size_t)Ttok * D * 4);
  __hip_bfloat16* lnb   = (__hip_bfloat16*)alloc((size_t)Ttok * D * 2);
  __hip_bfloat16* qkvb  = (__hip_bfloat16*)alloc((size_t)Ttok * 3 * D * 2);
  __hip_bfloat16* attnb = (__hip_bfloat16*)alloc((size_t)Ttok * D * 2);
  __hip_bfloat16* h1    = (__hip_bfloat16*)alloc((size_t)Ttok * HID * 2);
  float* combine        = (float*)alloc((size_t)Ttok * 8 * 4);
  float* cnt            = (float*)alloc((size_t)Ttok * 4);
  int* rt               = (int*)alloc((size_t)(32 + 16 * Ttok) * 4);  // hdr+lists
  int* smap             = (int*)alloc((size_t)Ttok * 8 * 4);
  int* tsmap            = (int*)alloc((size_t)Ttok * 8 * 4);
  int* valid            = (int*)alloc((size_t)8 * Ttok * 4);
  __hip_bfloat16* qkvaT = (__hip_bfloat16*)alloc((size_t)D * 3 * D * 2);
  __hip_bfloat16* projaT= (__hip_bfloat16*)alloc((size_t)D * D * 2);
  __hip_bfloat16* fc1T  = (__hip_bfloat16*)alloc((size_t)D * HID * 2);
  __hip_bfloat16* fc2T  = (__hip_bfloat16*)alloc((size_t)D * HID * 2);
  __hip_bfloat16* qkvbT = (__hip_bfloat16*)alloc((size_t)D * 3 * D * 2);
  __hip_bfloat16* projbT= (__hip_bfloat16*)alloc((size_t)D * D * 2);
  __hip_bfloat16* headT = (__hip_bfloat16*)alloc((size_t)8 * D * D * 2);
  __hip_bfloat16* wT    = (__hip_bfloat16*)alloc((size_t)D * HID * 2);

  // batched-MoE extra buffers (deterministic guard: ws_size constant per harness)
  const size_t used = (size_t)(wsp - (char*)d_ws);
  const size_t extraNeed = 2 * ((size_t)8 * D * HID * 2 + 255)        // w1T8 + w2T8
                         + ((size_t)8 * Ttok * HID * 2 + 255)         // h1_8
                         + (2 * (size_t)CAP * D * 4 + 255);           // yb
  const bool batched = (ws_size >= used + extraNeed);
  __hip_bfloat16* w1T8 = nullptr; __hip_bfloat16* w2T8 = nullptr; __hip_bfloat16* h1_8 = nullptr;
  float* yb = nullptr;
  if (batched) {
    w1T8 = (__hip_bfloat16*)alloc((size_t)8 * D * HID * 2);
    w2T8 = (__hip_bfloat16*)alloc((size_t)8 * D * HID * 2);
    h1_8 = (__hip_bfloat16*)alloc((size_t)8 * Ttok * HID * 2);
    yb   = (float*)alloc(2 * (size_t)CAP * D * 4);   // also reused as head slots (8T rows)
  }

  dim3 tb(32, 8);
  if (batched) {
    // single fused transpose dispatch for all 9 weight matrices (64x64 tiles)
    TPack p; int off = 0;
    auto addT = [&](int i, const float* s, __hip_bfloat16* dd, int R, int C, int nz) {
      int tpz = (R / 64) * (C / 64);
      p.d[i] = TDesc{s, dd, R, C, nz, tpz, off};
      off += tpz * nz;
    };
    addT(0, qkv_wa, qkvaT, D, 3 * D, 1);
    addT(1, proj_wa, projaT, D, D, 1);
    addT(2, fc1_w, fc1T, D, HID, 1);
    addT(3, fc2_w, fc2T, HID, D, 1);
    addT(4, qkv_wb, qkvbT, D, 3 * D, 1);
    addT(5, proj_wb, projbT, D, D, 1);
    addT(6, head_w, headT, D, D, 8);
    addT(7, w1, w1T8, D, HID, 8);
    addT(8, w2, w2T8, HID, D, 8);
    p.n = 9;
    transpose_all_k<<<off, 256, 0, stream>>>(p);
  } else {
    transpose_k<<<dim3(3*D/32, D/32, 1), tb, 0, stream>>>(qkv_wa, qkvaT, D, 3*D);
    transpose_k<<<dim3(D/32, D/32, 1),   tb, 0, stream>>>(proj_wa, projaT, D, D);
    transpose_k<<<dim3(HID/32, D/32, 1), tb, 0, stream>>>(fc1_w, fc1T, D, HID);
    transpose_k<<<dim3(D/32, HID/32, 1), tb, 0, stream>>>(fc2_w, fc2T, HID, D);
    transpose_k<<<dim3(3*D/32, D/32, 1), tb, 0, stream>>>(qkv_wb, qkvbT, D, 3*D);
    transpose_k<<<dim3(D/32, D/32, 1),   tb, 0, stream>>>(proj_wb, projbT, D, D);
    transpose_k<<<dim3(D/32, D/32, 8),   tb, 0, stream>>>(head_w, headT, D, D);
  }

  const int nTok = Ttok * D;
  hipMemcpyAsync(xf, x, (size_t)nTok * 4, hipMemcpyDeviceToDevice, stream);
  hipMemsetAsync(rt, 0, 128, stream);   // zero the 32 routing counters/bases
  mask_k<<<(Ttok + 255)/256, 256, 0, stream>>>(shared_masks, agg_mask, cnt, rt, tsmap, valid, Ttok);
  if (!batched) hipMemsetAsync(out, 0, (size_t)nTok * 4, stream);

  const int lnGrid = (Ttok + 3) / 4;
  dim3 g_qkv(3*D/128, 13, 1);
  dim3 g_proj(D/128, 13, 4);    // split-K x4
  dim3 g_fc1(HID/128, 13, 1);
  dim3 g_fc2(D/128, 13, 4);     // split-K x4
  dim3 g_head(D/128, 13, 8);    // z = task (routed: blocks past count exit)
  const int attnGrid = 96 * 4;  // (b,h) x 4 row-chunks

  // ---- dense ViT block ----
  ln_k<<<lnGrid, 256, 0, stream>>>(xf, ln1a_w, ln1a_b, lnb, Ttok);
  gemm_bt<EPI_STORE><<<g_qkv, 256, 0, stream>>>(lnb, qkvaT, qkv_ba, Ttok, 3*D, D, 1, 0, 0, 0, 0, 0, qkvb, nullptr, nullptr, nullptr);
  attn_mfma_k<<<attnGrid, 256, 0, stream>>>(qkvb, attnb);
  gemm_bt<EPI_RESADD><<<g_proj, 256, 0, stream>>>(attnb, projaT, proj_ba, Ttok, D, D, 4, 0, 0, 0, 0, 0, nullptr, xf, nullptr, nullptr);
  ln_k<<<lnGrid, 256, 0, stream>>>(xf, ln2a_w, ln2a_b, lnb, Ttok);
  gemm_bt<EPI_GELU><<<g_fc1, 256, 0, stream>>>(lnb, fc1T, fc1_b, Ttok, HID, D, 1, 0, 0, 0, 0, 0, h1, nullptr, nullptr, nullptr);
  gemm_bt<EPI_RESADD><<<g_fc2, 256, 0, stream>>>(h1, fc2T, fc2_b, Ttok, D, HID, 4, 0, 0, 0, 0, 0, nullptr, xf, nullptr, nullptr);

  // ---- MoE ViT block ----
  ln_k<<<lnGrid, 256, 0, stream>>>(xf, ln1b_w, ln1b_b, lnb, Ttok);
  gemm_bt<EPI_STORE><<<g_qkv, 256, 0, stream>>>(lnb, qkvbT, qkv_bb, Ttok, 3*D, D, 1, 0, 0, 0, 0, 0, qkvb, nullptr, nullptr, nullptr);
  attn_mfma_k<<<attnGrid, 256, 0, stream>>>(qkvb, attnb);
  gemm_bt<EPI_RESADD><<<g_proj, 256, 0, stream>>>(attnb, projbT, proj_bb, Ttok, D, D, 4, 0, 0, 0, 0, 0, nullptr, xf, nullptr, nullptr);
  gate_k<<<lnGrid, 256, 0, stream>>>(xf, ln2b_w, ln2b_b, gate_w, combine, rt, smap, lnb, Ttok);
  prefix_k<<<1, 64, 0, stream>>>(rt);
  if (batched) {
    gemm_bt<EPI_GELU_R><<<dim3(HID/128, 13, 8), 256, 0, stream>>>(
        lnb, w1T8, b1, Ttok, HID, D, 1, 0,
        (long long)D*HID, HID, 0, (long long)Ttok*HID, h1_8, nullptr, nullptr, rt);
    gemm_bt<EPI_MOEP><<<dim3(D/128, 13, 16), 256, 0, stream>>>(
        h1_8, w2T8, b2, Ttok, D, HID, 2, 0,
        (long long)HID*D, D, (long long)Ttok*HID, (long long)CAP*D, nullptr, yb, nullptr, rt);
    combine_k<<<lnGrid, 256, 0, stream>>>(yb, combine, rt, smap, xf, lnb, Ttok, CAP);
    // ---- heads: plain stores into compact task-slot buffer (yb reused) ----
    gemm_bt<EPI_HEADP><<<g_head, 256, 0, stream>>>(lnb, headT, head_b, Ttok, D, D, 1, 0, (long long)D*D, D, 0, 0, nullptr, yb, nullptr, rt);
    final2_k<<<lnGrid, 256, 0, stream>>>(yb, rt, tsmap, cnt, out, Ttok);
  } else {
    for (int e = 0; e < 8; ++e) {
      transpose_k<<<dim3(HID/32, D/32, 1), tb, 0, stream>>>(w1 + (size_t)e*D*HID, wT, D, HID);
      gemm_bt<EPI_GELU><<<g_fc1, 256, 0, stream>>>(lnb, wT, b1 + (size_t)e*HID, Ttok, HID, D, 1, 0, 0, 0, 0, 0, h1, nullptr, nullptr, nullptr);
      transpose_k<<<dim3(D/32, HID/32, 1), tb, 0, stream>>>(w2 + (size_t)e*HID*D, wT, HID, D);
      gemm_bt<EPI_MOE><<<g_fc2, 256, 0, stream>>>(h1, wT, b2 + (size_t)e*D, Ttok, D, HID, 4, e, 0, 0, 0, 0, nullptr, xf, combine, nullptr);
    }
    f2b_k<<<(nTok + 255)/256, 256, 0, stream>>>(xf, lnb, nTok);
    gemm_bt<EPI_HEAD_R><<<g_head, 256, 0, stream>>>(lnb, headT, head_b, Ttok, D, D, 1, 0, (long long)D*D, D, 0, 0, nullptr, out, nullptr, rt);
    final_k<<<(nTok + 255)/256, 256, 0, stream>>>(out, cnt, nTok);
  }
}

// Round 7
// 746.526 us; speedup vs baseline: 1.2823x; 1.0932x over previous
//
#include <hip/hip_runtime.h>
#include <hip/hip_bf16.h>

#define DEV static __device__ __forceinline__

typedef short bfx8 __attribute__((ext_vector_type(8)));   // 8 bf16 in 4 VGPRs (guide §3)
typedef float fx4  __attribute__((ext_vector_type(4)));

DEV float bf2f(__hip_bfloat16 h) { return __bfloat162float(h); }
DEV __hip_bfloat16 f2bf(float f) { return __float2bfloat16(f); }
DEV float uLO(unsigned u) { return __uint_as_float(u << 16); }
DEV unsigned short f2bfu(float f) { __hip_bfloat16 h = __float2bfloat16(f); return *(unsigned short*)&h; }

DEV float wave_sum(float v) {
#pragma unroll
  for (int o = 32; o; o >>= 1) v += __shfl_xor(v, o, 64);
  return v;
}

#define GLD_LDS16(gp, lp) __builtin_amdgcn_global_load_lds( \
    (__attribute__((address_space(1))) void*)(gp),          \
    (__attribute__((address_space(3))) void*)(lp), 16, 0, 0)

// -------- transpose+convert tiles: src fp32 [R][C] -> dst bf16 [C][R] -------
// 64x64 tiles; float4 loads; bf16 LDS stride-66; short8 stores.
// Tiles are carried either by transpose_all_k or as extra z-slices of gemm_bt
// (grid concatenation: overlap the pure-BW transpose with latency-bound GEMMs).
struct TDesc { const float* src; __hip_bfloat16* dst; int R, C, nz, tilesPerZ, tileOff; };
struct TPack { TDesc d[9]; int n; };

DEV void trans_tile(const TPack& p, int gtile, unsigned short* t, int tid) {
  int di = 0;
#pragma unroll
  for (int i = 1; i < 9; ++i)
    if (i < p.n && gtile >= p.d[i].tileOff) di = i;
  const TDesc d = p.d[di];
  int local = gtile - d.tileOff;
  int z = local / d.tilesPerZ;
  int rem = local - z * d.tilesPerZ;
  int ctiles = d.C >> 6;
  int bx = rem % ctiles, by = rem / ctiles;
  const float* src = d.src + (size_t)z * d.R * d.C;
  __hip_bfloat16* dst = d.dst + (size_t)z * d.R * d.C;
  int c0 = bx * 64, r0 = by * 64;
#pragma unroll
  for (int it = 0; it < 4; ++it) {
    int idx = tid + it * 256;
    int row = idx >> 4, q = idx & 15;
    float4 v = *(const float4*)(src + (size_t)(r0 + row) * d.C + c0 + q * 4);
    ushort2 lo, hi;
    lo.x = f2bfu(v.x); lo.y = f2bfu(v.y);
    hi.x = f2bfu(v.z); hi.y = f2bfu(v.w);
    *(ushort2*)&t[row * 66 + q * 4]     = lo;
    *(ushort2*)&t[row * 66 + q * 4 + 2] = hi;
  }
  __syncthreads();
#pragma unroll
  for (int it = 0; it < 2; ++it) {
    int idx = tid + it * 256;     // 512 short8-units
    int oc = idx >> 3, q = idx & 7;
    bfx8 w;
#pragma unroll
    for (int j = 0; j < 8; ++j)
      w[j] = (short)t[(q * 8 + j) * 66 + oc];
    *(bfx8*)(dst + (size_t)(c0 + oc) * d.R + r0 + q * 8) = w;
  }
}

__global__ __launch_bounds__(256) void transpose_all_k(TPack p, int tStart) {
  __shared__ __align__(16) unsigned short t[64 * 66];
  trans_tile(p, tStart + blockIdx.x, t, threadIdx.x);
}

// single-matrix transpose (fallback path only)
__global__ __launch_bounds__(256) void transpose_k(
    const float* __restrict__ src, __hip_bfloat16* __restrict__ dst,
    int R, int C)
{
  __shared__ float tile[32][33];
  size_t off = (size_t)blockIdx.z * R * C;
  src += off; dst += off;
  int c0 = blockIdx.x * 32, r0 = blockIdx.y * 32;
#pragma unroll
  for (int i = 0; i < 32; i += 8)
    tile[threadIdx.y + i][threadIdx.x] =
        src[(size_t)(r0 + threadIdx.y + i) * C + c0 + threadIdx.x];
  __syncthreads();
#pragma unroll
  for (int i = 0; i < 32; i += 8)
    dst[(size_t)(c0 + threadIdx.y + i) * R + r0 + threadIdx.x] =
        f2bf(tile[threadIdx.x][threadIdx.y + i]);
}

// ---------------- GEMM: C = A[M,K] x B  (B given transposed: BT[N,K]) ------
// 128x128 tile, 4 waves, 4x4 mfma_f32_16x16x32_bf16, 2-phase dbuf K-loop.
// Extra z-slices (z >= tZBase) run transpose tiles [tStart, tStart+tCount).
// rt layout: [0..7] expert counts, [8..15] task counts, [16..23] expert bases,
// [24..31] task bases, [32 .. 32+8T) expert token lists, [32+8T ..) task lists.
enum { EPI_STORE = 0, EPI_GELU = 1, EPI_RESADD = 2, EPI_MOE = 3,
       EPI_GELU_R = 4, EPI_MOEP = 5, EPI_HEAD_R = 6, EPI_HEADP = 7 };

template <int MODE>
__global__ __launch_bounds__(256) void gemm_bt(
    const __hip_bfloat16* __restrict__ A,    // [M,K]  (+ zt*strideAz)
    const __hip_bfloat16* __restrict__ BT,   // [zt][N,K]
    const float* __restrict__ bias,          // [zt][N] fp32
    int M, int N, int K, int splitK, int taskBase,
    long long strideBz, long long strideBiasz, long long strideAz, long long strideCz,
    __hip_bfloat16* __restrict__ Cb, float* __restrict__ Cf,
    const float* __restrict__ combine, const int* __restrict__ rt,
    TPack tp, int tZBase, int tStart, int tCount)
{
  constexpr bool ROUTED = (MODE == EPI_GELU_R || MODE == EPI_MOEP ||
                           MODE == EPI_HEAD_R || MODE == EPI_HEADP);
  constexpr bool GATHER = (MODE == EPI_GELU_R || MODE == EPI_HEAD_R || MODE == EPI_HEADP);
  __shared__ __align__(16) __hip_bfloat16 smem[4 * 128 * 32];  // sA[2] | sB[2]
  const int tid = threadIdx.x;

  // ---- carried transpose tiles (grid-concatenated BW work) ----
  if ((int)blockIdx.z >= tZBase) {
    int flat = ((int)blockIdx.z - tZBase) * (int)(gridDim.x * gridDim.y)
             + (int)blockIdx.y * (int)gridDim.x + (int)blockIdx.x;
    if (flat < tCount) trans_tile(tp, tStart + flat, (unsigned short*)smem, tid);
    return;
  }

  const int wave = tid >> 6, lane = tid & 63;
  const int quad = lane >> 4, l16 = lane & 15;
  const int z = blockIdx.z;
  const int zt = z / splitK;
  const int kc = z - zt * splitK;
  const int task = taskBase + zt;
  const int Ksub = K / splitK;
  const int kbeg = kc * Ksub;
  const int m0 = blockIdx.y * 128, n0 = blockIdx.x * 128;

  int Meff = M;
  int rtb = 0;
  const int* ilist = nullptr;
  if (ROUTED) {
    const int base = (MODE == EPI_HEAD_R || MODE == EPI_HEADP) ? 8 : 0;
    Meff = rt[base + zt];
    ilist = rt + 32 + (size_t)base * M + (size_t)zt * M;
    if (MODE == EPI_MOEP) rtb = rt[16 + zt];   // compact expert output base
    if (MODE == EPI_HEADP) rtb = rt[24 + zt];  // compact task output base
    if (m0 >= Meff) return;   // whole block exits together, before any barrier
  }

  A += (size_t)zt * strideAz;
  if (MODE != EPI_MOEP && MODE != EPI_HEADP) Cb += (size_t)zt * strideCz;
  const __hip_bfloat16* Bz = BT + (size_t)zt * strideBz;
  const float* biasz = bias + (size_t)zt * strideBiasz;
  const int wm = (wave >> 1) * 64, wn = (wave & 1) * 64;

  __hip_bfloat16* sA0 = smem;
  __hip_bfloat16* sA1 = smem + 128 * 32;
  __hip_bfloat16* sB0 = smem + 2 * 128 * 32;
  __hip_bfloat16* sB1 = smem + 3 * 128 * 32;

  fx4 acc[4][4];
#pragma unroll
  for (int i = 0; i < 4; ++i)
#pragma unroll
    for (int j = 0; j < 4; ++j) acc[i][j] = (fx4){0.f, 0.f, 0.f, 0.f};

  // staging: chunk c covers row c>>2, k-seg (c&3)*8 ; LDS dest = c*8 elems
  const int c0 = tid, c1 = tid + 256;
  const int mlim = Meff - 1;
  int gm0 = m0 + (c0 >> 2); if (gm0 > mlim) gm0 = mlim;
  int gm1 = m0 + (c1 >> 2); if (gm1 > mlim) gm1 = mlim;
  const int ar0 = GATHER ? ilist[gm0] : gm0;
  const int ar1 = GATHER ? ilist[gm1] : gm1;
  const int ak0 = (c0 & 3) * 8, ak1 = (c1 & 3) * 8;
  const __hip_bfloat16* pa0 = A + (size_t)ar0 * K + kbeg + ak0;
  const __hip_bfloat16* pa1 = A + (size_t)ar1 * K + kbeg + ak1;
  const __hip_bfloat16* pb0 = Bz + (size_t)(n0 + (c0 >> 2)) * K + kbeg + ak0;
  const __hip_bfloat16* pb1 = Bz + (size_t)(n0 + (c1 >> 2)) * K + kbeg + ak1;

  // prologue: stage tile 0 into buf 0
  GLD_LDS16(pa0, &sA0[c0 * 8]);
  GLD_LDS16(pa1, &sA0[c1 * 8]);
  GLD_LDS16(pb0, &sB0[c0 * 8]);
  GLD_LDS16(pb1, &sB0[c1 * 8]);
  __syncthreads();   // drains vmcnt -> LDS writes visible

  int cur = 0;
  for (int kk = 0; kk < Ksub; kk += 32) {
    const int nxt = kk + 32;
    if (nxt < Ksub) {          // prefetch t+1 into the other buffer
      GLD_LDS16(pa0 + nxt, (cur ? &sA0[c0 * 8] : &sA1[c0 * 8]));
      GLD_LDS16(pa1 + nxt, (cur ? &sA0[c1 * 8] : &sA1[c1 * 8]));
      GLD_LDS16(pb0 + nxt, (cur ? &sB0[c0 * 8] : &sB1[c0 * 8]));
      GLD_LDS16(pb1 + nxt, (cur ? &sB0[c1 * 8] : &sB1[c1 * 8]));
    }
    const __hip_bfloat16* sAc = cur ? sA1 : sA0;
    const __hip_bfloat16* sBc = cur ? sB1 : sB0;
    bfx8 af[4], bfr[4];
#pragma unroll
    for (int i = 0; i < 4; ++i)
      af[i] = *(const bfx8*)(&sAc[(wm + i * 16 + l16) * 32 + quad * 8]);
#pragma unroll
    for (int j = 0; j < 4; ++j)
      bfr[j] = *(const bfx8*)(&sBc[(wn + j * 16 + l16) * 32 + quad * 8]);
#pragma unroll
    for (int i = 0; i < 4; ++i)
#pragma unroll
      for (int j = 0; j < 4; ++j)
        acc[i][j] = __builtin_amdgcn_mfma_f32_16x16x32_bf16(af[i], bfr[j], acc[i][j], 0, 0, 0);
    __syncthreads();  // vmcnt(0)+barrier: t+1 visible, buf[cur] free for reuse
    cur ^= 1;
  }

  // epilogue: C/D layout col=lane&15, row=quad*4+reg (m89-verified)
  const int mb = m0 + wm + quad * 4;
  const int nb = n0 + wn + l16;
#pragma unroll
  for (int i = 0; i < 4; ++i) {
#pragma unroll
    for (int rr = 0; rr < 4; ++rr) {
      const int m = mb + i * 16 + rr;
      if (m >= Meff) continue;
      int orow = m;
      if (MODE == EPI_HEAD_R) orow = ilist[m];
#pragma unroll
      for (int j = 0; j < 4; ++j) {
        const int n = nb + j * 16;
        float v = acc[i][j][rr];
        if (MODE == EPI_STORE) {
          Cb[(size_t)m * N + n] = f2bf(v + biasz[n]);
        } else if (MODE == EPI_GELU || MODE == EPI_GELU_R) {
          float t = v + biasz[n];
          Cb[(size_t)m * N + n] = f2bf(0.5f * t * (1.f + erff(t * 0.70710678118654752f)));
        } else if (MODE == EPI_RESADD) {
          if (kc == 0) v += biasz[n];
          atomicAdd(&Cf[(size_t)m * N + n], v);
        } else if (MODE == EPI_MOE) {
          float s = combine[m * 8 + task];
          if (s != 0.f) {
            if (kc == 0) v += biasz[n];
            atomicAdd(&Cf[(size_t)m * N + n], s * v);
          }
        } else if (MODE == EPI_MOEP) {
          if (kc == 0) v += biasz[n];
          Cf[(size_t)kc * strideCz + (size_t)(rtb + m) * N + n] = v;
        } else if (MODE == EPI_HEADP) {
          Cf[(size_t)(rtb + m) * N + n] = v + biasz[n];   // plain store, no atomics
        } else {  // EPI_HEAD_R (fallback)
          atomicAdd(&Cf[(size_t)orow * N + n], v + biasz[n]);
        }
      }
    }
  }
}

// ---------------- MFMA attention ------------------------------------------
__global__ __launch_bounds__(256) void attn_mfma_k(
    const __hip_bfloat16* __restrict__ qkvb, __hip_bfloat16* __restrict__ outb)
{
  __shared__ __align__(16) unsigned short VT[64 * 232];       // V^T [d][tok], stride 232
  __shared__ __align__(16) unsigned short Pst[4][16 * 232];   // per-wave P strip [m][tok]
  const int tid = threadIdx.x;
  const int chunk = blockIdx.x & 3;
  const int bh = blockIdx.x >> 2;
  const int b = bh / 12, h = bh - b * 12;
  const size_t tokBase = (size_t)b * 197;
  const __hip_bfloat16* qkvh = qkvb + tokBase * 2304 + (size_t)h * 64;

  // stage V^T (which=2 -> +1536)
  for (int idx = tid; idx < 197 * 32; idx += 256) {
    int j = idx >> 5, dp = idx & 31;
    unsigned pv = *(const unsigned*)(qkvh + (size_t)j * 2304 + 1536 + dp * 2);
    VT[(2 * dp) * 232 + j]     = (unsigned short)(pv & 0xffffu);
    VT[(2 * dp + 1) * 232 + j] = (unsigned short)(pv >> 16);
  }
  // NaN fix: zero VT pad cols [197,232).
  for (int idx = tid; idx < 64 * 35; idx += 256) {
    int r = idx / 35, c = 197 + idx % 35;
    VT[r * 232 + c] = 0;
  }
  __syncthreads();

  const int wave = tid >> 6, lane = tid & 63;
  const int quad = lane >> 4, l16 = lane & 15;
  const int mt = chunk * 4 + wave;   // m-tile 0..12
  if (mt >= 13) return;

  // zero P strip pad cols [208,224)
  {
    int r = lane >> 2, c = 208 + (lane & 3) * 4;
    *(uint2*)&Pst[wave][r * 232 + c] = (uint2){0u, 0u};
  }

  // Q A-frags (clamped rows; invalid rows computed but never stored)
  int tq = mt * 16 + l16; if (tq > 196) tq = 196;
  const bfx8 af0 = *(const bfx8*)(qkvh + (size_t)tq * 2304 + quad * 8);
  const bfx8 af1 = *(const bfx8*)(qkvh + (size_t)tq * 2304 + 32 + quad * 8);

  // S strip: 13 n-tiles, K frags from global (which=1 -> +768)
  fx4 sv[13];
#pragma unroll
  for (int n0 = 0; n0 < 13; ++n0) {
    int tk = n0 * 16 + l16; if (tk > 196) tk = 196;
    const __hip_bfloat16* kp = qkvh + (size_t)tk * 2304 + 768;
    bfx8 bf0 = *(const bfx8*)(kp + quad * 8);
    bfx8 bf1 = *(const bfx8*)(kp + 32 + quad * 8);
    fx4 a = (fx4){0.f, 0.f, 0.f, 0.f};
    a = __builtin_amdgcn_mfma_f32_16x16x32_bf16(af0, bf0, a, 0, 0, 0);
    a = __builtin_amdgcn_mfma_f32_16x16x32_bf16(af1, bf1, a, 0, 0, 0);
    sv[n0] = a;
  }

  // softmax per row (row = quad*4+rr); cols of lane: n0*16+l16
  float inv[4];
#pragma unroll
  for (int rr = 0; rr < 4; ++rr) {
    float mx = -3.0e38f;
#pragma unroll
    for (int n0 = 0; n0 < 13; ++n0) {
      bool ok = (n0 < 12) | (l16 < 5);           // col < 197
      float s = ok ? sv[n0][rr] * 0.125f : -3.0e38f;
      sv[n0][rr] = s;
      mx = fmaxf(mx, s);
    }
#pragma unroll
    for (int o = 1; o < 16; o <<= 1) mx = fmaxf(mx, __shfl_xor(mx, o, 64));
    float sum = 0.f;
#pragma unroll
    for (int n0 = 0; n0 < 13; ++n0) {
      float s = sv[n0][rr];
      float e = (s > -1.0e38f) ? __expf(s - mx) : 0.f;
      sv[n0][rr] = e;
      sum += e;
    }
#pragma unroll
    for (int o = 1; o < 16; o <<= 1) sum += __shfl_xor(sum, o, 64);
    inv[rr] = 1.f / sum;
    const int row = quad * 4 + rr;
#pragma unroll
    for (int n0 = 0; n0 < 13; ++n0)
      Pst[wave][row * 232 + n0 * 16 + l16] = f2bfu(sv[n0][rr]);   // P hi
  }

  // PV pass 1 (P hi)
  fx4 pv[4];
#pragma unroll
  for (int nd = 0; nd < 4; ++nd) pv[nd] = (fx4){0.f, 0.f, 0.f, 0.f};
#pragma unroll
  for (int kk = 0; kk < 7; ++kk) {
    bfx8 paf = *(const bfx8*)&Pst[wave][l16 * 232 + kk * 32 + quad * 8];
#pragma unroll
    for (int nd = 0; nd < 4; ++nd) {
      bfx8 bfv = *(const bfx8*)&VT[(nd * 16 + l16) * 232 + kk * 32 + quad * 8];
      pv[nd] = __builtin_amdgcn_mfma_f32_16x16x32_bf16(paf, bfv, pv[nd], 0, 0, 0);
    }
  }

  // P lo = e - bf16(e), overwrite same strip (same-wave ordering -> safe)
#pragma unroll
  for (int rr = 0; rr < 4; ++rr) {
    const int row = quad * 4 + rr;
#pragma unroll
    for (int n0 = 0; n0 < 13; ++n0) {
      float e = sv[n0][rr];
      Pst[wave][row * 232 + n0 * 16 + l16] = f2bfu(e - uLO(f2bfu(e)));
    }
  }

  // PV pass 2 (P lo) accumulates
#pragma unroll
  for (int kk = 0; kk < 7; ++kk) {
    bfx8 paf = *(const bfx8*)&Pst[wave][l16 * 232 + kk * 32 + quad * 8];
#pragma unroll
    for (int nd = 0; nd < 4; ++nd) {
      bfx8 bfv = *(const bfx8*)&VT[(nd * 16 + l16) * 232 + kk * 32 + quad * 8];
      pv[nd] = __builtin_amdgcn_mfma_f32_16x16x32_bf16(paf, bfv, pv[nd], 0, 0, 0);
    }
  }

  // store: row m = mt*16 + quad*4 + rr, col d = nd*16 + l16
#pragma unroll
  for (int rr = 0; rr < 4; ++rr) {
    int m = mt * 16 + quad * 4 + rr;
    if (m > 196) continue;
    __hip_bfloat16* op = outb + (tokBase + m) * 768 + (size_t)h * 64;
#pragma unroll
    for (int nd = 0; nd < 4; ++nd)
      op[nd * 16 + l16] = f2bf(pv[nd][rr] * inv[rr]);
  }
}

// ---------------- LayerNorm: one wave per token, fp32 in -> bf16 out -------
__global__ __launch_bounds__(256) void ln_k(
    const float* __restrict__ xf, const float* __restrict__ w,
    const float* __restrict__ b, __hip_bfloat16* __restrict__ out, int T)
{
  int wv = threadIdx.x >> 6, lane = threadIdx.x & 63;
  int t = blockIdx.x * 4 + wv;
  if (t >= T) return;
  const float* row = xf + (size_t)t * 768;
  float v[12]; float s = 0.f;
#pragma unroll
  for (int i = 0; i < 12; ++i) { v[i] = row[lane + i * 64]; s += v[i]; }
  s = wave_sum(s);
  float mean = s * (1.f / 768.f);
  float q = 0.f;
#pragma unroll
  for (int i = 0; i < 12; ++i) { float d = v[i] - mean; q += d * d; }
  q = wave_sum(q);
  float rstd = rsqrtf(q * (1.f / 768.f) + 1e-5f);
#pragma unroll
  for (int i = 0; i < 12; ++i) {
    int d = lane + i * 64;
    out[(size_t)t * 768 + d] = f2bf((v[i] - mean) * rstd * w[d] + b[d]);
  }
}

// ---------------- MoE gating: fp32 LN + logits + softmax + top-4 ----------
__global__ __launch_bounds__(256) void gate_k(
    const float* __restrict__ xf, const float* __restrict__ lw,
    const float* __restrict__ lb, const float* __restrict__ gw,
    float* __restrict__ combine, int* __restrict__ rt, int* __restrict__ smap,
    __hip_bfloat16* __restrict__ lnbout, int T)
{
  int wv = threadIdx.x >> 6, lane = threadIdx.x & 63;
  int t = blockIdx.x * 4 + wv;
  if (t >= T) return;
  const float* row = xf + (size_t)t * 768;
  float v[12]; float s = 0.f;
#pragma unroll
  for (int i = 0; i < 12; ++i) { v[i] = row[lane + i * 64]; s += v[i]; }
  s = wave_sum(s);
  float mean = s * (1.f / 768.f);
  float qv = 0.f;
#pragma unroll
  for (int i = 0; i < 12; ++i) { float d = v[i] - mean; qv += d * d; }
  qv = wave_sum(qv);
  float rstd = rsqrtf(qv * (1.f / 768.f) + 1e-5f);
  float acc[8];
#pragma unroll
  for (int e = 0; e < 8; ++e) acc[e] = 0.f;
#pragma unroll
  for (int i = 0; i < 12; ++i) {
    int d = lane + i * 64;
    float xn = (v[i] - mean) * rstd * lw[d] + lb[d];
    lnbout[(size_t)t * 768 + d] = f2bf(xn);   // merged ln2b output
    float4 g0 = *(const float4*)(gw + (size_t)d * 8);
    float4 g1 = *(const float4*)(gw + (size_t)d * 8 + 4);
    acc[0] += xn * g0.x; acc[1] += xn * g0.y;
    acc[2] += xn * g0.z; acc[3] += xn * g0.w;
    acc[4] += xn * g1.x; acc[5] += xn * g1.y;
    acc[6] += xn * g1.z; acc[7] += xn * g1.w;
  }
#pragma unroll
  for (int e = 0; e < 8; ++e) acc[e] = wave_sum(acc[e]);
  float mx = acc[0];
#pragma unroll
  for (int e = 1; e < 8; ++e) mx = fmaxf(mx, acc[e]);
  float p[8]; float se = 0.f;
#pragma unroll
  for (int e = 0; e < 8; ++e) { p[e] = __expf(acc[e] - mx); se += p[e]; }
  float inv = 1.f / se;
#pragma unroll
  for (int e = 0; e < 8; ++e) p[e] *= inv;
  float outv[8]; bool used[8];
#pragma unroll
  for (int e = 0; e < 8; ++e) { outv[e] = 0.f; used[e] = false; }
  for (int k = 0; k < 4; ++k) {   // top-4, ties -> lowest index (matches top_k)
    int best = -1; float bv = -1.f;
#pragma unroll
    for (int e = 0; e < 8; ++e) if (!used[e] && p[e] > bv) { bv = p[e]; best = e; }
#pragma unroll
    for (int e = 0; e < 8; ++e) if (e == best) { used[e] = true; outv[e] = bv; }
  }
#pragma unroll
  for (int e = 0; e < 8; ++e) if (lane == e) combine[(size_t)t * 8 + e] = outv[e];
#pragma unroll
  for (int e = 0; e < 8; ++e)
    if (lane == e && outv[e] != 0.f) {
      int slot = atomicAdd(&rt[e], 1);
      rt[32 + e * T + slot] = t;
      smap[(size_t)t * 8 + e] = slot;
    }
}

// exclusive prefix of expert counts -> rt[16..23]; task counts -> rt[24..31]
__global__ void prefix_k(int* __restrict__ rt) {
  if (threadIdx.x == 0) {
    int s = 0;
#pragma unroll
    for (int e = 0; e < 8; ++e) { rt[16 + e] = s; s += rt[e]; }
    int s2 = 0;
#pragma unroll
    for (int tt = 0; tt < 8; ++tt) { rt[24 + tt] = s2; s2 += rt[8 + tt]; }
  }
}

// per-token MoE combine: xf[t] += sum_e s_e*(y0+y1); also writes bf16 lnb
__global__ __launch_bounds__(256) void combine_k(
    const float* __restrict__ y, const float* __restrict__ combine,
    const int* __restrict__ rt, const int* __restrict__ smap,
    float* __restrict__ xf, __hip_bfloat16* __restrict__ lnbout, int T, int CAP)
{
  int wv = threadIdx.x >> 6, lane = threadIdx.x & 63;
  int t = blockIdx.x * 4 + wv;
  if (t >= T) return;
  float acc[12];
#pragma unroll
  for (int i = 0; i < 12; ++i) acc[i] = 0.f;
  for (int e = 0; e < 8; ++e) {
    float s = combine[(size_t)t * 8 + e];
    if (s != 0.f) {                       // wave-uniform branch
      int r = rt[16 + e] + smap[(size_t)t * 8 + e];
      const float* y0 = y + (size_t)r * 768;
      const float* y1 = y0 + (size_t)CAP * 768;
#pragma unroll
      for (int i = 0; i < 12; ++i)
        acc[i] += s * (y0[lane + i * 64] + y1[lane + i * 64]);
    }
  }
  float* xr = xf + (size_t)t * 768;
#pragma unroll
  for (int i = 0; i < 12; ++i) {
    float nv = xr[lane + i * 64] + acc[i];
    xr[lane + i * 64] = nv;
    lnbout[(size_t)t * 768 + lane + i * 64] = f2bf(nv);  // fused f2b for head GEMM
  }
}

// ---------------- masks / small utils --------------------------------------
__global__ void mask_k(const int* __restrict__ sm, const int* __restrict__ am,
                       float* __restrict__ cnt, int* __restrict__ rt,
                       int* __restrict__ tsmap, int* __restrict__ valid, int T)
{
  int t = blockIdx.x * 256 + threadIdx.x;
  if (t >= T) return;
  int a = am[t] != 0;
  float c = 0.f;
#pragma unroll
  for (int tt = 0; tt < 8; ++tt) {
    int vv = (sm[tt * T + t] != 0) & a;
    valid[tt * T + t] = vv;
    int slot = -1;
    if (vv) {
      slot = atomicAdd(&rt[8 + tt], 1);
      rt[32 + 8 * T + tt * T + slot] = t;
    }
    tsmap[(size_t)t * 8 + tt] = slot;
    c += (float)vv;
  }
  cnt[t] = c;
}

__global__ void f2b_k(const float* __restrict__ in, __hip_bfloat16* __restrict__ out, int n) {
  int i = blockIdx.x * 256 + threadIdx.x;
  if (i < n) out[i] = f2bf(in[i]);
}
// fallback: out[i] = out[i] / (cnt[i/768] + 1e-6)
__global__ void final_k(float* __restrict__ out, const float* __restrict__ cnt, int n) {
  int i = blockIdx.x * 256 + threadIdx.x;
  if (i < n) out[i] = out[i] / (cnt[i / 768] + 1e-6f);
}
// batched: gather task slots, sum, divide; one wave per token
__global__ __launch_bounds__(256) void final2_k(
    const float* __restrict__ y2, const int* __restrict__ rt,
    const int* __restrict__ tsmap, const float* __restrict__ cnt,
    float* __restrict__ out, int T)
{
  int wv = threadIdx.x >> 6, lane = threadIdx.x & 63;
  int t = blockIdx.x * 4 + wv;
  if (t >= T) return;
  float acc[12];
#pragma unroll
  for (int i = 0; i < 12; ++i) acc[i] = 0.f;
  for (int tt = 0; tt < 8; ++tt) {
    int s = tsmap[(size_t)t * 8 + tt];
    if (s >= 0) {                         // wave-uniform branch
      const float* yr = y2 + (size_t)(rt[24 + tt] + s) * 768;
#pragma unroll
      for (int i = 0; i < 12; ++i) acc[i] += yr[lane + i * 64];
    }
  }
  float inv = 1.f / (cnt[t] + 1e-6f);
  float* orow = out + (size_t)t * 768;
#pragma unroll
  for (int i = 0; i < 12; ++i) orow[lane + i * 64] = acc[i] * inv;
}

// ---------------- host ------------------------------------------------------
extern "C" void kernel_launch(void* const* d_in, const int* in_sizes, int n_in,
                              void* d_out, int out_size, void* d_ws, size_t ws_size,
                              hipStream_t stream)
{
  (void)in_sizes; (void)n_in; (void)out_size;
  const int Ttok = 8 * 197;  // 1576
  const int D = 768, HID = 3072;
  const int CAP = 4 * Ttok;  // total routed (token,expert) pairs = top-4 exact

  const float* x       = (const float*)d_in[0];
  const float* ln1a_w  = (const float*)d_in[1];
  const float* ln1a_b  = (const float*)d_in[2];
  const float* qkv_wa  = (const float*)d_in[3];
  const float* qkv_ba  = (const float*)d_in[4];
  const float* proj_wa = (const float*)d_in[5];
  const float* proj_ba = (const float*)d_in[6];
  const float* ln2a_w  = (const float*)d_in[7];
  const float* ln2a_b  = (const float*)d_in[8];
  const float* fc1_w   = (const float*)d_in[9];
  const float* fc1_b   = (const float*)d_in[10];
  const float* fc2_w   = (const float*)d_in[11];
  const float* fc2_b   = (const float*)d_in[12];
  const float* ln1b_w  = (const float*)d_in[13];
  const float* ln1b_b  = (const float*)d_in[14];
  const float* qkv_wb  = (const float*)d_in[15];
  const float* qkv_bb  = (const float*)d_in[16];
  const float* proj_wb = (const float*)d_in[17];
  const float* proj_bb = (const float*)d_in[18];
  const float* ln2b_w  = (const float*)d_in[19];
  const float* ln2b_b  = (const float*)d_in[20];
  const float* gate_w  = (const float*)d_in[21];
  const float* w1      = (const float*)d_in[22];
  const float* b1      = (const float*)d_in[23];
  const float* w2      = (const float*)d_in[24];
  const float* b2      = (const float*)d_in[25];
  const float* head_w  = (const float*)d_in[26];
  const float* head_b  = (const float*)d_in[27];
  const int* shared_masks = (const int*)d_in[28];
  const int* agg_mask     = (const int*)d_in[29];
  float* out           = (float*)d_out;

  char* wsp = (char*)d_ws;
  auto alloc = [&](size_t bytes) { char* p = wsp; wsp += (bytes + 255) & ~(size_t)255; return p; };
  float* xf             = (float*)alloc((size_t)Ttok * D * 4);
  __hip_bfloat16* lnb   = (__hip_bfloat16*)alloc((size_t)Ttok * D * 2);
  __hip_bfloat16* qkvb  = (__hip_bfloat16*)alloc((size_t)Ttok * 3 * D * 2);
  __hip_bfloat16* attnb = (__hip_bfloat16*)alloc((size_t)Ttok * D * 2);
  __hip_bfloat16* h1    = (__hip_bfloat16*)alloc((size_t)Ttok * HID * 2);
  float* combine        = (float*)alloc((size_t)Ttok * 8 * 4);
  float* cnt            = (float*)alloc((size_t)Ttok * 4);
  int* rt               = (int*)alloc((size_t)(32 + 16 * Ttok) * 4);  // hdr+lists
  int* smap             = (int*)alloc((size_t)Ttok * 8 * 4);
  int* tsmap            = (int*)alloc((size_t)Ttok * 8 * 4);
  int* valid            = (int*)alloc((size_t)8 * Ttok * 4);
  __hip_bfloat16* qkvaT = (__hip_bfloat16*)alloc((size_t)D * 3 * D * 2);
  __hip_bfloat16* projaT= (__hip_bfloat16*)alloc((size_t)D * D * 2);
  __hip_bfloat16* fc1T  = (__hip_bfloat16*)alloc((size_t)D * HID * 2);
  __hip_bfloat16* fc2T  = (__hip_bfloat16*)alloc((size_t)D * HID * 2);
  __hip_bfloat16* qkvbT = (__hip_bfloat16*)alloc((size_t)D * 3 * D * 2);
  __hip_bfloat16* projbT= (__hip_bfloat16*)alloc((size_t)D * D * 2);
  __hip_bfloat16* headT = (__hip_bfloat16*)alloc((size_t)8 * D * D * 2);
  __hip_bfloat16* wT    = (__hip_bfloat16*)alloc((size_t)D * HID * 2);

  // batched-MoE extra buffers (deterministic guard: ws_size constant per harness)
  const size_t used = (size_t)(wsp - (char*)d_ws);
  const size_t extraNeed = 2 * ((size_t)8 * D * HID * 2 + 255)        // w1T8 + w2T8
                         + ((size_t)8 * Ttok * HID * 2 + 255)         // h1_8
                         + (2 * (size_t)CAP * D * 4 + 255);           // yb
  const bool batched = (ws_size >= used + extraNeed);
  __hip_bfloat16* w1T8 = nullptr; __hip_bfloat16* w2T8 = nullptr; __hip_bfloat16* h1_8 = nullptr;
  float* yb = nullptr;
  if (batched) {
    w1T8 = (__hip_bfloat16*)alloc((size_t)8 * D * HID * 2);
    w2T8 = (__hip_bfloat16*)alloc((size_t)8 * D * HID * 2);
    h1_8 = (__hip_bfloat16*)alloc((size_t)8 * Ttok * HID * 2);
    yb   = (float*)alloc(2 * (size_t)CAP * D * 4);   // also reused as head slots (8T rows)
  }

  dim3 tb(32, 8);
  TPack pk{}; pk.n = 0;
  int o_proj_wa = 0, o_fc2 = 0, o_proj_wb = 0, o_w1 = 0, o_w2 = 0, oTot = 0;
  if (batched) {
    int off = 0;
    auto addT = [&](int i, const float* s, __hip_bfloat16* dd, int R, int C, int nz) {
      int tpz = (R / 64) * (C / 64);
      pk.d[i] = TDesc{s, dd, R, C, nz, tpz, off};
      off += tpz * nz;
    };
    addT(0, qkv_wa, qkvaT, D, 3 * D, 1);   o_proj_wa = off;
    addT(1, proj_wa, projaT, D, D, 1);
    addT(2, fc1_w, fc1T, D, HID, 1);       o_fc2 = pk.d[2].tileOff + (D/64)*(HID/64);
    addT(3, fc2_w, fc2T, HID, D, 1);
    addT(4, qkv_wb, qkvbT, D, 3 * D, 1);   o_proj_wb = pk.d[4].tileOff + (D/64)*(3*D/64);
    addT(5, proj_wb, projbT, D, D, 1);
    addT(6, head_w, headT, D, D, 8);       o_w1 = pk.d[6].tileOff + 8*(D/64)*(D/64);
    addT(7, w1, w1T8, D, HID, 8);          o_w2 = pk.d[7].tileOff + 8*(D/64)*(HID/64);
    addT(8, w2, w2T8, HID, D, 8);
    pk.n = 9; oTot = off;
    // upfront: only qkv_wa (needed by the first GEMM)
    transpose_all_k<<<o_proj_wa, 256, 0, stream>>>(pk, 0);
  } else {
    transpose_k<<<dim3(3*D/32, D/32, 1), tb, 0, stream>>>(qkv_wa, qkvaT, D, 3*D);
    transpose_k<<<dim3(D/32, D/32, 1),   tb, 0, stream>>>(proj_wa, projaT, D, D);
    transpose_k<<<dim3(HID/32, D/32, 1), tb, 0, stream>>>(fc1_w, fc1T, D, HID);
    transpose_k<<<dim3(D/32, HID/32, 1), tb, 0, stream>>>(fc2_w, fc2T, HID, D);
    transpose_k<<<dim3(3*D/32, D/32, 1), tb, 0, stream>>>(qkv_wb, qkvbT, D, 3*D);
    transpose_k<<<dim3(D/32, D/32, 1),   tb, 0, stream>>>(proj_wb, projbT, D, D);
    transpose_k<<<dim3(D/32, D/32, 8),   tb, 0, stream>>>(head_w, headT, D, D);
  }

  const int nTok = Ttok * D;
  hipMemcpyAsync(xf, x, (size_t)nTok * 4, hipMemcpyDeviceToDevice, stream);
  hipMemsetAsync(rt, 0, 128, stream);   // zero the 32 routing counters/bases
  mask_k<<<(Ttok + 255)/256, 256, 0, stream>>>(shared_masks, agg_mask, cnt, rt, tsmap, valid, Ttok);
  if (!batched) hipMemsetAsync(out, 0, (size_t)nTok * 4, stream);

  const int lnGrid = (Ttok + 3) / 4;
  // carrier grid helper: extend z with ceil(cnt/perSlice) extra slices
  auto carry = [&](dim3 g, int cnt) {
    if (cnt > 0) { int ps = g.x * g.y; g.z += (cnt + ps - 1) / ps; }
    return g;
  };
  dim3 g_qkv(3*D/128, 13, 1);
  dim3 g_proj(D/128, 13, 4);    // split-K x4
  dim3 g_fc1(HID/128, 13, 1);
  dim3 g_fc2(D/128, 13, 4);     // split-K x4
  dim3 g_head(D/128, 13, 8);
  const int attnGrid = 96 * 4;  // (b,h) x 4 row-chunks

  // carrier windows (batched): [start,count] per launch; w1 split fc2/qkv_b,
  // w2 split proj_b/MoE-FC1. Each weight finishes >=1 dispatch before first use.
  int w1half = batched ? (o_w2 - o_w1) / 2 : 0;
  int w2half = batched ? (oTot - o_w2) / 2 : 0;
  int s1 = o_proj_wa, c1 = o_fc2 - o_proj_wa;          // proj_wa+fc1 -> in qkv_a
  int s2 = o_fc2,     c2 = o_proj_wb - o_fc2;          // fc2+qkv_wb  -> in proj_a
  int s3 = o_proj_wb, c3 = o_w1 - o_proj_wb;           // proj_wb+head-> in fc1
  int s4 = o_w1,      c4 = w1half;                     // w1 part1    -> in fc2
  int s5 = o_w1 + w1half, c5 = (o_w2 - o_w1) - w1half; // w1 part2    -> in qkv_b
  int s6 = o_w2,      c6 = w2half;                     // w2 part1    -> in proj_b
  int s7 = o_w2 + w2half, c7 = (oTot - o_w2) - w2half; // w2 part2    -> in MoE FC1
  if (!batched) { c1 = c2 = c3 = c4 = c5 = c6 = c7 = 0; }

  // ---- dense ViT block ----
  ln_k<<<lnGrid, 256, 0, stream>>>(xf, ln1a_w, ln1a_b, lnb, Ttok);
  gemm_bt<EPI_STORE><<<carry(g_qkv, c1), 256, 0, stream>>>(lnb, qkvaT, qkv_ba, Ttok, 3*D, D, 1, 0, 0, 0, 0, 0, qkvb, nullptr, nullptr, nullptr, pk, 1, s1, c1);
  attn_mfma_k<<<attnGrid, 256, 0, stream>>>(qkvb, attnb);
  gemm_bt<EPI_RESADD><<<carry(g_proj, c2), 256, 0, stream>>>(attnb, projaT, proj_ba, Ttok, D, D, 4, 0, 0, 0, 0, 0, nullptr, xf, nullptr, nullptr, pk, 4, s2, c2);
  ln_k<<<lnGrid, 256, 0, stream>>>(xf, ln2a_w, ln2a_b, lnb, Ttok);
  gemm_bt<EPI_GELU><<<carry(g_fc1, c3), 256, 0, stream>>>(lnb, fc1T, fc1_b, Ttok, HID, D, 1, 0, 0, 0, 0, 0, h1, nullptr, nullptr, nullptr, pk, 1, s3, c3);
  gemm_bt<EPI_RESADD><<<carry(g_fc2, c4), 256, 0, stream>>>(h1, fc2T, fc2_b, Ttok, D, HID, 4, 0, 0, 0, 0, 0, nullptr, xf, nullptr, nullptr, pk, 4, s4, c4);

  // ---- MoE ViT block ----
  ln_k<<<lnGrid, 256, 0, stream>>>(xf, ln1b_w, ln1b_b, lnb, Ttok);
  gemm_bt<EPI_STORE><<<carry(g_qkv, c5), 256, 0, stream>>>(lnb, qkvbT, qkv_bb, Ttok, 3*D, D, 1, 0, 0, 0, 0, 0, qkvb, nullptr, nullptr, nullptr, pk, 1, s5, c5);
  attn_mfma_k<<<attnGrid, 256, 0, stream>>>(qkvb, attnb);
  gemm_bt<EPI_RESADD><<<carry(g_proj, c6), 256, 0, stream>>>(attnb, projbT, proj_bb, Ttok, D, D, 4, 0, 0, 0, 0, 0, nullptr, xf, nullptr, nullptr, pk, 4, s6, c6);
  gate_k<<<lnGrid, 256, 0, stream>>>(xf, ln2b_w, ln2b_b, gate_w, combine, rt, smap, lnb, Ttok);
  prefix_k<<<1, 64, 0, stream>>>(rt);
  if (batched) {
    gemm_bt<EPI_GELU_R><<<carry(dim3(HID/128, 13, 8), c7), 256, 0, stream>>>(
        lnb, w1T8, b1, Ttok, HID, D, 1, 0,
        (long long)D*HID, HID, 0, (long long)Ttok*HID, h1_8, nullptr, nullptr, rt, pk, 8, s7, c7);
    gemm_bt<EPI_MOEP><<<dim3(D/128, 13, 16), 256, 0, stream>>>(
        h1_8, w2T8, b2, Ttok, D, HID, 2, 0,
        (long long)HID*D, D, (long long)Ttok*HID, (long long)CAP*D, nullptr, yb, nullptr, rt, pk, 16, 0, 0);
    combine_k<<<lnGrid, 256, 0, stream>>>(yb, combine, rt, smap, xf, lnb, Ttok, CAP);
    gemm_bt<EPI_HEADP><<<g_head, 256, 0, stream>>>(lnb, headT, head_b, Ttok, D, D, 1, 0, (long long)D*D, D, 0, 0, nullptr, yb, nullptr, rt, pk, 8, 0, 0);
    final2_k<<<lnGrid, 256, 0, stream>>>(yb, rt, tsmap, cnt, out, Ttok);
  } else {
    for (int e = 0; e < 8; ++e) {
      transpose_k<<<dim3(HID/32, D/32, 1), tb, 0, stream>>>(w1 + (size_t)e*D*HID, wT, D, HID);
      gemm_bt<EPI_GELU><<<g_fc1, 256, 0, stream>>>(lnb, wT, b1 + (size_t)e*HID, Ttok, HID, D, 1, 0, 0, 0, 0, 0, h1, nullptr, nullptr, nullptr, pk, 1, 0, 0);
      transpose_k<<<dim3(D/32, HID/32, 1), tb, 0, stream>>>(w2 + (size_t)e*HID*D, wT, HID, D);
      gemm_bt<EPI_MOE><<<g_fc2, 256, 0, stream>>>(h1, wT, b2 + (size_t)e*D, Ttok, D, HID, 4, e, 0, 0, 0, 0, nullptr, xf, combine, nullptr, pk, 4, 0, 0);
    }
    f2b_k<<<(nTok + 255)/256, 256, 0, stream>>>(xf, lnb, nTok);
    gemm_bt<EPI_HEAD_R><<<g_head, 256, 0, stream>>>(lnb, headT, head_b, Ttok, D, D, 1, 0, (long long)D*D, D, 0, 0, nullptr, out, nullptr, rt, pk, 8, 0, 0);
    final_k<<<(nTok + 255)/256, 256, 0, stream>>>(out, cnt, nTok);
  }
}

// Round 8
// 718.621 us; speedup vs baseline: 1.3321x; 1.0388x over previous
//
#include <hip/hip_runtime.h>
#include <hip/hip_bf16.h>

#define DEV static __device__ __forceinline__

typedef short bfx8 __attribute__((ext_vector_type(8)));   // 8 bf16 in 4 VGPRs (guide §3)
typedef float fx4  __attribute__((ext_vector_type(4)));

DEV float bf2f(__hip_bfloat16 h) { return __bfloat162float(h); }
DEV __hip_bfloat16 f2bf(float f) { return __float2bfloat16(f); }
DEV float uLO(unsigned u) { return __uint_as_float(u << 16); }
DEV unsigned short f2bfu(float f) { __hip_bfloat16 h = __float2bfloat16(f); return *(unsigned short*)&h; }

DEV float wave_sum(float v) {
#pragma unroll
  for (int o = 32; o; o >>= 1) v += __shfl_xor(v, o, 64);
  return v;
}

#define GLD_LDS16(gp, lp) __builtin_amdgcn_global_load_lds( \
    (__attribute__((address_space(1))) void*)(gp),          \
    (__attribute__((address_space(3))) void*)(lp), 16, 0, 0)

// -------- transpose+convert tiles: src fp32 [R][C] -> dst bf16 [C][R] -------
// 64x64 tiles; float4 loads; bf16 LDS stride-66; short8 stores.
// Tiles are carried either by transpose_all_k or as extra z-slices of gemm_bt
// (grid concatenation: overlap the pure-BW transpose with latency-bound GEMMs).
struct TDesc { const float* src; __hip_bfloat16* dst; int R, C, nz, tilesPerZ, tileOff; };
struct TPack { TDesc d[9]; int n; };

DEV void trans_tile(const TPack& p, int gtile, unsigned short* t, int tid) {
  int di = 0;
#pragma unroll
  for (int i = 1; i < 9; ++i)
    if (i < p.n && gtile >= p.d[i].tileOff) di = i;
  const TDesc d = p.d[di];
  int local = gtile - d.tileOff;
  int z = local / d.tilesPerZ;
  int rem = local - z * d.tilesPerZ;
  int ctiles = d.C >> 6;
  int bx = rem % ctiles, by = rem / ctiles;
  const float* src = d.src + (size_t)z * d.R * d.C;
  __hip_bfloat16* dst = d.dst + (size_t)z * d.R * d.C;
  int c0 = bx * 64, r0 = by * 64;
#pragma unroll
  for (int it = 0; it < 4; ++it) {
    int idx = tid + it * 256;
    int row = idx >> 4, q = idx & 15;
    float4 v = *(const float4*)(src + (size_t)(r0 + row) * d.C + c0 + q * 4);
    ushort2 lo, hi;
    lo.x = f2bfu(v.x); lo.y = f2bfu(v.y);
    hi.x = f2bfu(v.z); hi.y = f2bfu(v.w);
    *(ushort2*)&t[row * 66 + q * 4]     = lo;
    *(ushort2*)&t[row * 66 + q * 4 + 2] = hi;
  }
  __syncthreads();
#pragma unroll
  for (int it = 0; it < 2; ++it) {
    int idx = tid + it * 256;     // 512 short8-units
    int oc = idx >> 3, q = idx & 7;
    bfx8 w;
#pragma unroll
    for (int j = 0; j < 8; ++j)
      w[j] = (short)t[(q * 8 + j) * 66 + oc];
    *(bfx8*)(dst + (size_t)(c0 + oc) * d.R + r0 + q * 8) = w;
  }
}

__global__ __launch_bounds__(256) void transpose_all_k(TPack p, int tStart) {
  __shared__ __align__(16) unsigned short t[64 * 66];
  trans_tile(p, tStart + blockIdx.x, t, threadIdx.x);
}

// single-matrix transpose (fallback path only)
__global__ __launch_bounds__(256) void transpose_k(
    const float* __restrict__ src, __hip_bfloat16* __restrict__ dst,
    int R, int C)
{
  __shared__ float tile[32][33];
  size_t off = (size_t)blockIdx.z * R * C;
  src += off; dst += off;
  int c0 = blockIdx.x * 32, r0 = blockIdx.y * 32;
#pragma unroll
  for (int i = 0; i < 32; i += 8)
    tile[threadIdx.y + i][threadIdx.x] =
        src[(size_t)(r0 + threadIdx.y + i) * C + c0 + threadIdx.x];
  __syncthreads();
#pragma unroll
  for (int i = 0; i < 32; i += 8)
    dst[(size_t)(c0 + threadIdx.y + i) * R + r0 + threadIdx.x] =
        f2bf(tile[threadIdx.x][threadIdx.y + i]);
}

// ---------------- GEMM: C = A[M,K] x B  (B given transposed: BT[N,K]) ------
// 128x128 tile, 4 waves, 4x4 mfma_f32_16x16x32_bf16, 2-phase dbuf K-loop.
// XCD-aware bijective block swizzle (T1/m204): each XCD owns a contiguous
// chunk of the (z,y,x) tile space -> B panels stay L2-resident per XCD.
// Extra z-slices (z >= tZBase) run transpose tiles [tStart, tStart+tCount).
// rt layout: [0..7] expert counts, [8..15] task counts, [16..23] expert bases,
// [24..31] task bases, [32 .. 32+8T) expert token lists, [32+8T ..) task lists.
enum { EPI_STORE = 0, EPI_GELU = 1, EPI_RESADD = 2, EPI_MOE = 3,
       EPI_GELU_R = 4, EPI_MOEP = 5, EPI_HEAD_R = 6, EPI_HEADP = 7 };

template <int MODE>
__global__ __launch_bounds__(256) void gemm_bt(
    const __hip_bfloat16* __restrict__ A,    // [M,K]  (+ zt*strideAz)
    const __hip_bfloat16* __restrict__ BT,   // [zt][N,K]
    const float* __restrict__ bias,          // [zt][N] fp32
    int M, int N, int K, int splitK, int taskBase,
    long long strideBz, long long strideBiasz, long long strideAz, long long strideCz,
    __hip_bfloat16* __restrict__ Cb, float* __restrict__ Cf,
    const float* __restrict__ combine, const int* __restrict__ rt,
    TPack tp, int tZBase, int tStart, int tCount)
{
  constexpr bool ROUTED = (MODE == EPI_GELU_R || MODE == EPI_MOEP ||
                           MODE == EPI_HEAD_R || MODE == EPI_HEADP);
  constexpr bool GATHER = (MODE == EPI_GELU_R || MODE == EPI_HEAD_R || MODE == EPI_HEADP);
  __shared__ __align__(16) __hip_bfloat16 smem[4 * 128 * 32];  // sA[2] | sB[2]
  const int tid = threadIdx.x;

  // ---- carried transpose tiles (grid-concatenated BW work) ----
  if ((int)blockIdx.z >= tZBase) {
    int flat = ((int)blockIdx.z - tZBase) * (int)(gridDim.x * gridDim.y)
             + (int)blockIdx.y * (int)gridDim.x + (int)blockIdx.x;
    if (flat < tCount) trans_tile(tp, tStart + flat, (unsigned short*)smem, tid);
    return;
  }

  // ---- XCD-aware bijective swizzle over the GEMM block range ----
  const int gx = gridDim.x, gy = gridDim.y;
  int bx, by, bz;
  {
    int f = ((int)blockIdx.z * gy + (int)blockIdx.y) * gx + (int)blockIdx.x;
    const int NB = tZBase * gx * gy;
    int xcd = f & 7, idx = f >> 3;
    int q = NB >> 3, r = NB & 7;
    int t = (xcd < r ? xcd * (q + 1) : r * (q + 1) + (xcd - r) * q) + idx;
    bx = t % gx; int tmp = t / gx; by = tmp % gy; bz = tmp / gy;
  }

  const int wave = tid >> 6, lane = tid & 63;
  const int quad = lane >> 4, l16 = lane & 15;
  const int z = bz;
  const int zt = z / splitK;
  const int kc = z - zt * splitK;
  const int task = taskBase + zt;
  const int Ksub = K / splitK;
  const int kbeg = kc * Ksub;
  const int m0 = by * 128, n0 = bx * 128;

  int Meff = M;
  int rtb = 0;
  const int* ilist = nullptr;
  if (ROUTED) {
    const int base = (MODE == EPI_HEAD_R || MODE == EPI_HEADP) ? 8 : 0;
    Meff = rt[base + zt];
    ilist = rt + 32 + (size_t)base * M + (size_t)zt * M;
    if (MODE == EPI_MOEP) rtb = rt[16 + zt];   // compact expert output base
    if (MODE == EPI_HEADP) rtb = rt[24 + zt];  // compact task output base
    if (m0 >= Meff) return;   // whole block exits together, before any barrier
  }

  A += (size_t)zt * strideAz;
  if (MODE != EPI_MOEP && MODE != EPI_HEADP) Cb += (size_t)zt * strideCz;
  const __hip_bfloat16* Bz = BT + (size_t)zt * strideBz;
  const float* biasz = bias + (size_t)zt * strideBiasz;
  const int wm = (wave >> 1) * 64, wn = (wave & 1) * 64;

  __hip_bfloat16* sA0 = smem;
  __hip_bfloat16* sA1 = smem + 128 * 32;
  __hip_bfloat16* sB0 = smem + 2 * 128 * 32;
  __hip_bfloat16* sB1 = smem + 3 * 128 * 32;

  fx4 acc[4][4];
#pragma unroll
  for (int i = 0; i < 4; ++i)
#pragma unroll
    for (int j = 0; j < 4; ++j) acc[i][j] = (fx4){0.f, 0.f, 0.f, 0.f};

  // staging: chunk c covers row c>>2, k-seg (c&3)*8 ; LDS dest = c*8 elems
  const int c0 = tid, c1 = tid + 256;
  const int mlim = Meff - 1;
  int gm0 = m0 + (c0 >> 2); if (gm0 > mlim) gm0 = mlim;
  int gm1 = m0 + (c1 >> 2); if (gm1 > mlim) gm1 = mlim;
  const int ar0 = GATHER ? ilist[gm0] : gm0;
  const int ar1 = GATHER ? ilist[gm1] : gm1;
  const int ak0 = (c0 & 3) * 8, ak1 = (c1 & 3) * 8;
  const __hip_bfloat16* pa0 = A + (size_t)ar0 * K + kbeg + ak0;
  const __hip_bfloat16* pa1 = A + (size_t)ar1 * K + kbeg + ak1;
  const __hip_bfloat16* pb0 = Bz + (size_t)(n0 + (c0 >> 2)) * K + kbeg + ak0;
  const __hip_bfloat16* pb1 = Bz + (size_t)(n0 + (c1 >> 2)) * K + kbeg + ak1;

  // prologue: stage tile 0 into buf 0
  GLD_LDS16(pa0, &sA0[c0 * 8]);
  GLD_LDS16(pa1, &sA0[c1 * 8]);
  GLD_LDS16(pb0, &sB0[c0 * 8]);
  GLD_LDS16(pb1, &sB0[c1 * 8]);
  __syncthreads();   // drains vmcnt -> LDS writes visible

  int cur = 0;
  for (int kk = 0; kk < Ksub; kk += 32) {
    const int nxt = kk + 32;
    if (nxt < Ksub) {          // prefetch t+1 into the other buffer
      GLD_LDS16(pa0 + nxt, (cur ? &sA0[c0 * 8] : &sA1[c0 * 8]));
      GLD_LDS16(pa1 + nxt, (cur ? &sA0[c1 * 8] : &sA1[c1 * 8]));
      GLD_LDS16(pb0 + nxt, (cur ? &sB0[c0 * 8] : &sB1[c0 * 8]));
      GLD_LDS16(pb1 + nxt, (cur ? &sB0[c1 * 8] : &sB1[c1 * 8]));
    }
    const __hip_bfloat16* sAc = cur ? sA1 : sA0;
    const __hip_bfloat16* sBc = cur ? sB1 : sB0;
    bfx8 af[4], bfr[4];
#pragma unroll
    for (int i = 0; i < 4; ++i)
      af[i] = *(const bfx8*)(&sAc[(wm + i * 16 + l16) * 32 + quad * 8]);
#pragma unroll
    for (int j = 0; j < 4; ++j)
      bfr[j] = *(const bfx8*)(&sBc[(wn + j * 16 + l16) * 32 + quad * 8]);
#pragma unroll
    for (int i = 0; i < 4; ++i)
#pragma unroll
      for (int j = 0; j < 4; ++j)
        acc[i][j] = __builtin_amdgcn_mfma_f32_16x16x32_bf16(af[i], bfr[j], acc[i][j], 0, 0, 0);
    __syncthreads();  // vmcnt(0)+barrier: t+1 visible, buf[cur] free for reuse
    cur ^= 1;
  }

  // epilogue: C/D layout col=lane&15, row=quad*4+reg (m89-verified)
  const int mb = m0 + wm + quad * 4;
  const int nb = n0 + wn + l16;
#pragma unroll
  for (int i = 0; i < 4; ++i) {
#pragma unroll
    for (int rr = 0; rr < 4; ++rr) {
      const int m = mb + i * 16 + rr;
      if (m >= Meff) continue;
      int orow = m;
      if (MODE == EPI_HEAD_R) orow = ilist[m];
#pragma unroll
      for (int j = 0; j < 4; ++j) {
        const int n = nb + j * 16;
        float v = acc[i][j][rr];
        if (MODE == EPI_STORE) {
          Cb[(size_t)m * N + n] = f2bf(v + biasz[n]);
        } else if (MODE == EPI_GELU || MODE == EPI_GELU_R) {
          float t = v + biasz[n];
          Cb[(size_t)m * N + n] = f2bf(0.5f * t * (1.f + erff(t * 0.70710678118654752f)));
        } else if (MODE == EPI_RESADD) {
          if (kc == 0) v += biasz[n];
          atomicAdd(&Cf[(size_t)m * N + n], v);
        } else if (MODE == EPI_MOE) {
          float s = combine[m * 8 + task];
          if (s != 0.f) {
            if (kc == 0) v += biasz[n];
            atomicAdd(&Cf[(size_t)m * N + n], s * v);
          }
        } else if (MODE == EPI_MOEP) {
          if (kc == 0) v += biasz[n];
          Cf[(size_t)kc * strideCz + (size_t)(rtb + m) * N + n] = v;
        } else if (MODE == EPI_HEADP) {
          Cf[(size_t)(rtb + m) * N + n] = v + biasz[n];   // plain store, no atomics
        } else {  // EPI_HEAD_R (fallback)
          atomicAdd(&Cf[(size_t)orow * N + n], v + biasz[n]);
        }
      }
    }
  }
}

// ---------------- MFMA attention ------------------------------------------
__global__ __launch_bounds__(256) void attn_mfma_k(
    const __hip_bfloat16* __restrict__ qkvb, __hip_bfloat16* __restrict__ outb)
{
  __shared__ __align__(16) unsigned short VT[64 * 232];       // V^T [d][tok], stride 232
  __shared__ __align__(16) unsigned short Pst[4][16 * 232];   // per-wave P strip [m][tok]
  const int tid = threadIdx.x;
  const int chunk = blockIdx.x & 3;
  const int bh = blockIdx.x >> 2;
  const int b = bh / 12, h = bh - b * 12;
  const size_t tokBase = (size_t)b * 197;
  const __hip_bfloat16* qkvh = qkvb + tokBase * 2304 + (size_t)h * 64;

  // stage V^T (which=2 -> +1536)
  for (int idx = tid; idx < 197 * 32; idx += 256) {
    int j = idx >> 5, dp = idx & 31;
    unsigned pv = *(const unsigned*)(qkvh + (size_t)j * 2304 + 1536 + dp * 2);
    VT[(2 * dp) * 232 + j]     = (unsigned short)(pv & 0xffffu);
    VT[(2 * dp + 1) * 232 + j] = (unsigned short)(pv >> 16);
  }
  // NaN fix: zero VT pad cols [197,232).
  for (int idx = tid; idx < 64 * 35; idx += 256) {
    int r = idx / 35, c = 197 + idx % 35;
    VT[r * 232 + c] = 0;
  }
  __syncthreads();

  const int wave = tid >> 6, lane = tid & 63;
  const int quad = lane >> 4, l16 = lane & 15;
  const int mt = chunk * 4 + wave;   // m-tile 0..12
  if (mt >= 13) return;

  // zero P strip pad cols [208,224)
  {
    int r = lane >> 2, c = 208 + (lane & 3) * 4;
    *(uint2*)&Pst[wave][r * 232 + c] = (uint2){0u, 0u};
  }

  // Q A-frags (clamped rows; invalid rows computed but never stored)
  int tq = mt * 16 + l16; if (tq > 196) tq = 196;
  const bfx8 af0 = *(const bfx8*)(qkvh + (size_t)tq * 2304 + quad * 8);
  const bfx8 af1 = *(const bfx8*)(qkvh + (size_t)tq * 2304 + 32 + quad * 8);

  // S strip: 13 n-tiles, K frags from global (which=1 -> +768)
  fx4 sv[13];
#pragma unroll
  for (int n0 = 0; n0 < 13; ++n0) {
    int tk = n0 * 16 + l16; if (tk > 196) tk = 196;
    const __hip_bfloat16* kp = qkvh + (size_t)tk * 2304 + 768;
    bfx8 bf0 = *(const bfx8*)(kp + quad * 8);
    bfx8 bf1 = *(const bfx8*)(kp + 32 + quad * 8);
    fx4 a = (fx4){0.f, 0.f, 0.f, 0.f};
    a = __builtin_amdgcn_mfma_f32_16x16x32_bf16(af0, bf0, a, 0, 0, 0);
    a = __builtin_amdgcn_mfma_f32_16x16x32_bf16(af1, bf1, a, 0, 0, 0);
    sv[n0] = a;
  }

  // softmax per row (row = quad*4+rr); cols of lane: n0*16+l16
  float inv[4];
#pragma unroll
  for (int rr = 0; rr < 4; ++rr) {
    float mx = -3.0e38f;
#pragma unroll
    for (int n0 = 0; n0 < 13; ++n0) {
      bool ok = (n0 < 12) | (l16 < 5);           // col < 197
      float s = ok ? sv[n0][rr] * 0.125f : -3.0e38f;
      sv[n0][rr] = s;
      mx = fmaxf(mx, s);
    }
#pragma unroll
    for (int o = 1; o < 16; o <<= 1) mx = fmaxf(mx, __shfl_xor(mx, o, 64));
    float sum = 0.f;
#pragma unroll
    for (int n0 = 0; n0 < 13; ++n0) {
      float s = sv[n0][rr];
      float e = (s > -1.0e38f) ? __expf(s - mx) : 0.f;
      sv[n0][rr] = e;
      sum += e;
    }
#pragma unroll
    for (int o = 1; o < 16; o <<= 1) sum += __shfl_xor(sum, o, 64);
    inv[rr] = 1.f / sum;
    const int row = quad * 4 + rr;
#pragma unroll
    for (int n0 = 0; n0 < 13; ++n0)
      Pst[wave][row * 232 + n0 * 16 + l16] = f2bfu(sv[n0][rr]);   // P hi
  }

  // PV pass 1 (P hi)
  fx4 pv[4];
#pragma unroll
  for (int nd = 0; nd < 4; ++nd) pv[nd] = (fx4){0.f, 0.f, 0.f, 0.f};
#pragma unroll
  for (int kk = 0; kk < 7; ++kk) {
    bfx8 paf = *(const bfx8*)&Pst[wave][l16 * 232 + kk * 32 + quad * 8];
#pragma unroll
    for (int nd = 0; nd < 4; ++nd) {
      bfx8 bfv = *(const bfx8*)&VT[(nd * 16 + l16) * 232 + kk * 32 + quad * 8];
      pv[nd] = __builtin_amdgcn_mfma_f32_16x16x32_bf16(paf, bfv, pv[nd], 0, 0, 0);
    }
  }

  // P lo = e - bf16(e), overwrite same strip (same-wave ordering -> safe)
#pragma unroll
  for (int rr = 0; rr < 4; ++rr) {
    const int row = quad * 4 + rr;
#pragma unroll
    for (int n0 = 0; n0 < 13; ++n0) {
      float e = sv[n0][rr];
      Pst[wave][row * 232 + n0 * 16 + l16] = f2bfu(e - uLO(f2bfu(e)));
    }
  }

  // PV pass 2 (P lo) accumulates
#pragma unroll
  for (int kk = 0; kk < 7; ++kk) {
    bfx8 paf = *(const bfx8*)&Pst[wave][l16 * 232 + kk * 32 + quad * 8];
#pragma unroll
    for (int nd = 0; nd < 4; ++nd) {
      bfx8 bfv = *(const bfx8*)&VT[(nd * 16 + l16) * 232 + kk * 32 + quad * 8];
      pv[nd] = __builtin_amdgcn_mfma_f32_16x16x32_bf16(paf, bfv, pv[nd], 0, 0, 0);
    }
  }

  // store: row m = mt*16 + quad*4 + rr, col d = nd*16 + l16
#pragma unroll
  for (int rr = 0; rr < 4; ++rr) {
    int m = mt * 16 + quad * 4 + rr;
    if (m > 196) continue;
    __hip_bfloat16* op = outb + (tokBase + m) * 768 + (size_t)h * 64;
#pragma unroll
    for (int nd = 0; nd < 4; ++nd)
      op[nd * 16 + l16] = f2bf(pv[nd][rr] * inv[rr]);
  }
}

// ---------------- LayerNorm: one wave per token, fp32 in -> bf16 out -------
__global__ __launch_bounds__(256) void ln_k(
    const float* __restrict__ xf, const float* __restrict__ w,
    const float* __restrict__ b, __hip_bfloat16* __restrict__ out, int T)
{
  int wv = threadIdx.x >> 6, lane = threadIdx.x & 63;
  int t = blockIdx.x * 4 + wv;
  if (t >= T) return;
  const float* row = xf + (size_t)t * 768;
  float v[12]; float s = 0.f;
#pragma unroll
  for (int i = 0; i < 12; ++i) { v[i] = row[lane + i * 64]; s += v[i]; }
  s = wave_sum(s);
  float mean = s * (1.f / 768.f);
  float q = 0.f;
#pragma unroll
  for (int i = 0; i < 12; ++i) { float d = v[i] - mean; q += d * d; }
  q = wave_sum(q);
  float rstd = rsqrtf(q * (1.f / 768.f) + 1e-5f);
#pragma unroll
  for (int i = 0; i < 12; ++i) {
    int d = lane + i * 64;
    out[(size_t)t * 768 + d] = f2bf((v[i] - mean) * rstd * w[d] + b[d]);
  }
}

// ---------------- MoE gating: fp32 LN + logits + softmax + top-4 ----------
__global__ __launch_bounds__(256) void gate_k(
    const float* __restrict__ xf, const float* __restrict__ lw,
    const float* __restrict__ lb, const float* __restrict__ gw,
    float* __restrict__ combine, int* __restrict__ rt, int* __restrict__ smap,
    __hip_bfloat16* __restrict__ lnbout, int T)
{
  int wv = threadIdx.x >> 6, lane = threadIdx.x & 63;
  int t = blockIdx.x * 4 + wv;
  if (t >= T) return;
  const float* row = xf + (size_t)t * 768;
  float v[12]; float s = 0.f;
#pragma unroll
  for (int i = 0; i < 12; ++i) { v[i] = row[lane + i * 64]; s += v[i]; }
  s = wave_sum(s);
  float mean = s * (1.f / 768.f);
  float qv = 0.f;
#pragma unroll
  for (int i = 0; i < 12; ++i) { float d = v[i] - mean; qv += d * d; }
  qv = wave_sum(qv);
  float rstd = rsqrtf(qv * (1.f / 768.f) + 1e-5f);
  float acc[8];
#pragma unroll
  for (int e = 0; e < 8; ++e) acc[e] = 0.f;
#pragma unroll
  for (int i = 0; i < 12; ++i) {
    int d = lane + i * 64;
    float xn = (v[i] - mean) * rstd * lw[d] + lb[d];
    lnbout[(size_t)t * 768 + d] = f2bf(xn);   // merged ln2b output
    float4 g0 = *(const float4*)(gw + (size_t)d * 8);
    float4 g1 = *(const float4*)(gw + (size_t)d * 8 + 4);
    acc[0] += xn * g0.x; acc[1] += xn * g0.y;
    acc[2] += xn * g0.z; acc[3] += xn * g0.w;
    acc[4] += xn * g1.x; acc[5] += xn * g1.y;
    acc[6] += xn * g1.z; acc[7] += xn * g1.w;
  }
#pragma unroll
  for (int e = 0; e < 8; ++e) acc[e] = wave_sum(acc[e]);
  float mx = acc[0];
#pragma unroll
  for (int e = 1; e < 8; ++e) mx = fmaxf(mx, acc[e]);
  float p[8]; float se = 0.f;
#pragma unroll
  for (int e = 0; e < 8; ++e) { p[e] = __expf(acc[e] - mx); se += p[e]; }
  float inv = 1.f / se;
#pragma unroll
  for (int e = 0; e < 8; ++e) p[e] *= inv;
  float outv[8]; bool used[8];
#pragma unroll
  for (int e = 0; e < 8; ++e) { outv[e] = 0.f; used[e] = false; }
  for (int k = 0; k < 4; ++k) {   // top-4, ties -> lowest index (matches top_k)
    int best = -1; float bv = -1.f;
#pragma unroll
    for (int e = 0; e < 8; ++e) if (!used[e] && p[e] > bv) { bv = p[e]; best = e; }
#pragma unroll
    for (int e = 0; e < 8; ++e) if (e == best) { used[e] = true; outv[e] = bv; }
  }
#pragma unroll
  for (int e = 0; e < 8; ++e) if (lane == e) combine[(size_t)t * 8 + e] = outv[e];
#pragma unroll
  for (int e = 0; e < 8; ++e)
    if (lane == e && outv[e] != 0.f) {
      int slot = atomicAdd(&rt[e], 1);
      rt[32 + e * T + slot] = t;
      smap[(size_t)t * 8 + e] = slot;
    }
}

// exclusive prefix of expert counts -> rt[16..23]; task counts -> rt[24..31]
__global__ void prefix_k(int* __restrict__ rt) {
  if (threadIdx.x == 0) {
    int s = 0;
#pragma unroll
    for (int e = 0; e < 8; ++e) { rt[16 + e] = s; s += rt[e]; }
    int s2 = 0;
#pragma unroll
    for (int tt = 0; tt < 8; ++tt) { rt[24 + tt] = s2; s2 += rt[8 + tt]; }
  }
}

// per-token MoE combine: xf[t] += sum_e s_e*(y0+y1); also writes bf16 lnb
__global__ __launch_bounds__(256) void combine_k(
    const float* __restrict__ y, const float* __restrict__ combine,
    const int* __restrict__ rt, const int* __restrict__ smap,
    float* __restrict__ xf, __hip_bfloat16* __restrict__ lnbout, int T, int CAP)
{
  int wv = threadIdx.x >> 6, lane = threadIdx.x & 63;
  int t = blockIdx.x * 4 + wv;
  if (t >= T) return;
  float acc[12];
#pragma unroll
  for (int i = 0; i < 12; ++i) acc[i] = 0.f;
  for (int e = 0; e < 8; ++e) {
    float s = combine[(size_t)t * 8 + e];
    if (s != 0.f) {                       // wave-uniform branch
      int r = rt[16 + e] + smap[(size_t)t * 8 + e];
      const float* y0 = y + (size_t)r * 768;
      const float* y1 = y0 + (size_t)CAP * 768;
#pragma unroll
      for (int i = 0; i < 12; ++i)
        acc[i] += s * (y0[lane + i * 64] + y1[lane + i * 64]);
    }
  }
  float* xr = xf + (size_t)t * 768;
#pragma unroll
  for (int i = 0; i < 12; ++i) {
    float nv = xr[lane + i * 64] + acc[i];
    xr[lane + i * 64] = nv;
    lnbout[(size_t)t * 768 + lane + i * 64] = f2bf(nv);  // fused f2b for head GEMM
  }
}

// ---------------- masks / small utils --------------------------------------
__global__ void mask_k(const int* __restrict__ sm, const int* __restrict__ am,
                       float* __restrict__ cnt, int* __restrict__ rt,
                       int* __restrict__ tsmap, int* __restrict__ valid, int T)
{
  int t = blockIdx.x * 256 + threadIdx.x;
  if (t >= T) return;
  int a = am[t] != 0;
  float c = 0.f;
#pragma unroll
  for (int tt = 0; tt < 8; ++tt) {
    int vv = (sm[tt * T + t] != 0) & a;
    valid[tt * T + t] = vv;
    int slot = -1;
    if (vv) {
      slot = atomicAdd(&rt[8 + tt], 1);
      rt[32 + 8 * T + tt * T + slot] = t;
    }
    tsmap[(size_t)t * 8 + tt] = slot;
    c += (float)vv;
  }
  cnt[t] = c;
}

__global__ void f2b_k(const float* __restrict__ in, __hip_bfloat16* __restrict__ out, int n) {
  int i = blockIdx.x * 256 + threadIdx.x;
  if (i < n) out[i] = f2bf(in[i]);
}
// fallback: out[i] = out[i] / (cnt[i/768] + 1e-6)
__global__ void final_k(float* __restrict__ out, const float* __restrict__ cnt, int n) {
  int i = blockIdx.x * 256 + threadIdx.x;
  if (i < n) out[i] = out[i] / (cnt[i / 768] + 1e-6f);
}
// batched: gather task slots, sum, divide; one wave per token
__global__ __launch_bounds__(256) void final2_k(
    const float* __restrict__ y2, const int* __restrict__ rt,
    const int* __restrict__ tsmap, const float* __restrict__ cnt,
    float* __restrict__ out, int T)
{
  int wv = threadIdx.x >> 6, lane = threadIdx.x & 63;
  int t = blockIdx.x * 4 + wv;
  if (t >= T) return;
  float acc[12];
#pragma unroll
  for (int i = 0; i < 12; ++i) acc[i] = 0.f;
  for (int tt = 0; tt < 8; ++tt) {
    int s = tsmap[(size_t)t * 8 + tt];
    if (s >= 0) {                         // wave-uniform branch
      const float* yr = y2 + (size_t)(rt[24 + tt] + s) * 768;
#pragma unroll
      for (int i = 0; i < 12; ++i) acc[i] += yr[lane + i * 64];
    }
  }
  float inv = 1.f / (cnt[t] + 1e-6f);
  float* orow = out + (size_t)t * 768;
#pragma unroll
  for (int i = 0; i < 12; ++i) orow[lane + i * 64] = acc[i] * inv;
}

// ---------------- host ------------------------------------------------------
extern "C" void kernel_launch(void* const* d_in, const int* in_sizes, int n_in,
                              void* d_out, int out_size, void* d_ws, size_t ws_size,
                              hipStream_t stream)
{
  (void)in_sizes; (void)n_in; (void)out_size;
  const int Ttok = 8 * 197;  // 1576
  const int D = 768, HID = 3072;
  const int CAP = 4 * Ttok;  // total routed (token,expert) pairs = top-4 exact

  const float* x       = (const float*)d_in[0];
  const float* ln1a_w  = (const float*)d_in[1];
  const float* ln1a_b  = (const float*)d_in[2];
  const float* qkv_wa  = (const float*)d_in[3];
  const float* qkv_ba  = (const float*)d_in[4];
  const float* proj_wa = (const float*)d_in[5];
  const float* proj_ba = (const float*)d_in[6];
  const float* ln2a_w  = (const float*)d_in[7];
  const float* ln2a_b  = (const float*)d_in[8];
  const float* fc1_w   = (const float*)d_in[9];
  const float* fc1_b   = (const float*)d_in[10];
  const float* fc2_w   = (const float*)d_in[11];
  const float* fc2_b   = (const float*)d_in[12];
  const float* ln1b_w  = (const float*)d_in[13];
  const float* ln1b_b  = (const float*)d_in[14];
  const float* qkv_wb  = (const float*)d_in[15];
  const float* qkv_bb  = (const float*)d_in[16];
  const float* proj_wb = (const float*)d_in[17];
  const float* proj_bb = (const float*)d_in[18];
  const float* ln2b_w  = (const float*)d_in[19];
  const float* ln2b_b  = (const float*)d_in[20];
  const float* gate_w  = (const float*)d_in[21];
  const float* w1      = (const float*)d_in[22];
  const float* b1      = (const float*)d_in[23];
  const float* w2      = (const float*)d_in[24];
  const float* b2      = (const float*)d_in[25];
  const float* head_w  = (const float*)d_in[26];
  const float* head_b  = (const float*)d_in[27];
  const int* shared_masks = (const int*)d_in[28];
  const int* agg_mask     = (const int*)d_in[29];
  float* out           = (float*)d_out;

  char* wsp = (char*)d_ws;
  auto alloc = [&](size_t bytes) { char* p = wsp; wsp += (bytes + 255) & ~(size_t)255; return p; };
  float* xf             = (float*)alloc((size_t)Ttok * D * 4);
  __hip_bfloat16* lnb   = (__hip_bfloat16*)alloc((size_t)Ttok * D * 2);
  __hip_bfloat16* qkvb  = (__hip_bfloat16*)alloc((size_t)Ttok * 3 * D * 2);
  __hip_bfloat16* attnb = (__hip_bfloat16*)alloc((size_t)Ttok * D * 2);
  __hip_bfloat16* h1    = (__hip_bfloat16*)alloc((size_t)Ttok * HID * 2);
  float* combine        = (float*)alloc((size_t)Ttok * 8 * 4);
  float* cnt            = (float*)alloc((size_t)Ttok * 4);
  int* rt               = (int*)alloc((size_t)(32 + 16 * Ttok) * 4);  // hdr+lists
  int* smap             = (int*)alloc((size_t)Ttok * 8 * 4);
  int* tsmap            = (int*)alloc((size_t)Ttok * 8 * 4);
  int* valid            = (int*)alloc((size_t)8 * Ttok * 4);
  __hip_bfloat16* qkvaT = (__hip_bfloat16*)alloc((size_t)D * 3 * D * 2);
  __hip_bfloat16* projaT= (__hip_bfloat16*)alloc((size_t)D * D * 2);
  __hip_bfloat16* fc1T  = (__hip_bfloat16*)alloc((size_t)D * HID * 2);
  __hip_bfloat16* fc2T  = (__hip_bfloat16*)alloc((size_t)D * HID * 2);
  __hip_bfloat16* qkvbT = (__hip_bfloat16*)alloc((size_t)D * 3 * D * 2);
  __hip_bfloat16* projbT= (__hip_bfloat16*)alloc((size_t)D * D * 2);
  __hip_bfloat16* headT = (__hip_bfloat16*)alloc((size_t)8 * D * D * 2);
  __hip_bfloat16* wT    = (__hip_bfloat16*)alloc((size_t)D * HID * 2);

  // batched-MoE extra buffers (deterministic guard: ws_size constant per harness)
  const size_t used = (size_t)(wsp - (char*)d_ws);
  const size_t extraNeed = 2 * ((size_t)8 * D * HID * 2 + 255)        // w1T8 + w2T8
                         + ((size_t)8 * Ttok * HID * 2 + 255)         // h1_8
                         + (2 * (size_t)CAP * D * 4 + 255);           // yb
  const bool batched = (ws_size >= used + extraNeed);
  __hip_bfloat16* w1T8 = nullptr; __hip_bfloat16* w2T8 = nullptr; __hip_bfloat16* h1_8 = nullptr;
  float* yb = nullptr;
  if (batched) {
    w1T8 = (__hip_bfloat16*)alloc((size_t)8 * D * HID * 2);
    w2T8 = (__hip_bfloat16*)alloc((size_t)8 * D * HID * 2);
    h1_8 = (__hip_bfloat16*)alloc((size_t)8 * Ttok * HID * 2);
    yb   = (float*)alloc(2 * (size_t)CAP * D * 4);   // also reused as head slots (8T rows)
  }

  dim3 tb(32, 8);
  TPack pk{}; pk.n = 0;
  int o_proj_wa = 0, o_fc2 = 0, o_proj_wb = 0, o_w1 = 0, o_w2 = 0, oTot = 0;
  if (batched) {
    int off = 0;
    auto addT = [&](int i, const float* s, __hip_bfloat16* dd, int R, int C, int nz) {
      int tpz = (R / 64) * (C / 64);
      pk.d[i] = TDesc{s, dd, R, C, nz, tpz, off};
      off += tpz * nz;
    };
    addT(0, qkv_wa, qkvaT, D, 3 * D, 1);   o_proj_wa = off;
    addT(1, proj_wa, projaT, D, D, 1);
    addT(2, fc1_w, fc1T, D, HID, 1);       o_fc2 = pk.d[2].tileOff + (D/64)*(HID/64);
    addT(3, fc2_w, fc2T, HID, D, 1);
    addT(4, qkv_wb, qkvbT, D, 3 * D, 1);   o_proj_wb = pk.d[4].tileOff + (D/64)*(3*D/64);
    addT(5, proj_wb, projbT, D, D, 1);
    addT(6, head_w, headT, D, D, 8);       o_w1 = pk.d[6].tileOff + 8*(D/64)*(D/64);
    addT(7, w1, w1T8, D, HID, 8);          o_w2 = pk.d[7].tileOff + 8*(D/64)*(HID/64);
    addT(8, w2, w2T8, HID, D, 8);
    pk.n = 9; oTot = off;
    // upfront: only qkv_wa (needed by the first GEMM)
    transpose_all_k<<<o_proj_wa, 256, 0, stream>>>(pk, 0);
  } else {
    transpose_k<<<dim3(3*D/32, D/32, 1), tb, 0, stream>>>(qkv_wa, qkvaT, D, 3*D);
    transpose_k<<<dim3(D/32, D/32, 1),   tb, 0, stream>>>(proj_wa, projaT, D, D);
    transpose_k<<<dim3(HID/32, D/32, 1), tb, 0, stream>>>(fc1_w, fc1T, D, HID);
    transpose_k<<<dim3(D/32, HID/32, 1), tb, 0, stream>>>(fc2_w, fc2T, HID, D);
    transpose_k<<<dim3(3*D/32, D/32, 1), tb, 0, stream>>>(qkv_wb, qkvbT, D, 3*D);
    transpose_k<<<dim3(D/32, D/32, 1),   tb, 0, stream>>>(proj_wb, projbT, D, D);
    transpose_k<<<dim3(D/32, D/32, 8),   tb, 0, stream>>>(head_w, headT, D, D);
  }

  const int nTok = Ttok * D;
  hipMemcpyAsync(xf, x, (size_t)nTok * 4, hipMemcpyDeviceToDevice, stream);
  hipMemsetAsync(rt, 0, 128, stream);   // zero the 32 routing counters/bases
  mask_k<<<(Ttok + 255)/256, 256, 0, stream>>>(shared_masks, agg_mask, cnt, rt, tsmap, valid, Ttok);
  if (!batched) hipMemsetAsync(out, 0, (size_t)nTok * 4, stream);

  const int lnGrid = (Ttok + 3) / 4;
  // carrier grid helper: extend z with ceil(cnt/perSlice) extra slices
  auto carry = [&](dim3 g, int cnt) {
    if (cnt > 0) { int ps = g.x * g.y; g.z += (cnt + ps - 1) / ps; }
    return g;
  };
  dim3 g_qkv(3*D/128, 13, 1);
  dim3 g_proj(D/128, 13, 4);    // split-K x4
  dim3 g_fc1(HID/128, 13, 1);
  dim3 g_fc2(D/128, 13, 4);     // split-K x4
  dim3 g_head(D/128, 13, 8);
  const int attnGrid = 96 * 4;  // (b,h) x 4 row-chunks

  // carrier windows (batched): [start,count] per launch; w1 split fc2/qkv_b,
  // w2 split proj_b/MoE-FC1. Each weight finishes >=1 dispatch before first use.
  int w1half = batched ? (o_w2 - o_w1) / 2 : 0;
  int w2half = batched ? (oTot - o_w2) / 2 : 0;
  int s1 = o_proj_wa, c1 = o_fc2 - o_proj_wa;          // proj_wa+fc1 -> in qkv_a
  int s2 = o_fc2,     c2 = o_proj_wb - o_fc2;          // fc2+qkv_wb  -> in proj_a
  int s3 = o_proj_wb, c3 = o_w1 - o_proj_wb;           // proj_wb+head-> in fc1
  int s4 = o_w1,      c4 = w1half;                     // w1 part1    -> in fc2
  int s5 = o_w1 + w1half, c5 = (o_w2 - o_w1) - w1half; // w1 part2    -> in qkv_b
  int s6 = o_w2,      c6 = w2half;                     // w2 part1    -> in proj_b
  int s7 = o_w2 + w2half, c7 = (oTot - o_w2) - w2half; // w2 part2    -> in MoE FC1
  if (!batched) { c1 = c2 = c3 = c4 = c5 = c6 = c7 = 0; }

  // ---- dense ViT block ----
  ln_k<<<lnGrid, 256, 0, stream>>>(xf, ln1a_w, ln1a_b, lnb, Ttok);
  gemm_bt<EPI_STORE><<<carry(g_qkv, c1), 256, 0, stream>>>(lnb, qkvaT, qkv_ba, Ttok, 3*D, D, 1, 0, 0, 0, 0, 0, qkvb, nullptr, nullptr, nullptr, pk, 1, s1, c1);
  attn_mfma_k<<<attnGrid, 256, 0, stream>>>(qkvb, attnb);
  gemm_bt<EPI_RESADD><<<carry(g_proj, c2), 256, 0, stream>>>(attnb, projaT, proj_ba, Ttok, D, D, 4, 0, 0, 0, 0, 0, nullptr, xf, nullptr, nullptr, pk, 4, s2, c2);
  ln_k<<<lnGrid, 256, 0, stream>>>(xf, ln2a_w, ln2a_b, lnb, Ttok);
  gemm_bt<EPI_GELU><<<carry(g_fc1, c3), 256, 0, stream>>>(lnb, fc1T, fc1_b, Ttok, HID, D, 1, 0, 0, 0, 0, 0, h1, nullptr, nullptr, nullptr, pk, 1, s3, c3);
  gemm_bt<EPI_RESADD><<<carry(g_fc2, c4), 256, 0, stream>>>(h1, fc2T, fc2_b, Ttok, D, HID, 4, 0, 0, 0, 0, 0, nullptr, xf, nullptr, nullptr, pk, 4, s4, c4);

  // ---- MoE ViT block ----
  ln_k<<<lnGrid, 256, 0, stream>>>(xf, ln1b_w, ln1b_b, lnb, Ttok);
  gemm_bt<EPI_STORE><<<carry(g_qkv, c5), 256, 0, stream>>>(lnb, qkvbT, qkv_bb, Ttok, 3*D, D, 1, 0, 0, 0, 0, 0, qkvb, nullptr, nullptr, nullptr, pk, 1, s5, c5);
  attn_mfma_k<<<attnGrid, 256, 0, stream>>>(qkvb, attnb);
  gemm_bt<EPI_RESADD><<<carry(g_proj, c6), 256, 0, stream>>>(attnb, projbT, proj_bb, Ttok, D, D, 4, 0, 0, 0, 0, 0, nullptr, xf, nullptr, nullptr, pk, 4, s6, c6);
  gate_k<<<lnGrid, 256, 0, stream>>>(xf, ln2b_w, ln2b_b, gate_w, combine, rt, smap, lnb, Ttok);
  prefix_k<<<1, 64, 0, stream>>>(rt);
  if (batched) {
    gemm_bt<EPI_GELU_R><<<carry(dim3(HID/128, 13, 8), c7), 256, 0, stream>>>(
        lnb, w1T8, b1, Ttok, HID, D, 1, 0,
        (long long)D*HID, HID, 0, (long long)Ttok*HID, h1_8, nullptr, nullptr, rt, pk, 8, s7, c7);
    gemm_bt<EPI_MOEP><<<dim3(D/128, 13, 16), 256, 0, stream>>>(
        h1_8, w2T8, b2, Ttok, D, HID, 2, 0,
        (long long)HID*D, D, (long long)Ttok*HID, (long long)CAP*D, nullptr, yb, nullptr, rt, pk, 16, 0, 0);
    combine_k<<<lnGrid, 256, 0, stream>>>(yb, combine, rt, smap, xf, lnb, Ttok, CAP);
    gemm_bt<EPI_HEADP><<<g_head, 256, 0, stream>>>(lnb, headT, head_b, Ttok, D, D, 1, 0, (long long)D*D, D, 0, 0, nullptr, yb, nullptr, rt, pk, 8, 0, 0);
    final2_k<<<lnGrid, 256, 0, stream>>>(yb, rt, tsmap, cnt, out, Ttok);
  } else {
    for (int e = 0; e < 8; ++e) {
      transpose_k<<<dim3(HID/32, D/32, 1), tb, 0, stream>>>(w1 + (size_t)e*D*HID, wT, D, HID);
      gemm_bt<EPI_GELU><<<g_fc1, 256, 0, stream>>>(lnb, wT, b1 + (size_t)e*HID, Ttok, HID, D, 1, 0, 0, 0, 0, 0, h1, nullptr, nullptr, nullptr, pk, 1, 0, 0);
      transpose_k<<<dim3(D/32, HID/32, 1), tb, 0, stream>>>(w2 + (size_t)e*HID*D, wT, HID, D);
      gemm_bt<EPI_MOE><<<g_fc2, 256, 0, stream>>>(h1, wT, b2 + (size_t)e*D, Ttok, D, HID, 4, e, 0, 0, 0, 0, nullptr, xf, combine, nullptr, pk, 4, 0, 0);
    }
    f2b_k<<<(nTok + 255)/256, 256, 0, stream>>>(xf, lnb, nTok);
    gemm_bt<EPI_HEAD_R><<<g_head, 256, 0, stream>>>(lnb, headT, head_b, Ttok, D, D, 1, 0, (long long)D*D, D, 0, 0, nullptr, out, nullptr, rt, pk, 8, 0, 0);
    final_k<<<(nTok + 255)/256, 256, 0, stream>>>(out, cnt, nTok);
  }
}